// Round 1
// baseline (400.869 us; speedup 1.0000x reference)
//
#include <hip/hip_runtime.h>
#include <math.h>

// Problem constants
#define B_    1024
#define D_    768
#define C_    150
#define P_    64
#define TWOD  1536
#define NCLS  151   // C+1
#define CPAD  256   // partial row: 0..150 logits, 151..191 junk, 192..255 u

// fused_tile: 128b x 64c per block, 8x4/thr, e split 16 ways
#define ECHUNKS 16
#define ECHUNK  96

// gemm: 64x128 tile, BK=32, bf16 LDS stride 40
#define ASTR  40
// u-path LDS stride (halves)
#define USTRU 120
// pair phase LDS stride (halves)
#define USTR  72

// persistent grid
#define NBLK  512

// Workspace layout (float offsets)
#define OFF_MH      0
#define OFF_XH      (OFF_MH + (C_ * TWOD) / 2)
#define OFF_PARTIAL (OFF_XH + (B_ * TWOD) / 2)
#define OFF_UHF     (OFF_PARTIAL + ECHUNKS * B_ * CPAD)
#define OFF_SQN     (OFF_UHF + (B_ * P_) / 2)
#define OFF_CLS     (OFF_SQN + B_)
#define OFF_PAIR    (OFF_CLS + B_)
#define OFF_XBF     (OFF_PAIR + 1024)
#define OFF_MEMBF   (OFF_XBF + (B_ * D_) / 2)
#define OFF_WBF     (OFF_MEMBF + (C_ * D_) / 2)
#define OFF_P2H     (OFF_WBF + (TWOD * TWOD) / 2)
#define OFF_P1H     (OFF_P2H + (P_ * TWOD) / 2)
#define OFF_BAR     (OFF_P1H + TWOD / 2)   // int[528]: root cnt, gen, 32 group ctrs

typedef __bf16    bfx8   __attribute__((ext_vector_type(8)));
typedef _Float16  fp16x8 __attribute__((ext_vector_type(8)));
typedef _Float16  h2v    __attribute__((ext_vector_type(2)));
typedef float     f32x4  __attribute__((ext_vector_type(4)));

__device__ inline ushort f2bf(float f) {
    union { float f; unsigned u; } c; c.f = f;
    unsigned r = c.u + 0x7fffu + ((c.u >> 16) & 1u);
    return (ushort)(r >> 16);
}
__device__ inline ushort f2h(float f) {
    _Float16 h = (_Float16)f;
    return __builtin_bit_cast(ushort, h);
}
__device__ inline unsigned addrelu2(unsigned a, unsigned m) {
    h2v s = __builtin_bit_cast(h2v, a) + __builtin_bit_cast(h2v, m);
    h2v z = {(_Float16)0.f, (_Float16)0.f};
    s = __builtin_elementwise_max(s, z);
    return __builtin_bit_cast(unsigned, s);
}
__device__ inline unsigned relu2(unsigned a) {
    h2v s = __builtin_bit_cast(h2v, a);
    h2v z = {(_Float16)0.f, (_Float16)0.f};
    s = __builtin_elementwise_max(s, z);
    return __builtin_bit_cast(unsigned, s);
}
__device__ inline float dot2acc(unsigned a, unsigned b, float c) {
    return __builtin_amdgcn_fdot2(__builtin_bit_cast(h2v, a),
                                  __builtin_bit_cast(h2v, b), c, false);
}

// ---------------------------------------------------------------------------
// Two-level grid barrier: 32 groups of 16 blocks -> root of 32. Scoped
// acquire/release atomics give cross-XCD visibility (agent-scope release
// writes back L2; acquire invalidates L1/L2) — same cache traffic a kernel
// boundary pays. Max same-address serialization depth: 16 (group) + 32 (root).
// ---------------------------------------------------------------------------
__device__ __forceinline__ void grid_barrier(int* bar)
{
    __syncthreads();
    if (threadIdx.x == 0) {
        int* gen = bar + 1;
        const int g = __hip_atomic_load(gen, __ATOMIC_RELAXED,
                                        __HIP_MEMORY_SCOPE_AGENT);
        int* gcnt = bar + 16 + (blockIdx.x >> 4) * 16;   // 64B-spaced groups
        int gv = __hip_atomic_fetch_add(gcnt, 1, __ATOMIC_ACQ_REL,
                                        __HIP_MEMORY_SCOPE_AGENT);
        if (gv == 15) {
            __hip_atomic_store(gcnt, 0, __ATOMIC_RELAXED,
                               __HIP_MEMORY_SCOPE_AGENT);
            int rv = __hip_atomic_fetch_add(bar, 1, __ATOMIC_ACQ_REL,
                                            __HIP_MEMORY_SCOPE_AGENT);
            if (rv == 31) {
                __hip_atomic_store(bar, 0, __ATOMIC_RELAXED,
                                   __HIP_MEMORY_SCOPE_AGENT);
                __hip_atomic_fetch_add(gen, 1, __ATOMIC_RELEASE,
                                       __HIP_MEMORY_SCOPE_AGENT);
            }
        }
        while (__hip_atomic_load(gen, __ATOMIC_ACQUIRE,
                                 __HIP_MEMORY_SCOPE_AGENT) == g)
            __builtin_amdgcn_s_sleep(1);
    }
    __syncthreads();
}

// ---------------------------------------------------------------------------
// Phase A: fp32 -> bf16 (x, mem, fc_w) and fp32 -> f16 (p2w, p1w).
// ---------------------------------------------------------------------------
#define X4   (B_ * D_ / 4)
#define MEM4 (C_ * D_ / 4)
#define W4   (TWOD * TWOD / 4)
#define P24  (P_ * TWOD / 4)
#define P14  (TWOD / 4)
#define TOT4 (X4 + MEM4 + W4 + P24 + P14)

__device__ __forceinline__ void phase_cvt(
    const float* __restrict__ x, const float* __restrict__ mem,
    const float* __restrict__ w, const float* __restrict__ p2w,
    const float* __restrict__ p1w,
    ushort* __restrict__ xb, ushort* __restrict__ memb,
    ushort* __restrict__ wb, ushort* __restrict__ p2h,
    ushort* __restrict__ p1h)
{
    for (int i = blockIdx.x * 256 + threadIdx.x; i < TOT4; i += NBLK * 256) {
        const float* src; ushort* dst; int off; bool bf;
        if (i < X4)                        { src = x;   dst = xb;   off = i; bf = true; }
        else if (i < X4 + MEM4)            { src = mem; dst = memb; off = i - X4; bf = true; }
        else if (i < X4 + MEM4 + W4)       { src = w;   dst = wb;   off = i - X4 - MEM4; bf = true; }
        else if (i < X4 + MEM4 + W4 + P24) { src = p2w; dst = p2h;  off = i - X4 - MEM4 - W4; bf = false; }
        else                               { src = p1w; dst = p1h;  off = i - X4 - MEM4 - W4 - P24; bf = false; }
        float4 v = ((const float4*)src)[off];
        ushort4 o;
        if (bf) { o.x = f2bf(v.x); o.y = f2bf(v.y); o.z = f2bf(v.z); o.w = f2bf(v.w); }
        else    { o.x = f2h(v.x);  o.y = f2h(v.y);  o.z = f2h(v.z);  o.w = f2h(v.w); }
        ((ushort4*)dst)[off] = o;
    }
}

// ---------------------------------------------------------------------------
// Phase B: merged MFMA GEMM. tasks [0,192): xh = x @ Wx^T + fc_b ;
// tasks [192,228): mh = mem @ Wm^T. 64x128 tile, BK=32, 4 waves.
// ---------------------------------------------------------------------------
__device__ __forceinline__ void phase_gemm(
    int id, char* smemc,
    const ushort* __restrict__ xbf, const ushort* __restrict__ membf,
    const ushort* __restrict__ wbf, const float* __restrict__ fc_b,
    ushort* __restrict__ xh, ushort* __restrict__ mh)
{
    if (id >= 228) return;
    ushort* As = (ushort*)smemc;                    // 64 x ASTR
    ushort* Bs = (ushort*)(smemc + 64 * ASTR * 2);  // 128 x ASTR
    const int t = threadIdx.x;

    const ushort* A; ushort* Out; int M, m0, n0, koff; bool xblk;
    if (id < 192) {
        xblk = true;  A = xbf;  Out = xh; M = B_;
        m0 = (id & 15) * 64; n0 = (id >> 4) * 128; koff = 0;
    } else {
        int q = id - 192;
        xblk = false; A = membf; Out = mh; M = C_;
        m0 = (q % 3) * 64; n0 = (q / 3) * 128; koff = D_;
    }

    const int wave = t >> 6, lane = t & 63;
    const int wm = (wave & 1) * 32, wn = (wave >> 1) * 64;
    const int fm = lane & 15, quad = lane >> 4;

    const int row_a = t >> 2, qa = (t & 3) * 8;
    const int ar = min(m0 + row_a, M - 1);
    const ushort* Arow = A + (size_t)ar * D_ + qa;
    const ushort* Brow = wbf + (size_t)(n0 + row_a) * TWOD + koff + qa;

    f32x4 acc[2][4];
#pragma unroll
    for (int j = 0; j < 4; ++j) {
        float bv = xblk ? fc_b[n0 + wn + j * 16 + fm] : 0.f;
#pragma unroll
        for (int i = 0; i < 2; ++i)
            acc[i][j] = (f32x4){bv, bv, bv, bv};
    }

    uint4 pa  = *(const uint4*)(Arow);
    uint4 pb0 = *(const uint4*)(Brow);
    uint4 pb1 = *(const uint4*)(Brow + 64 * TWOD);

    for (int k0 = 0; k0 < D_; k0 += 32) {
        __syncthreads();
        *(uint4*)&As[row_a * ASTR + qa] = pa;
        *(uint4*)&Bs[row_a * ASTR + qa] = pb0;
        *(uint4*)&Bs[(64 + row_a) * ASTR + qa] = pb1;
        __syncthreads();
        if (k0 + 32 < D_) {
            pa  = *(const uint4*)(Arow + k0 + 32);
            pb0 = *(const uint4*)(Brow + k0 + 32);
            pb1 = *(const uint4*)(Brow + 64 * TWOD + k0 + 32);
        }
        bfx8 af[2], bff[4];
#pragma unroll
        for (int i = 0; i < 2; ++i)
            af[i] = *(const bfx8*)&As[(wm + i * 16 + fm) * ASTR + quad * 8];
#pragma unroll
        for (int j = 0; j < 4; ++j)
            bff[j] = *(const bfx8*)&Bs[(wn + j * 16 + fm) * ASTR + quad * 8];
#pragma unroll
        for (int i = 0; i < 2; ++i)
#pragma unroll
            for (int j = 0; j < 4; ++j)
                acc[i][j] = __builtin_amdgcn_mfma_f32_16x16x32_bf16(
                    af[i], bff[j], acc[i][j], 0, 0, 0);
    }

#pragma unroll
    for (int i = 0; i < 2; ++i)
#pragma unroll
        for (int j = 0; j < 4; ++j)
#pragma unroll
            for (int r = 0; r < 4; ++r) {
                int row = m0 + wm + i * 16 + quad * 4 + r;
                int col = n0 + wn + j * 16 + fm;
                if (row < M) Out[(size_t)row * TWOD + col] = f2h(acc[i][j][r]);
            }
}

// ---------------------------------------------------------------------------
// Phase C: fused tile. y<3: elementwise partial[z][b][c] = sum relu(xh+m)*p1
// y==3: MFMA f16 u-projection partial[z][b][192+n] = sum relu(xh)*p2.
// ---------------------------------------------------------------------------
__device__ __forceinline__ void phase_fused(
    int id, char* smem,
    const ushort* __restrict__ xh, const ushort* __restrict__ mh,
    const ushort* __restrict__ p1h, const ushort* __restrict__ p2h,
    float* __restrict__ partial)
{
    const int t  = threadIdx.x;
    const int b0 = (id & 7) * 128;
    const int y  = (id >> 3) & 3;
    const int z  = id >> 5;
    const int e0 = z * ECHUNK;

    if (y == 3) {
        // -------- MFMA f16 u-projection path --------
        ushort* Au = (ushort*)smem;                 // 128 x USTRU halves
        ushort* Wu = (ushort*)(smem + 30720);       // 64 x USTRU halves
        const int wave = t >> 6, lane = t & 63;
        const int fm = lane & 15, quad = lane >> 4;

        {   // stage relu(xh) f16 : 128 rows x 96 k
            const int row = t >> 1, kh = (t & 1) * 48;
            const ushort* src = xh + (size_t)(b0 + row) * TWOD + e0 + kh;
            uint4 v[6];
#pragma unroll
            for (int i = 0; i < 6; ++i) v[i] = *(const uint4*)&src[i * 8];
#pragma unroll
            for (int i = 0; i < 6; ++i) {
                v[i].x = relu2(v[i].x); v[i].y = relu2(v[i].y);
                v[i].z = relu2(v[i].z); v[i].w = relu2(v[i].w);
                *(uint4*)&Au[row * USTRU + kh + i * 8] = v[i];
            }
        }
        {   // stage p2 f16 : 64 rows x 96 k
            const int row = t >> 2, ks = (t & 3) * 24;
            const ushort* pw = p2h + (size_t)row * TWOD + e0 + ks;
#pragma unroll
            for (int i = 0; i < 3; ++i)
                *(uint4*)&Wu[row * USTRU + ks + i * 8] = *(const uint4*)&pw[i * 8];
        }
        __syncthreads();

        f32x4 uacc[2][4];
#pragma unroll
        for (int i = 0; i < 2; ++i)
#pragma unroll
            for (int j = 0; j < 4; ++j) uacc[i][j] = (f32x4){0.f, 0.f, 0.f, 0.f};
#pragma unroll
        for (int k0 = 0; k0 < ECHUNK; k0 += 32) {
            fp16x8 af[2], bff[4];
#pragma unroll
            for (int i = 0; i < 2; ++i)
                af[i] = *(const fp16x8*)&Au[(wave * 32 + i * 16 + fm) * USTRU + k0 + quad * 8];
#pragma unroll
            for (int j = 0; j < 4; ++j)
                bff[j] = *(const fp16x8*)&Wu[(j * 16 + fm) * USTRU + k0 + quad * 8];
#pragma unroll
            for (int i = 0; i < 2; ++i)
#pragma unroll
                for (int j = 0; j < 4; ++j)
                    uacc[i][j] = __builtin_amdgcn_mfma_f32_16x16x32_f16(
                        af[i], bff[j], uacc[i][j], 0, 0, 0);
        }
#pragma unroll
        for (int i = 0; i < 2; ++i)
#pragma unroll
            for (int j = 0; j < 4; ++j)
#pragma unroll
                for (int r = 0; r < 4; ++r) {
                    int row = b0 + wave * 32 + i * 16 + quad * 4 + r;
                    partial[((size_t)z * B_ + row) * CPAD + 192 + j * 16 + fm] =
                        uacc[i][j][r];
                }
        return;
    }

    // -------- elementwise f16 path: cols c0..c0+63 (c0 in {0,64,128}) -----
    unsigned* xT = (unsigned*)smem;             // [48 e-pairs][128 b]
    unsigned* mT = (unsigned*)(smem + 24576);   // [48][64 c]
    unsigned* wT = (unsigned*)(smem + 36864);   // [48]
    const int c0 = y * 64;
    const int tm = t & 15, tn = t >> 4;

    {   // stage x: 2 thr/row, 48 halves each
        const int row = t >> 1, ph = (t & 1) * 48;
        const ushort* src = xh + (size_t)(b0 + row) * TWOD + e0 + ph;
        uint4 v[6];
#pragma unroll
        for (int i = 0; i < 6; ++i) v[i] = *(const uint4*)&src[i * 8];
#pragma unroll
        for (int i = 0; i < 6; ++i) {
            const int ep = (t & 1) * 24 + i * 4;
            xT[(ep + 0) * 128 + row] = v[i].x;
            xT[(ep + 1) * 128 + row] = v[i].y;
            xT[(ep + 2) * 128 + row] = v[i].z;
            xT[(ep + 3) * 128 + row] = v[i].w;
        }
    }
    {   // stage m: 4 thr/col, 24 halves each
        const int col = t & 63, seg = t >> 6;
        const int gc  = c0 + col;
        uint4 v[3];
        if (gc < C_) {
            const ushort* src = mh + (size_t)gc * TWOD + e0 + seg * 24;
#pragma unroll
            for (int i = 0; i < 3; ++i) v[i] = *(const uint4*)&src[i * 8];
        } else {
#pragma unroll
            for (int i = 0; i < 3; ++i) v[i] = make_uint4(0, 0, 0, 0);
        }
#pragma unroll
        for (int i = 0; i < 3; ++i) {
            const int ep = seg * 12 + i * 4;
            mT[(ep + 0) * 64 + col] = v[i].x;
            mT[(ep + 1) * 64 + col] = v[i].y;
            mT[(ep + 2) * 64 + col] = v[i].z;
            mT[(ep + 3) * 64 + col] = v[i].w;
        }
    }
    if (t < 12) {  // stage w (p1): 96 halves
        uint4 v = *(const uint4*)&p1h[e0 + t * 8];
        wT[t * 4 + 0] = v.x; wT[t * 4 + 1] = v.y;
        wT[t * 4 + 2] = v.z; wT[t * 4 + 3] = v.w;
    }
    __syncthreads();

    float acc[8][4] = {};
#pragma unroll 4
    for (int ep = 0; ep < 48; ++ep) {
        uint4 a0 = *(const uint4*)&xT[ep * 128 + tm * 8];
        uint4 a1 = *(const uint4*)&xT[ep * 128 + tm * 8 + 4];
        uint4 mj = *(const uint4*)&mT[ep * 64 + tn * 4];
        const unsigned wv = wT[ep];
        const unsigned aa[8] = {a0.x, a0.y, a0.z, a0.w, a1.x, a1.y, a1.z, a1.w};
        const unsigned mm[4] = {mj.x, mj.y, mj.z, mj.w};
#pragma unroll
        for (int i = 0; i < 8; ++i)
#pragma unroll
            for (int j = 0; j < 4; ++j)
                acc[i][j] = dot2acc(addrelu2(aa[i], mm[j]), wv, acc[i][j]);
    }

#pragma unroll
    for (int i = 0; i < 8; ++i) {
        const int gb = b0 + tm * 8 + i;
        float4 v = make_float4(acc[i][0], acc[i][1], acc[i][2], acc[i][3]);
        *(float4*)&partial[((size_t)z * B_ + gb) * CPAD + c0 + tn * 4] = v;
    }
}

// ---------------------------------------------------------------------------
// Phase D: per-row reduce of partials + bias, u-normalize (f16) + cls loss.
// 512 blocks x 2 rows each.
// ---------------------------------------------------------------------------
__device__ __forceinline__ void phase_reduce(
    char* smemc,
    const float* __restrict__ partial,
    const float* __restrict__ p1b, const float* __restrict__ p2b,
    const int* __restrict__ lb,
    ushort* __restrict__ uhf, float* __restrict__ sqn,
    float* __restrict__ clsbuf)
{
    float* sval = (float*)smemc;
    const int t = threadIdx.x;
    for (int b = blockIdx.x; b < B_; b += NBLK) {
        float v = 0.f;
#pragma unroll
        for (int z = 0; z < ECHUNKS; ++z)
            v += partial[((size_t)z * B_ + b) * CPAD + t];
        if (t < NCLS)       v += p1b[0];
        else if (t >= 192)  v += p2b[t - 192];

        sval[t] = v;
        __syncthreads();

        if (t < 64) {
            float uv = sval[192 + t];
            float s = uv * uv;
#pragma unroll
            for (int off = 32; off; off >>= 1) s += __shfl_xor(s, off);
            float inv = 1.f / fmaxf(sqrtf(s), 1e-12f);
            uhf[(size_t)b * P_ + t] = f2h(uv * inv);
            if (t == 0) sqn[b] = s * inv * inv;

            const int l = lb[b];
            float mx = -1e30f;
            for (int j = t; j < NCLS; j += 64)
                if (!(j == l && l < C_)) mx = fmaxf(mx, sval[j]);
#pragma unroll
            for (int off = 32; off; off >>= 1) mx = fmaxf(mx, __shfl_xor(mx, off));
            float se = 0.f;
            for (int j = t; j < NCLS; j += 64)
                if (!(j == l && l < C_)) se += expf(sval[j] - mx);
#pragma unroll
            for (int off = 32; off; off >>= 1) se += __shfl_xor(se, off);

            if (t == 0) {
                float l150  = sval[C_];
                float loss2 = mx + logf(se) - l150;
                float loss1 = 0.f;
                if (l < C_) {
                    float a  = sval[l];
                    float m2 = fmaxf(a, l150);
                    loss1 = m2 - a + logf(expf(a - m2) + expf(l150 - m2));
                }
                clsbuf[b] = loss1 + loss2;
            }
        }
        __syncthreads();
    }
}

// ---------------------------------------------------------------------------
// Phase E: pairwise margin losses via f16 MFMA Gram tiles. 256 tasks.
// ---------------------------------------------------------------------------
__device__ __forceinline__ void phase_pair(
    int id, char* smemc,
    const ushort* __restrict__ uhf, const float* __restrict__ sqn,
    const int* __restrict__ lb, float* __restrict__ pairpart)
{
    if (id >= 256) return;
    ushort* ui_s = (ushort*)smemc;               // 64*USTR halves = 9216 B
    ushort* uj_s = (ushort*)(smemc + 9216);      // 9216 B
    float*  sni  = (float*)(smemc + 18432);
    float*  snj  = (float*)(smemc + 18688);
    int*    li   = (int*)(smemc + 18944);
    int*    lj   = (int*)(smemc + 19200);
    float*  red  = (float*)(smemc + 19456);      // [4][4]

    const int t  = threadIdx.x;
    const int i0 = (id & 15) * 64, j0 = (id >> 4) * 64;

    for (int idx = t; idx < 512; idx += 256) {
        int row = idx >> 3, ch = (idx & 7) * 8;
        *(uint4*)&ui_s[row * USTR + ch] =
            *(const uint4*)&uhf[(size_t)(i0 + row) * P_ + ch];
        *(uint4*)&uj_s[row * USTR + ch] =
            *(const uint4*)&uhf[(size_t)(j0 + row) * P_ + ch];
    }
    if (t < 64)       { sni[t] = sqn[i0 + t]; li[t] = lb[i0 + t]; }
    else if (t < 128) { int q = t - 64; snj[q] = sqn[j0 + q]; lj[q] = lb[j0 + q]; }
    __syncthreads();

    const int wave = t >> 6, lane = t & 63;
    const int n = lane & 15, quad = lane >> 4;
    const int iw = wave * 16;

    const fp16x8 af0 = *(const fp16x8*)&ui_s[(iw + n) * USTR + quad * 8];
    const fp16x8 af1 = *(const fp16x8*)&ui_s[(iw + n) * USTR + quad * 8 + 32];

    f32x4 acc[4];
#pragma unroll
    for (int jt = 0; jt < 4; ++jt) {
        const fp16x8 bf0 = *(const fp16x8*)&uj_s[(jt * 16 + n) * USTR + quad * 8];
        const fp16x8 bf1 = *(const fp16x8*)&uj_s[(jt * 16 + n) * USTR + quad * 8 + 32];
        acc[jt] = __builtin_amdgcn_mfma_f32_16x16x32_f16(
            af0, bf0, (f32x4){0.f, 0.f, 0.f, 0.f}, 0, 0, 0);
        acc[jt] = __builtin_amdgcn_mfma_f32_16x16x32_f16(
            af1, bf1, acc[jt], 0, 0, 0);
    }

    float ps = 0.f, pc = 0.f, ns = 0.f, nc = 0.f;
#pragma unroll
    for (int jt = 0; jt < 4; ++jt)
#pragma unroll
        for (int r = 0; r < 4; ++r) {
            const int il = iw + quad * 4 + r;
            const int jl = jt * 16 + n;
            float sq = sni[il] + snj[jl] - 2.f * acc[jt][r];
            float dist = sq > 0.f ? sqrtf(fmaxf(sq, 1e-16f)) : 0.f;
            bool same = (li[il] == lj[jl]);
            if (same) {
                if (i0 + il != j0 + jl) { ps += fmaxf(dist - 0.7f, 0.f); pc += 1.f; }
            } else {
                ns += fmaxf(1.4f - dist, 0.f); nc += 1.f;
            }
        }

#pragma unroll
    for (int off = 32; off; off >>= 1) {
        ps += __shfl_xor(ps, off); pc += __shfl_xor(pc, off);
        ns += __shfl_xor(ns, off); nc += __shfl_xor(nc, off);
    }
    if (lane == 0) { red[0 * 4 + wave] = ps; red[1 * 4 + wave] = pc;
                     red[2 * 4 + wave] = ns; red[3 * 4 + wave] = nc; }
    __syncthreads();
    if (t == 0) {
        float4 v;
        v.x = red[0] + red[1] + red[2] + red[3];
        v.y = red[4] + red[5] + red[6] + red[7];
        v.z = red[8] + red[9] + red[10] + red[11];
        v.w = red[12] + red[13] + red[14] + red[15];
        *(float4*)&pairpart[(size_t)id * 4] = v;
    }
}

// ---------------------------------------------------------------------------
// Phase F: block 0 reduces clsbuf[1024] and pairpart[256][4] -> out[0].
// ---------------------------------------------------------------------------
__device__ __forceinline__ void phase_final(
    char* smemc,
    const float* __restrict__ clsbuf, const float* __restrict__ pairpart,
    float* __restrict__ out)
{
    if (blockIdx.x != 0) return;
    float* red = (float*)smemc;   // [5][4]
    const int t = threadIdx.x;
    float c = clsbuf[t] + clsbuf[t + 256] + clsbuf[t + 512] + clsbuf[t + 768];
    float4 pp = *(const float4*)&pairpart[(size_t)t * 4];
    float ps = pp.x, pc = pp.y, ns = pp.z, nc = pp.w;
#pragma unroll
    for (int off = 32; off; off >>= 1) {
        c  += __shfl_xor(c, off);
        ps += __shfl_xor(ps, off); pc += __shfl_xor(pc, off);
        ns += __shfl_xor(ns, off); nc += __shfl_xor(nc, off);
    }
    const int wave = t >> 6, lane = t & 63;
    if (lane == 0) { red[0 * 4 + wave] = c; red[1 * 4 + wave] = ps;
                     red[2 * 4 + wave] = pc; red[3 * 4 + wave] = ns;
                     red[4 * 4 + wave] = nc; }
    __syncthreads();
    if (t == 0) {
        float C = 0.f, PS = 0.f, PC = 0.f, NS = 0.f, NC = 0.f;
#pragma unroll
        for (int w = 0; w < 4; ++w) {
            C += red[0 * 4 + w]; PS += red[1 * 4 + w]; PC += red[2 * 4 + w];
            NS += red[3 * 4 + w]; NC += red[4 * 4 + w];
        }
        out[0] = C / (float)B_ + PS / fmaxf(PC, 1.f) + NS / fmaxf(NC, 1.f);
    }
}

// ---------------------------------------------------------------------------
// Persistent mega-kernel: 512 blocks x 256 threads, 2 blocks/CU co-resident
// (LDS 46080 B -> 3/CU cap; launch_bounds(256,2) caps VGPR for 2/CU).
// ---------------------------------------------------------------------------
__global__ __launch_bounds__(256, 2) void mega(
    const float* __restrict__ x, const int* __restrict__ lb,
    const float* __restrict__ mem, const float* __restrict__ fc_w,
    const float* __restrict__ fc_b, const float* __restrict__ p1w,
    const float* __restrict__ p1b, const float* __restrict__ p2w,
    const float* __restrict__ p2b,
    float* ws, float* out)
{
    __shared__ __align__(16) char smem[46080];

    ushort* mh       = (ushort*)(ws + OFF_MH);
    ushort* xh       = (ushort*)(ws + OFF_XH);
    float*  partial  = ws + OFF_PARTIAL;
    ushort* uhf      = (ushort*)(ws + OFF_UHF);
    float*  sqn      = ws + OFF_SQN;
    float*  clsbuf   = ws + OFF_CLS;
    float*  pairpart = ws + OFF_PAIR;
    ushort* xbf      = (ushort*)(ws + OFF_XBF);
    ushort* membf    = (ushort*)(ws + OFF_MEMBF);
    ushort* wbf      = (ushort*)(ws + OFF_WBF);
    ushort* p2h      = (ushort*)(ws + OFF_P2H);
    ushort* p1h      = (ushort*)(ws + OFF_P1H);
    int*    bar      = (int*)(ws + OFF_BAR);

    const int id = blockIdx.x;

    phase_cvt(x, mem, fc_w, p2w, p1w, xbf, membf, wbf, p2h, p1h);
    grid_barrier(bar);
    phase_gemm(id, smem, xbf, membf, wbf, fc_b, xh, mh);
    grid_barrier(bar);
    phase_fused(id, smem, xh, mh, p1h, p2h, partial);
    grid_barrier(bar);
    phase_reduce(smem, partial, p1b, p2b, lb, uhf, sqn, clsbuf);
    grid_barrier(bar);
    phase_pair(id, smem, uhf, sqn, lb, pairpart);
    grid_barrier(bar);
    phase_final(smem, clsbuf, pairpart, out);
}

extern "C" void kernel_launch(void* const* d_in, const int* in_sizes, int n_in,
                              void* d_out, int out_size, void* d_ws, size_t ws_size,
                              hipStream_t stream)
{
    const float* x    = (const float*)d_in[0];
    const int*   lb   = (const int*)d_in[1];
    const float* mem  = (const float*)d_in[2];
    const float* fc_w = (const float*)d_in[3];
    const float* fc_b = (const float*)d_in[4];
    const float* p1w  = (const float*)d_in[5];
    const float* p1b  = (const float*)d_in[6];
    const float* p2w  = (const float*)d_in[7];
    const float* p2b  = (const float*)d_in[8];

    float* ws  = (float*)d_ws;
    int*   bar = (int*)(ws + OFF_BAR);

    // Zero barrier state (root cnt, gen, 32 group counters) — captured node.
    hipMemsetAsync(bar, 0, 4096, stream);

    mega<<<NBLK, 256, 0, stream>>>(x, lb, mem, fc_w, fc_b,
                                   p1w, p1b, p2w, p2b, ws, (float*)d_out);
}

// Round 2
// 244.752 us; speedup vs baseline: 1.6379x; 1.6379x over previous
//
#include <hip/hip_runtime.h>
#include <math.h>

// Problem constants
#define B_    1024
#define D_    768
#define C_    150
#define P_    64
#define TWOD  1536
#define NCLS  151   // C+1
#define CPAD  256   // partial row: 0..150 logits, 151..191 junk, 192..255 u

// fused_tile: 128b x 64c per block, 8x4/thr, e split 16 ways
#define ECHUNKS 16
#define ECHUNK  96

// gemm: 64x128 tile, BK=32, bf16 LDS stride 40
#define ASTR  40
// u-path LDS stride (halves)
#define USTRU 120
// pair phase LDS stride (halves)
#define USTR  72

// persistent grid
#define NBLK  512

// Workspace layout (float offsets)
#define OFF_MH      0
#define OFF_XH      (OFF_MH + (C_ * TWOD) / 2)
#define OFF_PARTIAL (OFF_XH + (B_ * TWOD) / 2)
#define OFF_UHF     (OFF_PARTIAL + ECHUNKS * B_ * CPAD)
#define OFF_SQN     (OFF_UHF + (B_ * P_) / 2)
#define OFF_CLS     (OFF_SQN + B_)
#define OFF_PAIR    (OFF_CLS + B_)
#define OFF_XBF     (OFF_PAIR + 1024)
#define OFF_MEMBF   (OFF_XBF + (B_ * D_) / 2)
#define OFF_WBF     (OFF_MEMBF + (C_ * D_) / 2)
#define OFF_P2H     (OFF_WBF + (TWOD * TWOD) / 2)
#define OFF_P1H     (OFF_P2H + (P_ * TWOD) / 2)
#define OFF_BAR     (OFF_P1H + TWOD / 2)   // int[528]: root cnt, gen, 32 group ctrs

typedef __bf16    bfx8   __attribute__((ext_vector_type(8)));
typedef _Float16  fp16x8 __attribute__((ext_vector_type(8)));
typedef _Float16  h2v    __attribute__((ext_vector_type(2)));
typedef float     f32x4  __attribute__((ext_vector_type(4)));

__device__ inline ushort f2bf(float f) {
    union { float f; unsigned u; } c; c.f = f;
    unsigned r = c.u + 0x7fffu + ((c.u >> 16) & 1u);
    return (ushort)(r >> 16);
}
__device__ inline ushort f2h(float f) {
    _Float16 h = (_Float16)f;
    return __builtin_bit_cast(ushort, h);
}
__device__ inline unsigned addrelu2(unsigned a, unsigned m) {
    h2v s = __builtin_bit_cast(h2v, a) + __builtin_bit_cast(h2v, m);
    h2v z = {(_Float16)0.f, (_Float16)0.f};
    s = __builtin_elementwise_max(s, z);
    return __builtin_bit_cast(unsigned, s);
}
__device__ inline unsigned relu2(unsigned a) {
    h2v s = __builtin_bit_cast(h2v, a);
    h2v z = {(_Float16)0.f, (_Float16)0.f};
    s = __builtin_elementwise_max(s, z);
    return __builtin_bit_cast(unsigned, s);
}
__device__ inline float dot2acc(unsigned a, unsigned b, float c) {
    return __builtin_amdgcn_fdot2(__builtin_bit_cast(h2v, a),
                                  __builtin_bit_cast(h2v, b), c, false);
}

// ---------------------------------------------------------------------------
// Two-level grid barrier, v2 (storm-free).
// v1 bug: the spin loop used ACQUIRE agent loads -> one buffer_inv (L1+L2
// invalidate) PER POLL per spinner -> L2 controllers saturated with cache-
// maintenance ops (~60us/barrier, chip idle). v2: spin with RELAXED loads
// (no cache ops), exactly ONE acquire fence after exit. Release chain:
// member gcnt add (ACQ_REL) -> group winner root add (ACQ_REL) -> root
// winner gen add (RELEASE); spinner's relaxed read of the released value +
// acquire fence synchronizes transitively (RMW release sequences).
// ---------------------------------------------------------------------------
__device__ __forceinline__ void grid_barrier(int* bar)
{
    __syncthreads();
    if (threadIdx.x == 0) {
        int* gen  = bar + 1;
        int* gcnt = bar + 16 + (blockIdx.x >> 4) * 16;   // 64B-spaced groups
        const int g = __hip_atomic_load(gen, __ATOMIC_RELAXED,
                                        __HIP_MEMORY_SCOPE_AGENT);
        int gv = __hip_atomic_fetch_add(gcnt, 1, __ATOMIC_ACQ_REL,
                                        __HIP_MEMORY_SCOPE_AGENT);
        if (gv == 15) {
            __hip_atomic_store(gcnt, 0, __ATOMIC_RELAXED,
                               __HIP_MEMORY_SCOPE_AGENT);
            int rv = __hip_atomic_fetch_add(bar, 1, __ATOMIC_ACQ_REL,
                                            __HIP_MEMORY_SCOPE_AGENT);
            if (rv == 31) {
                __hip_atomic_store(bar, 0, __ATOMIC_RELAXED,
                                   __HIP_MEMORY_SCOPE_AGENT);
                __hip_atomic_fetch_add(gen, 1, __ATOMIC_RELEASE,
                                       __HIP_MEMORY_SCOPE_AGENT);
            }
        }
        while (__hip_atomic_load(gen, __ATOMIC_RELAXED,
                                 __HIP_MEMORY_SCOPE_AGENT) == g)
            __builtin_amdgcn_s_sleep(8);
        __builtin_amdgcn_fence(__ATOMIC_ACQUIRE, "agent");  // ONE inv, not per-poll
    }
    __syncthreads();
}

// ---------------------------------------------------------------------------
// Phase A: fp32 -> bf16 (x, mem, fc_w) and fp32 -> f16 (p2w, p1w).
// ---------------------------------------------------------------------------
#define X4   (B_ * D_ / 4)
#define MEM4 (C_ * D_ / 4)
#define W4   (TWOD * TWOD / 4)
#define P24  (P_ * TWOD / 4)
#define P14  (TWOD / 4)
#define TOT4 (X4 + MEM4 + W4 + P24 + P14)

__device__ __forceinline__ void phase_cvt(
    const float* __restrict__ x, const float* __restrict__ mem,
    const float* __restrict__ w, const float* __restrict__ p2w,
    const float* __restrict__ p1w,
    ushort* __restrict__ xb, ushort* __restrict__ memb,
    ushort* __restrict__ wb, ushort* __restrict__ p2h,
    ushort* __restrict__ p1h)
{
    for (int i = blockIdx.x * 256 + threadIdx.x; i < TOT4; i += NBLK * 256) {
        const float* src; ushort* dst; int off; bool bf;
        if (i < X4)                        { src = x;   dst = xb;   off = i; bf = true; }
        else if (i < X4 + MEM4)            { src = mem; dst = memb; off = i - X4; bf = true; }
        else if (i < X4 + MEM4 + W4)       { src = w;   dst = wb;   off = i - X4 - MEM4; bf = true; }
        else if (i < X4 + MEM4 + W4 + P24) { src = p2w; dst = p2h;  off = i - X4 - MEM4 - W4; bf = false; }
        else                               { src = p1w; dst = p1h;  off = i - X4 - MEM4 - W4 - P24; bf = false; }
        float4 v = ((const float4*)src)[off];
        ushort4 o;
        if (bf) { o.x = f2bf(v.x); o.y = f2bf(v.y); o.z = f2bf(v.z); o.w = f2bf(v.w); }
        else    { o.x = f2h(v.x);  o.y = f2h(v.y);  o.z = f2h(v.z);  o.w = f2h(v.w); }
        ((ushort4*)dst)[off] = o;
    }
}

// ---------------------------------------------------------------------------
// Phase B: merged MFMA GEMM. tasks [0,192): xh = x @ Wx^T + fc_b ;
// tasks [192,228): mh = mem @ Wm^T. 64x128 tile, BK=32, 4 waves.
// ---------------------------------------------------------------------------
__device__ __forceinline__ void phase_gemm(
    int id, char* smemc,
    const ushort* __restrict__ xbf, const ushort* __restrict__ membf,
    const ushort* __restrict__ wbf, const float* __restrict__ fc_b,
    ushort* __restrict__ xh, ushort* __restrict__ mh)
{
    if (id >= 228) return;
    ushort* As = (ushort*)smemc;                    // 64 x ASTR
    ushort* Bs = (ushort*)(smemc + 64 * ASTR * 2);  // 128 x ASTR
    const int t = threadIdx.x;

    const ushort* A; ushort* Out; int M, m0, n0, koff; bool xblk;
    if (id < 192) {
        xblk = true;  A = xbf;  Out = xh; M = B_;
        m0 = (id & 15) * 64; n0 = (id >> 4) * 128; koff = 0;
    } else {
        int q = id - 192;
        xblk = false; A = membf; Out = mh; M = C_;
        m0 = (q % 3) * 64; n0 = (q / 3) * 128; koff = D_;
    }

    const int wave = t >> 6, lane = t & 63;
    const int wm = (wave & 1) * 32, wn = (wave >> 1) * 64;
    const int fm = lane & 15, quad = lane >> 4;

    const int row_a = t >> 2, qa = (t & 3) * 8;
    const int ar = min(m0 + row_a, M - 1);
    const ushort* Arow = A + (size_t)ar * D_ + qa;
    const ushort* Brow = wbf + (size_t)(n0 + row_a) * TWOD + koff + qa;

    f32x4 acc[2][4];
#pragma unroll
    for (int j = 0; j < 4; ++j) {
        float bv = xblk ? fc_b[n0 + wn + j * 16 + fm] : 0.f;
#pragma unroll
        for (int i = 0; i < 2; ++i)
            acc[i][j] = (f32x4){bv, bv, bv, bv};
    }

    uint4 pa  = *(const uint4*)(Arow);
    uint4 pb0 = *(const uint4*)(Brow);
    uint4 pb1 = *(const uint4*)(Brow + 64 * TWOD);

    for (int k0 = 0; k0 < D_; k0 += 32) {
        __syncthreads();
        *(uint4*)&As[row_a * ASTR + qa] = pa;
        *(uint4*)&Bs[row_a * ASTR + qa] = pb0;
        *(uint4*)&Bs[(64 + row_a) * ASTR + qa] = pb1;
        __syncthreads();
        if (k0 + 32 < D_) {
            pa  = *(const uint4*)(Arow + k0 + 32);
            pb0 = *(const uint4*)(Brow + k0 + 32);
            pb1 = *(const uint4*)(Brow + 64 * TWOD + k0 + 32);
        }
        bfx8 af[2], bff[4];
#pragma unroll
        for (int i = 0; i < 2; ++i)
            af[i] = *(const bfx8*)&As[(wm + i * 16 + fm) * ASTR + quad * 8];
#pragma unroll
        for (int j = 0; j < 4; ++j)
            bff[j] = *(const bfx8*)&Bs[(wn + j * 16 + fm) * ASTR + quad * 8];
#pragma unroll
        for (int i = 0; i < 2; ++i)
#pragma unroll
            for (int j = 0; j < 4; ++j)
                acc[i][j] = __builtin_amdgcn_mfma_f32_16x16x32_bf16(
                    af[i], bff[j], acc[i][j], 0, 0, 0);
    }

#pragma unroll
    for (int i = 0; i < 2; ++i)
#pragma unroll
        for (int j = 0; j < 4; ++j)
#pragma unroll
            for (int r = 0; r < 4; ++r) {
                int row = m0 + wm + i * 16 + quad * 4 + r;
                int col = n0 + wn + j * 16 + fm;
                if (row < M) Out[(size_t)row * TWOD + col] = f2h(acc[i][j][r]);
            }
}

// ---------------------------------------------------------------------------
// Phase C: fused tile. y<3: elementwise partial[z][b][c] = sum relu(xh+m)*p1
// y==3: MFMA f16 u-projection partial[z][b][192+n] = sum relu(xh)*p2.
// ---------------------------------------------------------------------------
__device__ __forceinline__ void phase_fused(
    int id, char* smem,
    const ushort* __restrict__ xh, const ushort* __restrict__ mh,
    const ushort* __restrict__ p1h, const ushort* __restrict__ p2h,
    float* __restrict__ partial)
{
    const int t  = threadIdx.x;
    const int b0 = (id & 7) * 128;
    const int y  = (id >> 3) & 3;
    const int z  = id >> 5;
    const int e0 = z * ECHUNK;

    if (y == 3) {
        // -------- MFMA f16 u-projection path --------
        ushort* Au = (ushort*)smem;                 // 128 x USTRU halves
        ushort* Wu = (ushort*)(smem + 30720);       // 64 x USTRU halves
        const int wave = t >> 6, lane = t & 63;
        const int fm = lane & 15, quad = lane >> 4;

        {   // stage relu(xh) f16 : 128 rows x 96 k
            const int row = t >> 1, kh = (t & 1) * 48;
            const ushort* src = xh + (size_t)(b0 + row) * TWOD + e0 + kh;
            uint4 v[6];
#pragma unroll
            for (int i = 0; i < 6; ++i) v[i] = *(const uint4*)&src[i * 8];
#pragma unroll
            for (int i = 0; i < 6; ++i) {
                v[i].x = relu2(v[i].x); v[i].y = relu2(v[i].y);
                v[i].z = relu2(v[i].z); v[i].w = relu2(v[i].w);
                *(uint4*)&Au[row * USTRU + kh + i * 8] = v[i];
            }
        }
        {   // stage p2 f16 : 64 rows x 96 k
            const int row = t >> 2, ks = (t & 3) * 24;
            const ushort* pw = p2h + (size_t)row * TWOD + e0 + ks;
#pragma unroll
            for (int i = 0; i < 3; ++i)
                *(uint4*)&Wu[row * USTRU + ks + i * 8] = *(const uint4*)&pw[i * 8];
        }
        __syncthreads();

        f32x4 uacc[2][4];
#pragma unroll
        for (int i = 0; i < 2; ++i)
#pragma unroll
            for (int j = 0; j < 4; ++j) uacc[i][j] = (f32x4){0.f, 0.f, 0.f, 0.f};
#pragma unroll
        for (int k0 = 0; k0 < ECHUNK; k0 += 32) {
            fp16x8 af[2], bff[4];
#pragma unroll
            for (int i = 0; i < 2; ++i)
                af[i] = *(const fp16x8*)&Au[(wave * 32 + i * 16 + fm) * USTRU + k0 + quad * 8];
#pragma unroll
            for (int j = 0; j < 4; ++j)
                bff[j] = *(const fp16x8*)&Wu[(j * 16 + fm) * USTRU + k0 + quad * 8];
#pragma unroll
            for (int i = 0; i < 2; ++i)
#pragma unroll
                for (int j = 0; j < 4; ++j)
                    uacc[i][j] = __builtin_amdgcn_mfma_f32_16x16x32_f16(
                        af[i], bff[j], uacc[i][j], 0, 0, 0);
        }
#pragma unroll
        for (int i = 0; i < 2; ++i)
#pragma unroll
            for (int j = 0; j < 4; ++j)
#pragma unroll
                for (int r = 0; r < 4; ++r) {
                    int row = b0 + wave * 32 + i * 16 + quad * 4 + r;
                    partial[((size_t)z * B_ + row) * CPAD + 192 + j * 16 + fm] =
                        uacc[i][j][r];
                }
        return;
    }

    // -------- elementwise f16 path: cols c0..c0+63 (c0 in {0,64,128}) -----
    unsigned* xT = (unsigned*)smem;             // [48 e-pairs][128 b]
    unsigned* mT = (unsigned*)(smem + 24576);   // [48][64 c]
    unsigned* wT = (unsigned*)(smem + 36864);   // [48]
    const int c0 = y * 64;
    const int tm = t & 15, tn = t >> 4;

    {   // stage x: 2 thr/row, 48 halves each
        const int row = t >> 1, ph = (t & 1) * 48;
        const ushort* src = xh + (size_t)(b0 + row) * TWOD + e0 + ph;
        uint4 v[6];
#pragma unroll
        for (int i = 0; i < 6; ++i) v[i] = *(const uint4*)&src[i * 8];
#pragma unroll
        for (int i = 0; i < 6; ++i) {
            const int ep = (t & 1) * 24 + i * 4;
            xT[(ep + 0) * 128 + row] = v[i].x;
            xT[(ep + 1) * 128 + row] = v[i].y;
            xT[(ep + 2) * 128 + row] = v[i].z;
            xT[(ep + 3) * 128 + row] = v[i].w;
        }
    }
    {   // stage m: 4 thr/col, 24 halves each
        const int col = t & 63, seg = t >> 6;
        const int gc  = c0 + col;
        uint4 v[3];
        if (gc < C_) {
            const ushort* src = mh + (size_t)gc * TWOD + e0 + seg * 24;
#pragma unroll
            for (int i = 0; i < 3; ++i) v[i] = *(const uint4*)&src[i * 8];
        } else {
#pragma unroll
            for (int i = 0; i < 3; ++i) v[i] = make_uint4(0, 0, 0, 0);
        }
#pragma unroll
        for (int i = 0; i < 3; ++i) {
            const int ep = seg * 12 + i * 4;
            mT[(ep + 0) * 64 + col] = v[i].x;
            mT[(ep + 1) * 64 + col] = v[i].y;
            mT[(ep + 2) * 64 + col] = v[i].z;
            mT[(ep + 3) * 64 + col] = v[i].w;
        }
    }
    if (t < 12) {  // stage w (p1): 96 halves
        uint4 v = *(const uint4*)&p1h[e0 + t * 8];
        wT[t * 4 + 0] = v.x; wT[t * 4 + 1] = v.y;
        wT[t * 4 + 2] = v.z; wT[t * 4 + 3] = v.w;
    }
    __syncthreads();

    float acc[8][4] = {};
#pragma unroll 4
    for (int ep = 0; ep < 48; ++ep) {
        uint4 a0 = *(const uint4*)&xT[ep * 128 + tm * 8];
        uint4 a1 = *(const uint4*)&xT[ep * 128 + tm * 8 + 4];
        uint4 mj = *(const uint4*)&mT[ep * 64 + tn * 4];
        const unsigned wv = wT[ep];
        const unsigned aa[8] = {a0.x, a0.y, a0.z, a0.w, a1.x, a1.y, a1.z, a1.w};
        const unsigned mm[4] = {mj.x, mj.y, mj.z, mj.w};
#pragma unroll
        for (int i = 0; i < 8; ++i)
#pragma unroll
            for (int j = 0; j < 4; ++j)
                acc[i][j] = dot2acc(addrelu2(aa[i], mm[j]), wv, acc[i][j]);
    }

#pragma unroll
    for (int i = 0; i < 8; ++i) {
        const int gb = b0 + tm * 8 + i;
        float4 v = make_float4(acc[i][0], acc[i][1], acc[i][2], acc[i][3]);
        *(float4*)&partial[((size_t)z * B_ + gb) * CPAD + c0 + tn * 4] = v;
    }
}

// ---------------------------------------------------------------------------
// Phase D: per-row reduce of partials + bias, u-normalize (f16) + cls loss.
// 512 blocks x 2 rows each.
// ---------------------------------------------------------------------------
__device__ __forceinline__ void phase_reduce(
    char* smemc,
    const float* __restrict__ partial,
    const float* __restrict__ p1b, const float* __restrict__ p2b,
    const int* __restrict__ lb,
    ushort* __restrict__ uhf, float* __restrict__ sqn,
    float* __restrict__ clsbuf)
{
    float* sval = (float*)smemc;
    const int t = threadIdx.x;
    for (int b = blockIdx.x; b < B_; b += NBLK) {
        float v = 0.f;
#pragma unroll
        for (int z = 0; z < ECHUNKS; ++z)
            v += partial[((size_t)z * B_ + b) * CPAD + t];
        if (t < NCLS)       v += p1b[0];
        else if (t >= 192)  v += p2b[t - 192];

        sval[t] = v;
        __syncthreads();

        if (t < 64) {
            float uv = sval[192 + t];
            float s = uv * uv;
#pragma unroll
            for (int off = 32; off; off >>= 1) s += __shfl_xor(s, off);
            float inv = 1.f / fmaxf(sqrtf(s), 1e-12f);
            uhf[(size_t)b * P_ + t] = f2h(uv * inv);
            if (t == 0) sqn[b] = s * inv * inv;

            const int l = lb[b];
            float mx = -1e30f;
            for (int j = t; j < NCLS; j += 64)
                if (!(j == l && l < C_)) mx = fmaxf(mx, sval[j]);
#pragma unroll
            for (int off = 32; off; off >>= 1) mx = fmaxf(mx, __shfl_xor(mx, off));
            float se = 0.f;
            for (int j = t; j < NCLS; j += 64)
                if (!(j == l && l < C_)) se += expf(sval[j] - mx);
#pragma unroll
            for (int off = 32; off; off >>= 1) se += __shfl_xor(se, off);

            if (t == 0) {
                float l150  = sval[C_];
                float loss2 = mx + logf(se) - l150;
                float loss1 = 0.f;
                if (l < C_) {
                    float a  = sval[l];
                    float m2 = fmaxf(a, l150);
                    loss1 = m2 - a + logf(expf(a - m2) + expf(l150 - m2));
                }
                clsbuf[b] = loss1 + loss2;
            }
        }
        __syncthreads();
    }
}

// ---------------------------------------------------------------------------
// Phase E: pairwise margin losses via f16 MFMA Gram tiles. 256 tasks.
// ---------------------------------------------------------------------------
__device__ __forceinline__ void phase_pair(
    int id, char* smemc,
    const ushort* __restrict__ uhf, const float* __restrict__ sqn,
    const int* __restrict__ lb, float* __restrict__ pairpart)
{
    if (id >= 256) return;
    ushort* ui_s = (ushort*)smemc;               // 64*USTR halves = 9216 B
    ushort* uj_s = (ushort*)(smemc + 9216);      // 9216 B
    float*  sni  = (float*)(smemc + 18432);
    float*  snj  = (float*)(smemc + 18688);
    int*    li   = (int*)(smemc + 18944);
    int*    lj   = (int*)(smemc + 19200);
    float*  red  = (float*)(smemc + 19456);      // [4][4]

    const int t  = threadIdx.x;
    const int i0 = (id & 15) * 64, j0 = (id >> 4) * 64;

    for (int idx = t; idx < 512; idx += 256) {
        int row = idx >> 3, ch = (idx & 7) * 8;
        *(uint4*)&ui_s[row * USTR + ch] =
            *(const uint4*)&uhf[(size_t)(i0 + row) * P_ + ch];
        *(uint4*)&uj_s[row * USTR + ch] =
            *(const uint4*)&uhf[(size_t)(j0 + row) * P_ + ch];
    }
    if (t < 64)       { sni[t] = sqn[i0 + t]; li[t] = lb[i0 + t]; }
    else if (t < 128) { int q = t - 64; snj[q] = sqn[j0 + q]; lj[q] = lb[j0 + q]; }
    __syncthreads();

    const int wave = t >> 6, lane = t & 63;
    const int n = lane & 15, quad = lane >> 4;
    const int iw = wave * 16;

    const fp16x8 af0 = *(const fp16x8*)&ui_s[(iw + n) * USTR + quad * 8];
    const fp16x8 af1 = *(const fp16x8*)&ui_s[(iw + n) * USTR + quad * 8 + 32];

    f32x4 acc[4];
#pragma unroll
    for (int jt = 0; jt < 4; ++jt) {
        const fp16x8 bf0 = *(const fp16x8*)&uj_s[(jt * 16 + n) * USTR + quad * 8];
        const fp16x8 bf1 = *(const fp16x8*)&uj_s[(jt * 16 + n) * USTR + quad * 8 + 32];
        acc[jt] = __builtin_amdgcn_mfma_f32_16x16x32_f16(
            af0, bf0, (f32x4){0.f, 0.f, 0.f, 0.f}, 0, 0, 0);
        acc[jt] = __builtin_amdgcn_mfma_f32_16x16x32_f16(
            af1, bf1, acc[jt], 0, 0, 0);
    }

    float ps = 0.f, pc = 0.f, ns = 0.f, nc = 0.f;
#pragma unroll
    for (int jt = 0; jt < 4; ++jt)
#pragma unroll
        for (int r = 0; r < 4; ++r) {
            const int il = iw + quad * 4 + r;
            const int jl = jt * 16 + n;
            float sq = sni[il] + snj[jl] - 2.f * acc[jt][r];
            float dist = sq > 0.f ? sqrtf(fmaxf(sq, 1e-16f)) : 0.f;
            bool same = (li[il] == lj[jl]);
            if (same) {
                if (i0 + il != j0 + jl) { ps += fmaxf(dist - 0.7f, 0.f); pc += 1.f; }
            } else {
                ns += fmaxf(1.4f - dist, 0.f); nc += 1.f;
            }
        }

#pragma unroll
    for (int off = 32; off; off >>= 1) {
        ps += __shfl_xor(ps, off); pc += __shfl_xor(pc, off);
        ns += __shfl_xor(ns, off); nc += __shfl_xor(nc, off);
    }
    if (lane == 0) { red[0 * 4 + wave] = ps; red[1 * 4 + wave] = pc;
                     red[2 * 4 + wave] = ns; red[3 * 4 + wave] = nc; }
    __syncthreads();
    if (t == 0) {
        float4 v;
        v.x = red[0] + red[1] + red[2] + red[3];
        v.y = red[4] + red[5] + red[6] + red[7];
        v.z = red[8] + red[9] + red[10] + red[11];
        v.w = red[12] + red[13] + red[14] + red[15];
        *(float4*)&pairpart[(size_t)id * 4] = v;
    }
}

// ---------------------------------------------------------------------------
// Phase F: block 0 reduces clsbuf[1024] and pairpart[256][4] -> out[0].
// ---------------------------------------------------------------------------
__device__ __forceinline__ void phase_final(
    char* smemc,
    const float* __restrict__ clsbuf, const float* __restrict__ pairpart,
    float* __restrict__ out)
{
    if (blockIdx.x != 0) return;
    float* red = (float*)smemc;   // [5][4]
    const int t = threadIdx.x;
    float c = clsbuf[t] + clsbuf[t + 256] + clsbuf[t + 512] + clsbuf[t + 768];
    float4 pp = *(const float4*)&pairpart[(size_t)t * 4];
    float ps = pp.x, pc = pp.y, ns = pp.z, nc = pp.w;
#pragma unroll
    for (int off = 32; off; off >>= 1) {
        c  += __shfl_xor(c, off);
        ps += __shfl_xor(ps, off); pc += __shfl_xor(pc, off);
        ns += __shfl_xor(ns, off); nc += __shfl_xor(nc, off);
    }
    const int wave = t >> 6, lane = t & 63;
    if (lane == 0) { red[0 * 4 + wave] = c; red[1 * 4 + wave] = ps;
                     red[2 * 4 + wave] = pc; red[3 * 4 + wave] = ns;
                     red[4 * 4 + wave] = nc; }
    __syncthreads();
    if (t == 0) {
        float C = 0.f, PS = 0.f, PC = 0.f, NS = 0.f, NC = 0.f;
#pragma unroll
        for (int w = 0; w < 4; ++w) {
            C += red[0 * 4 + w]; PS += red[1 * 4 + w]; PC += red[2 * 4 + w];
            NS += red[3 * 4 + w]; NC += red[4 * 4 + w];
        }
        out[0] = C / (float)B_ + PS / fmaxf(PC, 1.f) + NS / fmaxf(NC, 1.f);
    }
}

// ---------------------------------------------------------------------------
// Persistent mega-kernel: 512 blocks x 256 threads, 2 blocks/CU co-resident.
// ---------------------------------------------------------------------------
__global__ __launch_bounds__(256, 2) void mega(
    const float* __restrict__ x, const int* __restrict__ lb,
    const float* __restrict__ mem, const float* __restrict__ fc_w,
    const float* __restrict__ fc_b, const float* __restrict__ p1w,
    const float* __restrict__ p1b, const float* __restrict__ p2w,
    const float* __restrict__ p2b,
    float* ws, float* out)
{
    __shared__ __align__(16) char smem[46080];

    ushort* mh       = (ushort*)(ws + OFF_MH);
    ushort* xh       = (ushort*)(ws + OFF_XH);
    float*  partial  = ws + OFF_PARTIAL;
    ushort* uhf      = (ushort*)(ws + OFF_UHF);
    float*  sqn      = ws + OFF_SQN;
    float*  clsbuf   = ws + OFF_CLS;
    float*  pairpart = ws + OFF_PAIR;
    ushort* xbf      = (ushort*)(ws + OFF_XBF);
    ushort* membf    = (ushort*)(ws + OFF_MEMBF);
    ushort* wbf      = (ushort*)(ws + OFF_WBF);
    ushort* p2h      = (ushort*)(ws + OFF_P2H);
    ushort* p1h      = (ushort*)(ws + OFF_P1H);
    int*    bar      = (int*)(ws + OFF_BAR);

    const int id = blockIdx.x;

    phase_cvt(x, mem, fc_w, p2w, p1w, xbf, membf, wbf, p2h, p1h);
    grid_barrier(bar);
    phase_gemm(id, smem, xbf, membf, wbf, fc_b, xh, mh);
    grid_barrier(bar);
    phase_fused(id, smem, xh, mh, p1h, p2h, partial);
    grid_barrier(bar);
    phase_reduce(smem, partial, p1b, p2b, lb, uhf, sqn, clsbuf);
    grid_barrier(bar);
    phase_pair(id, smem, uhf, sqn, lb, pairpart);
    grid_barrier(bar);
    phase_final(smem, clsbuf, pairpart, out);
}

extern "C" void kernel_launch(void* const* d_in, const int* in_sizes, int n_in,
                              void* d_out, int out_size, void* d_ws, size_t ws_size,
                              hipStream_t stream)
{
    const float* x    = (const float*)d_in[0];
    const int*   lb   = (const int*)d_in[1];
    const float* mem  = (const float*)d_in[2];
    const float* fc_w = (const float*)d_in[3];
    const float* fc_b = (const float*)d_in[4];
    const float* p1w  = (const float*)d_in[5];
    const float* p1b  = (const float*)d_in[6];
    const float* p2w  = (const float*)d_in[7];
    const float* p2b  = (const float*)d_in[8];

    float* ws  = (float*)d_ws;
    int*   bar = (int*)(ws + OFF_BAR);

    // Zero barrier state (root cnt, gen, 32 group counters) — captured node.
    hipMemsetAsync(bar, 0, 4096, stream);

    mega<<<NBLK, 256, 0, stream>>>(x, lb, mem, fc_w, fc_b,
                                   p1w, p1b, p2w, p2b, ws, (float*)d_out);
}

// Round 3
// 170.516 us; speedup vs baseline: 2.3509x; 1.4354x over previous
//
#include <hip/hip_runtime.h>
#include <math.h>

// Problem constants
#define B_    1024
#define D_    768
#define C_    150
#define P_    64
#define TWOD  1536
#define NCLS  151   // C+1
#define CPAD  256   // partial row: 0..150 logits, 151..191 junk, 192..255 u

// fused_tile: 128b x 64c per block, 8x4/thr, e split 16 ways
#define ECHUNKS 16
#define ECHUNK  96

// gemm: 64x128 tile, BK=32, bf16 LDS stride 40
#define ASTR  40
// u-path LDS stride (halves)
#define USTRU 120
// pair phase LDS stride (halves)
#define USTR  72

// persistent grid
#define NBLK  512

// Workspace layout (float offsets) — conversions folded, so no bf16/f16
// staging buffers anymore.
#define OFF_MH      0
#define OFF_XH      (OFF_MH + (C_ * TWOD) / 2)
#define OFF_PARTIAL (OFF_XH + (B_ * TWOD) / 2)
#define OFF_UHF     (OFF_PARTIAL + ECHUNKS * B_ * CPAD)
#define OFF_SQN     (OFF_UHF + (B_ * P_) / 2)
#define OFF_CLS     (OFF_SQN + B_)
#define OFF_PAIR    (OFF_CLS + B_)
#define OFF_BAR     (OFF_PAIR + 1024)   // int[1024]: 512 slots, gen, done

typedef __bf16    bfx8   __attribute__((ext_vector_type(8)));
typedef _Float16  fp16x8 __attribute__((ext_vector_type(8)));
typedef _Float16  h2v    __attribute__((ext_vector_type(2)));
typedef float     f32x4  __attribute__((ext_vector_type(4)));

__device__ inline ushort f2bf(float f) {
    union { float f; unsigned u; } c; c.f = f;
    unsigned r = c.u + 0x7fffu + ((c.u >> 16) & 1u);
    return (ushort)(r >> 16);
}
__device__ inline ushort f2h(float f) {
    _Float16 h = (_Float16)f;
    return __builtin_bit_cast(ushort, h);
}
// pack 8 fp32 -> 8 bf16 in a uint4 (same byte layout as ushort[8])
__device__ inline uint4 pack_bf8(float4 a, float4 b) {
    uint4 r;
    r.x = (unsigned)f2bf(a.x) | ((unsigned)f2bf(a.y) << 16);
    r.y = (unsigned)f2bf(a.z) | ((unsigned)f2bf(a.w) << 16);
    r.z = (unsigned)f2bf(b.x) | ((unsigned)f2bf(b.y) << 16);
    r.w = (unsigned)f2bf(b.z) | ((unsigned)f2bf(b.w) << 16);
    return r;
}
// pack 8 fp32 -> 8 f16 in a uint4
__device__ inline uint4 pack_h8(float4 a, float4 b) {
    uint4 r;
    r.x = (unsigned)f2h(a.x) | ((unsigned)f2h(a.y) << 16);
    r.y = (unsigned)f2h(a.z) | ((unsigned)f2h(a.w) << 16);
    r.z = (unsigned)f2h(b.x) | ((unsigned)f2h(b.y) << 16);
    r.w = (unsigned)f2h(b.z) | ((unsigned)f2h(b.w) << 16);
    return r;
}
__device__ inline unsigned addrelu2(unsigned a, unsigned m) {
    h2v s = __builtin_bit_cast(h2v, a) + __builtin_bit_cast(h2v, m);
    h2v z = {(_Float16)0.f, (_Float16)0.f};
    s = __builtin_elementwise_max(s, z);
    return __builtin_bit_cast(unsigned, s);
}
__device__ inline unsigned relu2(unsigned a) {
    h2v s = __builtin_bit_cast(h2v, a);
    h2v z = {(_Float16)0.f, (_Float16)0.f};
    s = __builtin_elementwise_max(s, z);
    return __builtin_bit_cast(unsigned, s);
}
__device__ inline float dot2acc(unsigned a, unsigned b, float c) {
    return __builtin_amdgcn_fdot2(__builtin_bit_cast(h2v, a),
                                  __builtin_bit_cast(h2v, b), c, false);
}

// ---------------------------------------------------------------------------
// Grid barrier v3: slot arrival + single detector block.
// v2 cost model: 512 ACQ_REL RMWs/barrier, each = wbl2 + inv (plus exit inv)
// -> ~1536 L2-maintenance ops per barrier, ~27us/barrier with chip idle.
// v3: arrival is ONE release STORE (wbl2 only) into a per-block slot; block 0
// (64-lane sweep over the 512 slots, relaxed sc1 loads) detects completion,
// does ONE acquire fence, release-stores gen=ph; spinners poll gen relaxed
// and do ONE acquire fence (inv) on exit. Phases numbered 1..3, slots/gen
// monotonic within a launch (memset to 0 at launch, >= compares).
// ---------------------------------------------------------------------------
__device__ __forceinline__ void grid_barrier(int* bar, int ph)
{
    __syncthreads();
    int* slots = bar;
    int* gen   = bar + 512;
    const int t = threadIdx.x;
    if (blockIdx.x == 0) {
        if (t < 64) {
            bool alldone = false;
            while (!alldone) {
                bool mine = true;
#pragma unroll
                for (int k = 0; k < 8; ++k) {
                    const int idx = t + k * 64;
                    int v = (idx == 0) ? ph
                        : __hip_atomic_load(&slots[idx], __ATOMIC_RELAXED,
                                            __HIP_MEMORY_SCOPE_AGENT);
                    mine &= (v >= ph);
                }
                alldone = __all(mine);
                if (!alldone) __builtin_amdgcn_s_sleep(1);
            }
            if (t == 0) {
                __builtin_amdgcn_fence(__ATOMIC_ACQUIRE, "agent");
                __hip_atomic_store(gen, ph, __ATOMIC_RELEASE,
                                   __HIP_MEMORY_SCOPE_AGENT);
            }
        }
        __syncthreads();
    } else {
        if (t == 0) {
            __hip_atomic_store(&slots[blockIdx.x], ph, __ATOMIC_RELEASE,
                               __HIP_MEMORY_SCOPE_AGENT);
            while (__hip_atomic_load(gen, __ATOMIC_RELAXED,
                                     __HIP_MEMORY_SCOPE_AGENT) < ph)
                __builtin_amdgcn_s_sleep(2);
            __builtin_amdgcn_fence(__ATOMIC_ACQUIRE, "agent");
        }
        __syncthreads();
    }
}

// ---------------------------------------------------------------------------
// Phase B: merged MFMA GEMM, fp32 inputs with in-register fp32->bf16 convert
// during LDS staging (phase A folded in). tasks [0,192): xh = x@Wx^T + fc_b;
// tasks [192,228): mh = mem@Wm^T. 64x128 tile, BK=32, 4 waves.
// ---------------------------------------------------------------------------
__device__ __forceinline__ void phase_gemm(
    int id, char* smemc,
    const float* __restrict__ x, const float* __restrict__ mem,
    const float* __restrict__ fc_w, const float* __restrict__ fc_b,
    ushort* __restrict__ xh, ushort* __restrict__ mh)
{
    if (id >= 228) return;
    ushort* As = (ushort*)smemc;                    // 64 x ASTR
    ushort* Bs = (ushort*)(smemc + 64 * ASTR * 2);  // 128 x ASTR
    const int t = threadIdx.x;

    const float* A; ushort* Out; int M, m0, n0, koff; bool xblk;
    if (id < 192) {
        xblk = true;  A = x;    Out = xh; M = B_;
        m0 = (id & 15) * 64; n0 = (id >> 4) * 128; koff = 0;
    } else {
        int q = id - 192;
        xblk = false; A = mem;  Out = mh; M = C_;
        m0 = (q % 3) * 64; n0 = (q / 3) * 128; koff = D_;
    }

    const int wave = t >> 6, lane = t & 63;
    const int wm = (wave & 1) * 32, wn = (wave >> 1) * 64;
    const int fm = lane & 15, quad = lane >> 4;

    const int row_a = t >> 2, qa = (t & 3) * 8;
    const int ar = min(m0 + row_a, M - 1);
    const float* Arow = A + (size_t)ar * D_ + qa;
    const float* Brow = fc_w + (size_t)(n0 + row_a) * TWOD + koff + qa;

    f32x4 acc[2][4];
#pragma unroll
    for (int j = 0; j < 4; ++j) {
        float bv = xblk ? fc_b[n0 + wn + j * 16 + fm] : 0.f;
#pragma unroll
        for (int i = 0; i < 2; ++i)
            acc[i][j] = (f32x4){bv, bv, bv, bv};
    }

    float4 pa0  = *(const float4*)(Arow);
    float4 pa1  = *(const float4*)(Arow + 4);
    float4 pb00 = *(const float4*)(Brow);
    float4 pb01 = *(const float4*)(Brow + 4);
    float4 pb10 = *(const float4*)(Brow + 64 * TWOD);
    float4 pb11 = *(const float4*)(Brow + 64 * TWOD + 4);

    for (int k0 = 0; k0 < D_; k0 += 32) {
        __syncthreads();
        *(uint4*)&As[row_a * ASTR + qa]        = pack_bf8(pa0, pa1);
        *(uint4*)&Bs[row_a * ASTR + qa]        = pack_bf8(pb00, pb01);
        *(uint4*)&Bs[(64 + row_a) * ASTR + qa] = pack_bf8(pb10, pb11);
        __syncthreads();
        if (k0 + 32 < D_) {
            pa0  = *(const float4*)(Arow + k0 + 32);
            pa1  = *(const float4*)(Arow + k0 + 36);
            pb00 = *(const float4*)(Brow + k0 + 32);
            pb01 = *(const float4*)(Brow + k0 + 36);
            pb10 = *(const float4*)(Brow + 64 * TWOD + k0 + 32);
            pb11 = *(const float4*)(Brow + 64 * TWOD + k0 + 36);
        }
        bfx8 af[2], bff[4];
#pragma unroll
        for (int i = 0; i < 2; ++i)
            af[i] = *(const bfx8*)&As[(wm + i * 16 + fm) * ASTR + quad * 8];
#pragma unroll
        for (int j = 0; j < 4; ++j)
            bff[j] = *(const bfx8*)&Bs[(wn + j * 16 + fm) * ASTR + quad * 8];
#pragma unroll
        for (int i = 0; i < 2; ++i)
#pragma unroll
            for (int j = 0; j < 4; ++j)
                acc[i][j] = __builtin_amdgcn_mfma_f32_16x16x32_bf16(
                    af[i], bff[j], acc[i][j], 0, 0, 0);
    }

#pragma unroll
    for (int i = 0; i < 2; ++i)
#pragma unroll
        for (int j = 0; j < 4; ++j)
#pragma unroll
            for (int r = 0; r < 4; ++r) {
                int row = m0 + wm + i * 16 + quad * 4 + r;
                int col = n0 + wn + j * 16 + fm;
                if (row < M) Out[(size_t)row * TWOD + col] = f2h(acc[i][j][r]);
            }
}

// ---------------------------------------------------------------------------
// Phase C: fused tile. y<3: elementwise partial[z][b][c] = sum relu(xh+m)*p1
// y==3: MFMA f16 u-projection partial[z][b][192+n] = sum relu(xh)*p2.
// p1/p2 read as fp32 and converted during staging (phase A folded in).
// ---------------------------------------------------------------------------
__device__ __forceinline__ void phase_fused(
    int id, char* smem,
    const ushort* __restrict__ xh, const ushort* __restrict__ mh,
    const float* __restrict__ p1w, const float* __restrict__ p2w,
    float* __restrict__ partial)
{
    const int t  = threadIdx.x;
    const int b0 = (id & 7) * 128;
    const int y  = (id >> 3) & 3;
    const int z  = id >> 5;
    const int e0 = z * ECHUNK;

    if (y == 3) {
        // -------- MFMA f16 u-projection path --------
        ushort* Au = (ushort*)smem;                 // 128 x USTRU halves
        ushort* Wu = (ushort*)(smem + 30720);       // 64 x USTRU halves
        const int wave = t >> 6, lane = t & 63;
        const int fm = lane & 15, quad = lane >> 4;

        {   // stage relu(xh) f16 : 128 rows x 96 k
            const int row = t >> 1, kh = (t & 1) * 48;
            const ushort* src = xh + (size_t)(b0 + row) * TWOD + e0 + kh;
            uint4 v[6];
#pragma unroll
            for (int i = 0; i < 6; ++i) v[i] = *(const uint4*)&src[i * 8];
#pragma unroll
            for (int i = 0; i < 6; ++i) {
                v[i].x = relu2(v[i].x); v[i].y = relu2(v[i].y);
                v[i].z = relu2(v[i].z); v[i].w = relu2(v[i].w);
                *(uint4*)&Au[row * USTRU + kh + i * 8] = v[i];
            }
        }
        {   // stage p2 (fp32 -> f16) : 64 rows x 96 k
            const int row = t >> 2, ks = (t & 3) * 24;
            const float* pw = p2w + (size_t)row * TWOD + e0 + ks;
#pragma unroll
            for (int i = 0; i < 3; ++i) {
                float4 lo = *(const float4*)&pw[i * 8];
                float4 hi = *(const float4*)&pw[i * 8 + 4];
                *(uint4*)&Wu[row * USTRU + ks + i * 8] = pack_h8(lo, hi);
            }
        }
        __syncthreads();

        f32x4 uacc[2][4];
#pragma unroll
        for (int i = 0; i < 2; ++i)
#pragma unroll
            for (int j = 0; j < 4; ++j) uacc[i][j] = (f32x4){0.f, 0.f, 0.f, 0.f};
#pragma unroll
        for (int k0 = 0; k0 < ECHUNK; k0 += 32) {
            fp16x8 af[2], bff[4];
#pragma unroll
            for (int i = 0; i < 2; ++i)
                af[i] = *(const fp16x8*)&Au[(wave * 32 + i * 16 + fm) * USTRU + k0 + quad * 8];
#pragma unroll
            for (int j = 0; j < 4; ++j)
                bff[j] = *(const fp16x8*)&Wu[(j * 16 + fm) * USTRU + k0 + quad * 8];
#pragma unroll
            for (int i = 0; i < 2; ++i)
#pragma unroll
                for (int j = 0; j < 4; ++j)
                    uacc[i][j] = __builtin_amdgcn_mfma_f32_16x16x32_f16(
                        af[i], bff[j], uacc[i][j], 0, 0, 0);
        }
#pragma unroll
        for (int i = 0; i < 2; ++i)
#pragma unroll
            for (int j = 0; j < 4; ++j)
#pragma unroll
                for (int r = 0; r < 4; ++r) {
                    int row = b0 + wave * 32 + i * 16 + quad * 4 + r;
                    partial[((size_t)z * B_ + row) * CPAD + 192 + j * 16 + fm] =
                        uacc[i][j][r];
                }
        return;
    }

    // -------- elementwise f16 path: cols c0..c0+63 (c0 in {0,64,128}) -----
    unsigned* xT = (unsigned*)smem;             // [48 e-pairs][128 b]
    unsigned* mT = (unsigned*)(smem + 24576);   // [48][64 c]
    unsigned* wT = (unsigned*)(smem + 36864);   // [48]
    const int c0 = y * 64;
    const int tm = t & 15, tn = t >> 4;

    {   // stage x: 2 thr/row, 48 halves each
        const int row = t >> 1, ph = (t & 1) * 48;
        const ushort* src = xh + (size_t)(b0 + row) * TWOD + e0 + ph;
        uint4 v[6];
#pragma unroll
        for (int i = 0; i < 6; ++i) v[i] = *(const uint4*)&src[i * 8];
#pragma unroll
        for (int i = 0; i < 6; ++i) {
            const int ep = (t & 1) * 24 + i * 4;
            xT[(ep + 0) * 128 + row] = v[i].x;
            xT[(ep + 1) * 128 + row] = v[i].y;
            xT[(ep + 2) * 128 + row] = v[i].z;
            xT[(ep + 3) * 128 + row] = v[i].w;
        }
    }
    {   // stage m: 4 thr/col, 24 halves each
        const int col = t & 63, seg = t >> 6;
        const int gc  = c0 + col;
        uint4 v[3];
        if (gc < C_) {
            const ushort* src = mh + (size_t)gc * TWOD + e0 + seg * 24;
#pragma unroll
            for (int i = 0; i < 3; ++i) v[i] = *(const uint4*)&src[i * 8];
        } else {
#pragma unroll
            for (int i = 0; i < 3; ++i) v[i] = make_uint4(0, 0, 0, 0);
        }
#pragma unroll
        for (int i = 0; i < 3; ++i) {
            const int ep = seg * 12 + i * 4;
            mT[(ep + 0) * 64 + col] = v[i].x;
            mT[(ep + 1) * 64 + col] = v[i].y;
            mT[(ep + 2) * 64 + col] = v[i].z;
            mT[(ep + 3) * 64 + col] = v[i].w;
        }
    }
    if (t < 12) {  // stage w (p1, fp32 -> f16): 96 halves
        float4 lo = *(const float4*)&p1w[e0 + t * 8];
        float4 hi = *(const float4*)&p1w[e0 + t * 8 + 4];
        uint4 v = pack_h8(lo, hi);
        wT[t * 4 + 0] = v.x; wT[t * 4 + 1] = v.y;
        wT[t * 4 + 2] = v.z; wT[t * 4 + 3] = v.w;
    }
    __syncthreads();

    float acc[8][4] = {};
#pragma unroll 4
    for (int ep = 0; ep < 48; ++ep) {
        uint4 a0 = *(const uint4*)&xT[ep * 128 + tm * 8];
        uint4 a1 = *(const uint4*)&xT[ep * 128 + tm * 8 + 4];
        uint4 mj = *(const uint4*)&mT[ep * 64 + tn * 4];
        const unsigned wv = wT[ep];
        const unsigned aa[8] = {a0.x, a0.y, a0.z, a0.w, a1.x, a1.y, a1.z, a1.w};
        const unsigned mm[4] = {mj.x, mj.y, mj.z, mj.w};
#pragma unroll
        for (int i = 0; i < 8; ++i)
#pragma unroll
            for (int j = 0; j < 4; ++j)
                acc[i][j] = dot2acc(addrelu2(aa[i], mm[j]), wv, acc[i][j]);
    }

#pragma unroll
    for (int i = 0; i < 8; ++i) {
        const int gb = b0 + tm * 8 + i;
        float4 v = make_float4(acc[i][0], acc[i][1], acc[i][2], acc[i][3]);
        *(float4*)&partial[((size_t)z * B_ + gb) * CPAD + c0 + tn * 4] = v;
    }
}

// ---------------------------------------------------------------------------
// Phase D: per-row reduce of partials + bias, u-normalize (f16) + cls loss.
// 512 blocks x 2 rows each.
// ---------------------------------------------------------------------------
__device__ __forceinline__ void phase_reduce(
    char* smemc,
    const float* __restrict__ partial,
    const float* __restrict__ p1b, const float* __restrict__ p2b,
    const int* __restrict__ lb,
    ushort* __restrict__ uhf, float* __restrict__ sqn,
    float* __restrict__ clsbuf)
{
    float* sval = (float*)smemc;
    const int t = threadIdx.x;
    for (int b = blockIdx.x; b < B_; b += NBLK) {
        float v = 0.f;
#pragma unroll
        for (int z = 0; z < ECHUNKS; ++z)
            v += partial[((size_t)z * B_ + b) * CPAD + t];
        if (t < NCLS)       v += p1b[0];
        else if (t >= 192)  v += p2b[t - 192];

        sval[t] = v;
        __syncthreads();

        if (t < 64) {
            float uv = sval[192 + t];
            float s = uv * uv;
#pragma unroll
            for (int off = 32; off; off >>= 1) s += __shfl_xor(s, off);
            float inv = 1.f / fmaxf(sqrtf(s), 1e-12f);
            uhf[(size_t)b * P_ + t] = f2h(uv * inv);
            if (t == 0) sqn[b] = s * inv * inv;

            const int l = lb[b];
            float mx = -1e30f;
            for (int j = t; j < NCLS; j += 64)
                if (!(j == l && l < C_)) mx = fmaxf(mx, sval[j]);
#pragma unroll
            for (int off = 32; off; off >>= 1) mx = fmaxf(mx, __shfl_xor(mx, off));
            float se = 0.f;
            for (int j = t; j < NCLS; j += 64)
                if (!(j == l && l < C_)) se += expf(sval[j] - mx);
#pragma unroll
            for (int off = 32; off; off >>= 1) se += __shfl_xor(se, off);

            if (t == 0) {
                float l150  = sval[C_];
                float loss2 = mx + logf(se) - l150;
                float loss1 = 0.f;
                if (l < C_) {
                    float a  = sval[l];
                    float m2 = fmaxf(a, l150);
                    loss1 = m2 - a + logf(expf(a - m2) + expf(l150 - m2));
                }
                clsbuf[b] = loss1 + loss2;
            }
        }
        __syncthreads();
    }
}

// ---------------------------------------------------------------------------
// Phase E: pairwise margin losses via f16 MFMA Gram tiles. 256 tasks.
// ---------------------------------------------------------------------------
__device__ __forceinline__ void phase_pair(
    int id, char* smemc,
    const ushort* __restrict__ uhf, const float* __restrict__ sqn,
    const int* __restrict__ lb, float* __restrict__ pairpart)
{
    if (id >= 256) return;
    ushort* ui_s = (ushort*)smemc;               // 64*USTR halves = 9216 B
    ushort* uj_s = (ushort*)(smemc + 9216);      // 9216 B
    float*  sni  = (float*)(smemc + 18432);
    float*  snj  = (float*)(smemc + 18688);
    int*    li   = (int*)(smemc + 18944);
    int*    lj   = (int*)(smemc + 19200);
    float*  red  = (float*)(smemc + 19456);      // [4][4]

    const int t  = threadIdx.x;
    const int i0 = (id & 15) * 64, j0 = (id >> 4) * 64;

    for (int idx = t; idx < 512; idx += 256) {
        int row = idx >> 3, ch = (idx & 7) * 8;
        *(uint4*)&ui_s[row * USTR + ch] =
            *(const uint4*)&uhf[(size_t)(i0 + row) * P_ + ch];
        *(uint4*)&uj_s[row * USTR + ch] =
            *(const uint4*)&uhf[(size_t)(j0 + row) * P_ + ch];
    }
    if (t < 64)       { sni[t] = sqn[i0 + t]; li[t] = lb[i0 + t]; }
    else if (t < 128) { int q = t - 64; snj[q] = sqn[j0 + q]; lj[q] = lb[j0 + q]; }
    __syncthreads();

    const int wave = t >> 6, lane = t & 63;
    const int n = lane & 15, quad = lane >> 4;
    const int iw = wave * 16;

    const fp16x8 af0 = *(const fp16x8*)&ui_s[(iw + n) * USTR + quad * 8];
    const fp16x8 af1 = *(const fp16x8*)&ui_s[(iw + n) * USTR + quad * 8 + 32];

    f32x4 acc[4];
#pragma unroll
    for (int jt = 0; jt < 4; ++jt) {
        const fp16x8 bf0 = *(const fp16x8*)&uj_s[(jt * 16 + n) * USTR + quad * 8];
        const fp16x8 bf1 = *(const fp16x8*)&uj_s[(jt * 16 + n) * USTR + quad * 8 + 32];
        acc[jt] = __builtin_amdgcn_mfma_f32_16x16x32_f16(
            af0, bf0, (f32x4){0.f, 0.f, 0.f, 0.f}, 0, 0, 0);
        acc[jt] = __builtin_amdgcn_mfma_f32_16x16x32_f16(
            af1, bf1, acc[jt], 0, 0, 0);
    }

    float ps = 0.f, pc = 0.f, ns = 0.f, nc = 0.f;
#pragma unroll
    for (int jt = 0; jt < 4; ++jt)
#pragma unroll
        for (int r = 0; r < 4; ++r) {
            const int il = iw + quad * 4 + r;
            const int jl = jt * 16 + n;
            float sq = sni[il] + snj[jl] - 2.f * acc[jt][r];
            float dist = sq > 0.f ? sqrtf(fmaxf(sq, 1e-16f)) : 0.f;
            bool same = (li[il] == lj[jl]);
            if (same) {
                if (i0 + il != j0 + jl) { ps += fmaxf(dist - 0.7f, 0.f); pc += 1.f; }
            } else {
                ns += fmaxf(1.4f - dist, 0.f); nc += 1.f;
            }
        }

#pragma unroll
    for (int off = 32; off; off >>= 1) {
        ps += __shfl_xor(ps, off); pc += __shfl_xor(pc, off);
        ns += __shfl_xor(ns, off); nc += __shfl_xor(nc, off);
    }
    if (lane == 0) { red[0 * 4 + wave] = ps; red[1 * 4 + wave] = pc;
                     red[2 * 4 + wave] = ns; red[3 * 4 + wave] = nc; }
    __syncthreads();
    if (t == 0) {
        float4 v;
        v.x = red[0] + red[1] + red[2] + red[3];
        v.y = red[4] + red[5] + red[6] + red[7];
        v.z = red[8] + red[9] + red[10] + red[11];
        v.w = red[12] + red[13] + red[14] + red[15];
        *(float4*)&pairpart[(size_t)id * 4] = v;
    }
}

// ---------------------------------------------------------------------------
// Phase F: winner block reduces clsbuf[1024] and pairpart[256][4] -> out[0].
// ---------------------------------------------------------------------------
__device__ __forceinline__ void phase_final(
    char* smemc,
    const float* __restrict__ clsbuf, const float* __restrict__ pairpart,
    float* __restrict__ out)
{
    float* red = (float*)smemc;   // [5][4]
    const int t = threadIdx.x;
    float c = clsbuf[t] + clsbuf[t + 256] + clsbuf[t + 512] + clsbuf[t + 768];
    float4 pp = *(const float4*)&pairpart[(size_t)t * 4];
    float ps = pp.x, pc = pp.y, ns = pp.z, nc = pp.w;
#pragma unroll
    for (int off = 32; off; off >>= 1) {
        c  += __shfl_xor(c, off);
        ps += __shfl_xor(ps, off); pc += __shfl_xor(pc, off);
        ns += __shfl_xor(ns, off); nc += __shfl_xor(nc, off);
    }
    const int wave = t >> 6, lane = t & 63;
    if (lane == 0) { red[0 * 4 + wave] = c; red[1 * 4 + wave] = ps;
                     red[2 * 4 + wave] = pc; red[3 * 4 + wave] = ns;
                     red[4 * 4 + wave] = nc; }
    __syncthreads();
    if (t == 0) {
        float C = 0.f, PS = 0.f, PC = 0.f, NS = 0.f, NC = 0.f;
#pragma unroll
        for (int w = 0; w < 4; ++w) {
            C += red[0 * 4 + w]; PS += red[1 * 4 + w]; PC += red[2 * 4 + w];
            NS += red[3 * 4 + w]; NC += red[4 * 4 + w];
        }
        out[0] = C / (float)B_ + PS / fmaxf(PC, 1.f) + NS / fmaxf(NC, 1.f);
    }
}

// ---------------------------------------------------------------------------
// Persistent mega-kernel: 512 blocks x 256 threads, 2 blocks/CU co-resident.
// 3 grid barriers (was 5): phase A folded into B/C; phase F gated by a
// last-finisher done-counter instead of a barrier.
// ---------------------------------------------------------------------------
__global__ __launch_bounds__(256, 2) void mega(
    const float* __restrict__ x, const int* __restrict__ lb,
    const float* __restrict__ mem, const float* __restrict__ fc_w,
    const float* __restrict__ fc_b, const float* __restrict__ p1w,
    const float* __restrict__ p1b, const float* __restrict__ p2w,
    const float* __restrict__ p2b,
    float* ws, float* out)
{
    __shared__ __align__(16) char smem[46080];
    __shared__ int winflag;

    ushort* mh       = (ushort*)(ws + OFF_MH);
    ushort* xh       = (ushort*)(ws + OFF_XH);
    float*  partial  = ws + OFF_PARTIAL;
    ushort* uhf      = (ushort*)(ws + OFF_UHF);
    float*  sqn      = ws + OFF_SQN;
    float*  clsbuf   = ws + OFF_CLS;
    float*  pairpart = ws + OFF_PAIR;
    int*    bar      = (int*)(ws + OFF_BAR);

    const int id = blockIdx.x;

    phase_gemm(id, smem, x, mem, fc_w, fc_b, xh, mh);
    grid_barrier(bar, 1);
    phase_fused(id, smem, xh, mh, p1w, p2w, partial);
    grid_barrier(bar, 2);
    phase_reduce(smem, partial, p1b, p2b, lb, uhf, sqn, clsbuf);
    grid_barrier(bar, 3);
    if (id < 256) {
        phase_pair(id, smem, uhf, sqn, lb, pairpart);
        if (threadIdx.x == 0) {
            int rv = __hip_atomic_fetch_add(bar + 513, 1, __ATOMIC_ACQ_REL,
                                            __HIP_MEMORY_SCOPE_AGENT);
            winflag = (rv == 255);
        }
        __syncthreads();
        if (winflag) phase_final(smem, clsbuf, pairpart, out);
    }
}

extern "C" void kernel_launch(void* const* d_in, const int* in_sizes, int n_in,
                              void* d_out, int out_size, void* d_ws, size_t ws_size,
                              hipStream_t stream)
{
    const float* x    = (const float*)d_in[0];
    const int*   lb   = (const int*)d_in[1];
    const float* mem  = (const float*)d_in[2];
    const float* fc_w = (const float*)d_in[3];
    const float* fc_b = (const float*)d_in[4];
    const float* p1w  = (const float*)d_in[5];
    const float* p1b  = (const float*)d_in[6];
    const float* p2w  = (const float*)d_in[7];
    const float* p2b  = (const float*)d_in[8];

    float* ws  = (float*)d_ws;
    int*   bar = (int*)(ws + OFF_BAR);

    // Zero barrier state (512 slots + gen + done) — captured node.
    hipMemsetAsync(bar, 0, 4096, stream);

    mega<<<NBLK, 256, 0, stream>>>(x, lb, mem, fc_w, fc_b,
                                   p1w, p1b, p2w, p2b, ws, (float*)d_out);
}

// Round 4
// 146.620 us; speedup vs baseline: 2.7341x; 1.1630x over previous
//
#include <hip/hip_runtime.h>
#include <math.h>

// Problem constants
#define B_    1024
#define D_    768
#define C_    150
#define P_    64
#define TWOD  1536
#define NCLS  151   // C+1
#define CPAD  256   // partial row: 0..150 logits, 151..191 junk, 192..255 u

// fused_tile: 128b x 64c per block, 8x4/thr, e split 16 ways
#define ECHUNKS 16
#define ECHUNK  96

// gemm: 64x128 tile, BK=32, bf16 LDS stride 40
#define ASTR  40
// u-path LDS stride (halves)
#define USTRU 120
// pair phase LDS stride (halves)
#define USTR  72

// persistent grid
#define NBLK  512

// Workspace layout (float offsets)
#define OFF_MH      0
#define OFF_XH      (OFF_MH + (C_ * TWOD) / 2)
#define OFF_PARTIAL (OFF_XH + (B_ * TWOD) / 2)
#define OFF_UHF     (OFF_PARTIAL + ECHUNKS * B_ * CPAD)
#define OFF_SQN     (OFF_UHF + (B_ * P_) / 2)
#define OFF_CLS     (OFF_SQN + B_)
#define OFF_PAIR    (OFF_CLS + B_)
#define OFF_BAR     (OFF_PAIR + 1024)
// bar layout (ints, 16-int = 64B spacing):
//   arr[4 barriers][8 xcds] at (b*8+x)*16      (512 ints)
//   done[4]              at 512 + b*16         (64 ints)
//   gen[32 replicas]     at 576 + r*16         (512 ints)

typedef __bf16    bfx8   __attribute__((ext_vector_type(8)));
typedef _Float16  fp16x8 __attribute__((ext_vector_type(8)));
typedef _Float16  h2v    __attribute__((ext_vector_type(2)));
typedef float     f32x4  __attribute__((ext_vector_type(4)));

__device__ inline ushort f2bf(float f) {
    union { float f; unsigned u; } c; c.f = f;
    unsigned r = c.u + 0x7fffu + ((c.u >> 16) & 1u);
    return (ushort)(r >> 16);
}
__device__ inline ushort f2h(float f) {
    _Float16 h = (_Float16)f;
    return __builtin_bit_cast(ushort, h);
}
// pack 8 fp32 -> 8 bf16 in a uint4
__device__ inline uint4 pack_bf8(float4 a, float4 b) {
    uint4 r;
    r.x = (unsigned)f2bf(a.x) | ((unsigned)f2bf(a.y) << 16);
    r.y = (unsigned)f2bf(a.z) | ((unsigned)f2bf(a.w) << 16);
    r.z = (unsigned)f2bf(b.x) | ((unsigned)f2bf(b.y) << 16);
    r.w = (unsigned)f2bf(b.z) | ((unsigned)f2bf(b.w) << 16);
    return r;
}
// pack 8 fp32 -> 8 f16 in a uint4
__device__ inline uint4 pack_h8(float4 a, float4 b) {
    uint4 r;
    r.x = (unsigned)f2h(a.x) | ((unsigned)f2h(a.y) << 16);
    r.y = (unsigned)f2h(a.z) | ((unsigned)f2h(a.w) << 16);
    r.z = (unsigned)f2h(b.x) | ((unsigned)f2h(b.y) << 16);
    r.w = (unsigned)f2h(b.z) | ((unsigned)f2h(b.w) << 16);
    return r;
}
__device__ inline unsigned addrelu2(unsigned a, unsigned m) {
    h2v s = __builtin_bit_cast(h2v, a) + __builtin_bit_cast(h2v, m);
    h2v z = {(_Float16)0.f, (_Float16)0.f};
    s = __builtin_elementwise_max(s, z);
    return __builtin_bit_cast(unsigned, s);
}
__device__ inline unsigned relu2(unsigned a) {
    h2v s = __builtin_bit_cast(h2v, a);
    h2v z = {(_Float16)0.f, (_Float16)0.f};
    s = __builtin_elementwise_max(s, z);
    return __builtin_bit_cast(unsigned, s);
}
__device__ inline float dot2acc(unsigned a, unsigned b, float c) {
    return __builtin_amdgcn_fdot2(__builtin_bit_cast(h2v, a),
                                  __builtin_bit_cast(h2v, b), c, false);
}

__device__ __forceinline__ int read_xcc_id() {
    int v;
    asm volatile("s_getreg_b32 %0, hwreg(HW_REG_XCC_ID)" : "=s"(v));
    return v & 7;
}

// ---------------------------------------------------------------------------
// Grid barrier v4: per-XCD designated flusher, zero per-block cache ops.
// v3 cost model (measured ~25us/barrier): 512 release stores (each = full
// buffer_wbl2 L2 writeback scan, ~64 serialized per XCD) + 512 acquire invs
// + 512 spinners hammering ONE gen line at the coherence point.
// v4: (1) arrival = RELAXED fetch_add on per-XCD counter (8 lines, no cache
// ops; block's writes already drained to local L2 by __syncthreads' vmcnt(0));
// (2) first arriver per XCD waits for global all-arrived then issues ONE
// agent-release fence (one wbl2 per XCD, 8 total, parallel) + done++ (REL);
// (3) root waits done==T (T = #active XCDs), ONE acquire fence, publishes
// gen to 32 replicated lines; (4) readers poll their replica RELAXED, no
// fence on exit: dataflow is strictly forward (no address read before its
// write within this dispatch), so no reader XCD can hold a stale line —
// dispatch-start acquire wiped pre-kernel state. Reader freshness comes from
// L3, which the flusher wbl2s populated before gen was published.
// ---------------------------------------------------------------------------
__device__ __forceinline__ void grid_barrier(int* bar, int b)
{
    __syncthreads();   // compiler emits s_waitcnt vmcnt(0): writes are in L2
    if (threadIdx.x == 0) {
        int* arr  = bar;
        int* done = bar + 512 + (b - 1) * 16;
        int* gen  = bar + 576;
        const int base = (b - 1) * 8;
        const int xcc = read_xcc_id();
        int o = __hip_atomic_fetch_add(&arr[(base + xcc) * 16], 1,
                                       __ATOMIC_RELAXED,
                                       __HIP_MEMORY_SCOPE_AGENT);
        if (o == 0) {
            // XCD flusher: wait until ALL blocks arrived (so every block on
            // this XCD has drained its writes into this L2), then writeback.
            for (;;) {
                int s = 0;
#pragma unroll
                for (int k = 0; k < 8; ++k)
                    s += __hip_atomic_load(&arr[(base + k) * 16],
                                           __ATOMIC_RELAXED,
                                           __HIP_MEMORY_SCOPE_AGENT);
                if (s == NBLK) break;
                __builtin_amdgcn_s_sleep(2);
            }
            __builtin_amdgcn_fence(__ATOMIC_RELEASE, "agent"); // one wbl2
            __hip_atomic_fetch_add(done, 1, __ATOMIC_RELEASE,
                                   __HIP_MEMORY_SCOPE_AGENT);
        }
        if (blockIdx.x == 0) {
            int T = 0;
            for (;;) {
                int s = 0; T = 0;
#pragma unroll
                for (int k = 0; k < 8; ++k) {
                    int v = __hip_atomic_load(&arr[(base + k) * 16],
                                              __ATOMIC_RELAXED,
                                              __HIP_MEMORY_SCOPE_AGENT);
                    s += v; T += (v != 0);
                }
                if (s == NBLK) break;
                __builtin_amdgcn_s_sleep(2);
            }
            while (__hip_atomic_load(done, __ATOMIC_RELAXED,
                                     __HIP_MEMORY_SCOPE_AGENT) < T)
                __builtin_amdgcn_s_sleep(2);
            __builtin_amdgcn_fence(__ATOMIC_ACQUIRE, "agent"); // one inv
#pragma unroll
            for (int r = 0; r < 32; ++r)
                __hip_atomic_store(&gen[r * 16], b, __ATOMIC_RELAXED,
                                   __HIP_MEMORY_SCOPE_AGENT);
        } else {
            int* myg = &gen[(blockIdx.x & 31) * 16];
            while (__hip_atomic_load(myg, __ATOMIC_RELAXED,
                                     __HIP_MEMORY_SCOPE_AGENT) < b)
                __builtin_amdgcn_s_sleep(8);
        }
        asm volatile("" ::: "memory");
    }
    __syncthreads();
}

// ---------------------------------------------------------------------------
// Phase B: merged MFMA GEMM, fp32 inputs with in-register fp32->bf16 convert
// during LDS staging. tasks [0,192): xh = x@Wx^T + fc_b;
// tasks [192,228): mh = mem@Wm^T. 64x128 tile, BK=32, 4 waves.
// ---------------------------------------------------------------------------
__device__ __forceinline__ void phase_gemm(
    int id, char* smemc,
    const float* __restrict__ x, const float* __restrict__ mem,
    const float* __restrict__ fc_w, const float* __restrict__ fc_b,
    ushort* __restrict__ xh, ushort* __restrict__ mh)
{
    if (id >= 228) return;
    ushort* As = (ushort*)smemc;                    // 64 x ASTR
    ushort* Bs = (ushort*)(smemc + 64 * ASTR * 2);  // 128 x ASTR
    const int t = threadIdx.x;

    const float* A; ushort* Out; int M, m0, n0, koff; bool xblk;
    if (id < 192) {
        xblk = true;  A = x;    Out = xh; M = B_;
        m0 = (id & 15) * 64; n0 = (id >> 4) * 128; koff = 0;
    } else {
        int q = id - 192;
        xblk = false; A = mem;  Out = mh; M = C_;
        m0 = (q % 3) * 64; n0 = (q / 3) * 128; koff = D_;
    }

    const int wave = t >> 6, lane = t & 63;
    const int wm = (wave & 1) * 32, wn = (wave >> 1) * 64;
    const int fm = lane & 15, quad = lane >> 4;

    const int row_a = t >> 2, qa = (t & 3) * 8;
    const int ar = min(m0 + row_a, M - 1);
    const float* Arow = A + (size_t)ar * D_ + qa;
    const float* Brow = fc_w + (size_t)(n0 + row_a) * TWOD + koff + qa;

    f32x4 acc[2][4];
#pragma unroll
    for (int j = 0; j < 4; ++j) {
        float bv = xblk ? fc_b[n0 + wn + j * 16 + fm] : 0.f;
#pragma unroll
        for (int i = 0; i < 2; ++i)
            acc[i][j] = (f32x4){bv, bv, bv, bv};
    }

    float4 pa0  = *(const float4*)(Arow);
    float4 pa1  = *(const float4*)(Arow + 4);
    float4 pb00 = *(const float4*)(Brow);
    float4 pb01 = *(const float4*)(Brow + 4);
    float4 pb10 = *(const float4*)(Brow + 64 * TWOD);
    float4 pb11 = *(const float4*)(Brow + 64 * TWOD + 4);

    for (int k0 = 0; k0 < D_; k0 += 32) {
        __syncthreads();
        *(uint4*)&As[row_a * ASTR + qa]        = pack_bf8(pa0, pa1);
        *(uint4*)&Bs[row_a * ASTR + qa]        = pack_bf8(pb00, pb01);
        *(uint4*)&Bs[(64 + row_a) * ASTR + qa] = pack_bf8(pb10, pb11);
        __syncthreads();
        if (k0 + 32 < D_) {
            pa0  = *(const float4*)(Arow + k0 + 32);
            pa1  = *(const float4*)(Arow + k0 + 36);
            pb00 = *(const float4*)(Brow + k0 + 32);
            pb01 = *(const float4*)(Brow + k0 + 36);
            pb10 = *(const float4*)(Brow + 64 * TWOD + k0 + 32);
            pb11 = *(const float4*)(Brow + 64 * TWOD + k0 + 36);
        }
        bfx8 af[2], bff[4];
#pragma unroll
        for (int i = 0; i < 2; ++i)
            af[i] = *(const bfx8*)&As[(wm + i * 16 + fm) * ASTR + quad * 8];
#pragma unroll
        for (int j = 0; j < 4; ++j)
            bff[j] = *(const bfx8*)&Bs[(wn + j * 16 + fm) * ASTR + quad * 8];
#pragma unroll
        for (int i = 0; i < 2; ++i)
#pragma unroll
            for (int j = 0; j < 4; ++j)
                acc[i][j] = __builtin_amdgcn_mfma_f32_16x16x32_bf16(
                    af[i], bff[j], acc[i][j], 0, 0, 0);
    }

#pragma unroll
    for (int i = 0; i < 2; ++i)
#pragma unroll
        for (int j = 0; j < 4; ++j)
#pragma unroll
            for (int r = 0; r < 4; ++r) {
                int row = m0 + wm + i * 16 + quad * 4 + r;
                int col = n0 + wn + j * 16 + fm;
                if (row < M) Out[(size_t)row * TWOD + col] = f2h(acc[i][j][r]);
            }
}

// ---------------------------------------------------------------------------
// Phase C: fused tile. y<3: elementwise partial[z][b][c] = sum relu(xh+m)*p1
// y==3: MFMA f16 u-projection partial[z][b][192+n] = sum relu(xh)*p2.
// ---------------------------------------------------------------------------
__device__ __forceinline__ void phase_fused(
    int id, char* smem,
    const ushort* __restrict__ xh, const ushort* __restrict__ mh,
    const float* __restrict__ p1w, const float* __restrict__ p2w,
    float* __restrict__ partial)
{
    const int t  = threadIdx.x;
    const int b0 = (id & 7) * 128;
    const int y  = (id >> 3) & 3;
    const int z  = id >> 5;
    const int e0 = z * ECHUNK;

    if (y == 3) {
        // -------- MFMA f16 u-projection path --------
        ushort* Au = (ushort*)smem;                 // 128 x USTRU halves
        ushort* Wu = (ushort*)(smem + 30720);       // 64 x USTRU halves
        const int wave = t >> 6, lane = t & 63;
        const int fm = lane & 15, quad = lane >> 4;

        {   // stage relu(xh) f16 : 128 rows x 96 k
            const int row = t >> 1, kh = (t & 1) * 48;
            const ushort* src = xh + (size_t)(b0 + row) * TWOD + e0 + kh;
            uint4 v[6];
#pragma unroll
            for (int i = 0; i < 6; ++i) v[i] = *(const uint4*)&src[i * 8];
#pragma unroll
            for (int i = 0; i < 6; ++i) {
                v[i].x = relu2(v[i].x); v[i].y = relu2(v[i].y);
                v[i].z = relu2(v[i].z); v[i].w = relu2(v[i].w);
                *(uint4*)&Au[row * USTRU + kh + i * 8] = v[i];
            }
        }
        {   // stage p2 (fp32 -> f16) : 64 rows x 96 k
            const int row = t >> 2, ks = (t & 3) * 24;
            const float* pw = p2w + (size_t)row * TWOD + e0 + ks;
#pragma unroll
            for (int i = 0; i < 3; ++i) {
                float4 lo = *(const float4*)&pw[i * 8];
                float4 hi = *(const float4*)&pw[i * 8 + 4];
                *(uint4*)&Wu[row * USTRU + ks + i * 8] = pack_h8(lo, hi);
            }
        }
        __syncthreads();

        f32x4 uacc[2][4];
#pragma unroll
        for (int i = 0; i < 2; ++i)
#pragma unroll
            for (int j = 0; j < 4; ++j) uacc[i][j] = (f32x4){0.f, 0.f, 0.f, 0.f};
#pragma unroll
        for (int k0 = 0; k0 < ECHUNK; k0 += 32) {
            fp16x8 af[2], bff[4];
#pragma unroll
            for (int i = 0; i < 2; ++i)
                af[i] = *(const fp16x8*)&Au[(wave * 32 + i * 16 + fm) * USTRU + k0 + quad * 8];
#pragma unroll
            for (int j = 0; j < 4; ++j)
                bff[j] = *(const fp16x8*)&Wu[(j * 16 + fm) * USTRU + k0 + quad * 8];
#pragma unroll
            for (int i = 0; i < 2; ++i)
#pragma unroll
                for (int j = 0; j < 4; ++j)
                    uacc[i][j] = __builtin_amdgcn_mfma_f32_16x16x32_f16(
                        af[i], bff[j], uacc[i][j], 0, 0, 0);
        }
#pragma unroll
        for (int i = 0; i < 2; ++i)
#pragma unroll
            for (int j = 0; j < 4; ++j)
#pragma unroll
                for (int r = 0; r < 4; ++r) {
                    int row = b0 + wave * 32 + i * 16 + quad * 4 + r;
                    partial[((size_t)z * B_ + row) * CPAD + 192 + j * 16 + fm] =
                        uacc[i][j][r];
                }
        return;
    }

    // -------- elementwise f16 path: cols c0..c0+63 (c0 in {0,64,128}) -----
    unsigned* xT = (unsigned*)smem;             // [48 e-pairs][128 b]
    unsigned* mT = (unsigned*)(smem + 24576);   // [48][64 c]
    unsigned* wT = (unsigned*)(smem + 36864);   // [48]
    const int c0 = y * 64;
    const int tm = t & 15, tn = t >> 4;

    {   // stage x: 2 thr/row, 48 halves each
        const int row = t >> 1, ph = (t & 1) * 48;
        const ushort* src = xh + (size_t)(b0 + row) * TWOD + e0 + ph;
        uint4 v[6];
#pragma unroll
        for (int i = 0; i < 6; ++i) v[i] = *(const uint4*)&src[i * 8];
#pragma unroll
        for (int i = 0; i < 6; ++i) {
            const int ep = (t & 1) * 24 + i * 4;
            xT[(ep + 0) * 128 + row] = v[i].x;
            xT[(ep + 1) * 128 + row] = v[i].y;
            xT[(ep + 2) * 128 + row] = v[i].z;
            xT[(ep + 3) * 128 + row] = v[i].w;
        }
    }
    {   // stage m: 4 thr/col, 24 halves each
        const int col = t & 63, seg = t >> 6;
        const int gc  = c0 + col;
        uint4 v[3];
        if (gc < C_) {
            const ushort* src = mh + (size_t)gc * TWOD + e0 + seg * 24;
#pragma unroll
            for (int i = 0; i < 3; ++i) v[i] = *(const uint4*)&src[i * 8];
        } else {
#pragma unroll
            for (int i = 0; i < 3; ++i) v[i] = make_uint4(0, 0, 0, 0);
        }
#pragma unroll
        for (int i = 0; i < 3; ++i) {
            const int ep = seg * 12 + i * 4;
            mT[(ep + 0) * 64 + col] = v[i].x;
            mT[(ep + 1) * 64 + col] = v[i].y;
            mT[(ep + 2) * 64 + col] = v[i].z;
            mT[(ep + 3) * 64 + col] = v[i].w;
        }
    }
    if (t < 12) {  // stage w (p1, fp32 -> f16): 96 halves
        float4 lo = *(const float4*)&p1w[e0 + t * 8];
        float4 hi = *(const float4*)&p1w[e0 + t * 8 + 4];
        uint4 v = pack_h8(lo, hi);
        wT[t * 4 + 0] = v.x; wT[t * 4 + 1] = v.y;
        wT[t * 4 + 2] = v.z; wT[t * 4 + 3] = v.w;
    }
    __syncthreads();

    float acc[8][4] = {};
#pragma unroll 4
    for (int ep = 0; ep < 48; ++ep) {
        uint4 a0 = *(const uint4*)&xT[ep * 128 + tm * 8];
        uint4 a1 = *(const uint4*)&xT[ep * 128 + tm * 8 + 4];
        uint4 mj = *(const uint4*)&mT[ep * 64 + tn * 4];
        const unsigned wv = wT[ep];
        const unsigned aa[8] = {a0.x, a0.y, a0.z, a0.w, a1.x, a1.y, a1.z, a1.w};
        const unsigned mm[4] = {mj.x, mj.y, mj.z, mj.w};
#pragma unroll
        for (int i = 0; i < 8; ++i)
#pragma unroll
            for (int j = 0; j < 4; ++j)
                acc[i][j] = dot2acc(addrelu2(aa[i], mm[j]), wv, acc[i][j]);
    }

#pragma unroll
    for (int i = 0; i < 8; ++i) {
        const int gb = b0 + tm * 8 + i;
        float4 v = make_float4(acc[i][0], acc[i][1], acc[i][2], acc[i][3]);
        *(float4*)&partial[((size_t)z * B_ + gb) * CPAD + c0 + tn * 4] = v;
    }
}

// ---------------------------------------------------------------------------
// Phase D: per-row reduce of partials + bias, u-normalize (f16) + cls loss.
// ---------------------------------------------------------------------------
__device__ __forceinline__ void phase_reduce(
    char* smemc,
    const float* __restrict__ partial,
    const float* __restrict__ p1b, const float* __restrict__ p2b,
    const int* __restrict__ lb,
    ushort* __restrict__ uhf, float* __restrict__ sqn,
    float* __restrict__ clsbuf)
{
    float* sval = (float*)smemc;
    const int t = threadIdx.x;
    for (int b = blockIdx.x; b < B_; b += NBLK) {
        float v = 0.f;
#pragma unroll
        for (int z = 0; z < ECHUNKS; ++z)
            v += partial[((size_t)z * B_ + b) * CPAD + t];
        if (t < NCLS)       v += p1b[0];
        else if (t >= 192)  v += p2b[t - 192];

        sval[t] = v;
        __syncthreads();

        if (t < 64) {
            float uv = sval[192 + t];
            float s = uv * uv;
#pragma unroll
            for (int off = 32; off; off >>= 1) s += __shfl_xor(s, off);
            float inv = 1.f / fmaxf(sqrtf(s), 1e-12f);
            uhf[(size_t)b * P_ + t] = f2h(uv * inv);
            if (t == 0) sqn[b] = s * inv * inv;

            const int l = lb[b];
            float mx = -1e30f;
            for (int j = t; j < NCLS; j += 64)
                if (!(j == l && l < C_)) mx = fmaxf(mx, sval[j]);
#pragma unroll
            for (int off = 32; off; off >>= 1) mx = fmaxf(mx, __shfl_xor(mx, off));
            float se = 0.f;
            for (int j = t; j < NCLS; j += 64)
                if (!(j == l && l < C_)) se += expf(sval[j] - mx);
#pragma unroll
            for (int off = 32; off; off >>= 1) se += __shfl_xor(se, off);

            if (t == 0) {
                float l150  = sval[C_];
                float loss2 = mx + logf(se) - l150;
                float loss1 = 0.f;
                if (l < C_) {
                    float a  = sval[l];
                    float m2 = fmaxf(a, l150);
                    loss1 = m2 - a + logf(expf(a - m2) + expf(l150 - m2));
                }
                clsbuf[b] = loss1 + loss2;
            }
        }
        __syncthreads();
    }
}

// ---------------------------------------------------------------------------
// Phase E: pairwise margin losses via f16 MFMA Gram tiles. 256 tasks.
// ---------------------------------------------------------------------------
__device__ __forceinline__ void phase_pair(
    int id, char* smemc,
    const ushort* __restrict__ uhf, const float* __restrict__ sqn,
    const int* __restrict__ lb, float* __restrict__ pairpart)
{
    ushort* ui_s = (ushort*)smemc;               // 64*USTR halves = 9216 B
    ushort* uj_s = (ushort*)(smemc + 9216);      // 9216 B
    float*  sni  = (float*)(smemc + 18432);
    float*  snj  = (float*)(smemc + 18688);
    int*    li   = (int*)(smemc + 18944);
    int*    lj   = (int*)(smemc + 19200);
    float*  red  = (float*)(smemc + 19456);      // [4][4]

    const int t  = threadIdx.x;
    const int i0 = (id & 15) * 64, j0 = (id >> 4) * 64;

    for (int idx = t; idx < 512; idx += 256) {
        int row = idx >> 3, ch = (idx & 7) * 8;
        *(uint4*)&ui_s[row * USTR + ch] =
            *(const uint4*)&uhf[(size_t)(i0 + row) * P_ + ch];
        *(uint4*)&uj_s[row * USTR + ch] =
            *(const uint4*)&uhf[(size_t)(j0 + row) * P_ + ch];
    }
    if (t < 64)       { sni[t] = sqn[i0 + t]; li[t] = lb[i0 + t]; }
    else if (t < 128) { int q = t - 64; snj[q] = sqn[j0 + q]; lj[q] = lb[j0 + q]; }
    __syncthreads();

    const int wave = t >> 6, lane = t & 63;
    const int n = lane & 15, quad = lane >> 4;
    const int iw = wave * 16;

    const fp16x8 af0 = *(const fp16x8*)&ui_s[(iw + n) * USTR + quad * 8];
    const fp16x8 af1 = *(const fp16x8*)&ui_s[(iw + n) * USTR + quad * 8 + 32];

    f32x4 acc[4];
#pragma unroll
    for (int jt = 0; jt < 4; ++jt) {
        const fp16x8 bf0 = *(const fp16x8*)&uj_s[(jt * 16 + n) * USTR + quad * 8];
        const fp16x8 bf1 = *(const fp16x8*)&uj_s[(jt * 16 + n) * USTR + quad * 8 + 32];
        acc[jt] = __builtin_amdgcn_mfma_f32_16x16x32_f16(
            af0, bf0, (f32x4){0.f, 0.f, 0.f, 0.f}, 0, 0, 0);
        acc[jt] = __builtin_amdgcn_mfma_f32_16x16x32_f16(
            af1, bf1, acc[jt], 0, 0, 0);
    }

    float ps = 0.f, pc = 0.f, ns = 0.f, nc = 0.f;
#pragma unroll
    for (int jt = 0; jt < 4; ++jt)
#pragma unroll
        for (int r = 0; r < 4; ++r) {
            const int il = iw + quad * 4 + r;
            const int jl = jt * 16 + n;
            float sq = sni[il] + snj[jl] - 2.f * acc[jt][r];
            float dist = sq > 0.f ? sqrtf(fmaxf(sq, 1e-16f)) : 0.f;
            bool same = (li[il] == lj[jl]);
            if (same) {
                if (i0 + il != j0 + jl) { ps += fmaxf(dist - 0.7f, 0.f); pc += 1.f; }
            } else {
                ns += fmaxf(1.4f - dist, 0.f); nc += 1.f;
            }
        }

#pragma unroll
    for (int off = 32; off; off >>= 1) {
        ps += __shfl_xor(ps, off); pc += __shfl_xor(pc, off);
        ns += __shfl_xor(ns, off); nc += __shfl_xor(nc, off);
    }
    if (lane == 0) { red[0 * 4 + wave] = ps; red[1 * 4 + wave] = pc;
                     red[2 * 4 + wave] = ns; red[3 * 4 + wave] = nc; }
    __syncthreads();
    if (t == 0) {
        float4 v;
        v.x = red[0] + red[1] + red[2] + red[3];
        v.y = red[4] + red[5] + red[6] + red[7];
        v.z = red[8] + red[9] + red[10] + red[11];
        v.w = red[12] + red[13] + red[14] + red[15];
        *(float4*)&pairpart[(size_t)id * 4] = v;
    }
}

// ---------------------------------------------------------------------------
// Phase F: block 0 reduces clsbuf[1024] and pairpart[256][4] -> out[0].
// ---------------------------------------------------------------------------
__device__ __forceinline__ void phase_final(
    char* smemc,
    const float* __restrict__ clsbuf, const float* __restrict__ pairpart,
    float* __restrict__ out)
{
    float* red = (float*)smemc;   // [5][4]
    const int t = threadIdx.x;
    float c = clsbuf[t] + clsbuf[t + 256] + clsbuf[t + 512] + clsbuf[t + 768];
    float4 pp = *(const float4*)&pairpart[(size_t)t * 4];
    float ps = pp.x, pc = pp.y, ns = pp.z, nc = pp.w;
#pragma unroll
    for (int off = 32; off; off >>= 1) {
        c  += __shfl_xor(c, off);
        ps += __shfl_xor(ps, off); pc += __shfl_xor(pc, off);
        ns += __shfl_xor(ns, off); nc += __shfl_xor(nc, off);
    }
    const int wave = t >> 6, lane = t & 63;
    if (lane == 0) { red[0 * 4 + wave] = c; red[1 * 4 + wave] = ps;
                     red[2 * 4 + wave] = pc; red[3 * 4 + wave] = ns;
                     red[4 * 4 + wave] = nc; }
    __syncthreads();
    if (t == 0) {
        float C = 0.f, PS = 0.f, PC = 0.f, NS = 0.f, NC = 0.f;
#pragma unroll
        for (int w = 0; w < 4; ++w) {
            C += red[0 * 4 + w]; PS += red[1 * 4 + w]; PC += red[2 * 4 + w];
            NS += red[3 * 4 + w]; NC += red[4 * 4 + w];
        }
        out[0] = C / (float)B_ + PS / fmaxf(PC, 1.f) + NS / fmaxf(NC, 1.f);
    }
}

// ---------------------------------------------------------------------------
// Persistent mega-kernel: 512 blocks x 256 threads, 2 blocks/CU co-resident.
// Barriers 1-3 full rendezvous (v4 protocol); barrier 4 is arrive-only:
// non-root blocks exit after arrival, root waits for flushers then runs
// phase_final itself.
// ---------------------------------------------------------------------------
__global__ __launch_bounds__(256, 2) void mega(
    const float* __restrict__ x, const int* __restrict__ lb,
    const float* __restrict__ mem, const float* __restrict__ fc_w,
    const float* __restrict__ fc_b, const float* __restrict__ p1w,
    const float* __restrict__ p1b, const float* __restrict__ p2w,
    const float* __restrict__ p2b,
    float* ws, float* out)
{
    __shared__ __align__(16) char smem[46080];

    ushort* mh       = (ushort*)(ws + OFF_MH);
    ushort* xh       = (ushort*)(ws + OFF_XH);
    float*  partial  = ws + OFF_PARTIAL;
    ushort* uhf      = (ushort*)(ws + OFF_UHF);
    float*  sqn      = ws + OFF_SQN;
    float*  clsbuf   = ws + OFF_CLS;
    float*  pairpart = ws + OFF_PAIR;
    int*    bar      = (int*)(ws + OFF_BAR);

    const int id = blockIdx.x;

    phase_gemm(id, smem, x, mem, fc_w, fc_b, xh, mh);
    grid_barrier(bar, 1);
    phase_fused(id, smem, xh, mh, p1w, p2w, partial);
    grid_barrier(bar, 2);
    phase_reduce(smem, partial, p1b, p2b, lb, uhf, sqn, clsbuf);
    grid_barrier(bar, 3);
    if (id < 256) phase_pair(id, smem, uhf, sqn, lb, pairpart);

    // ---- barrier 4 (arrive-only) + root-runs-final ----
    __syncthreads();   // drain vmcnt: pairpart writes in local L2
    if (threadIdx.x == 0) {
        int* arr  = bar;
        int* done = bar + 512 + 3 * 16;
        const int base = 3 * 8;
        const int xcc = read_xcc_id();
        int o = __hip_atomic_fetch_add(&arr[(base + xcc) * 16], 1,
                                       __ATOMIC_RELAXED,
                                       __HIP_MEMORY_SCOPE_AGENT);
        if (o == 0) {
            for (;;) {
                int s = 0;
#pragma unroll
                for (int k = 0; k < 8; ++k)
                    s += __hip_atomic_load(&arr[(base + k) * 16],
                                           __ATOMIC_RELAXED,
                                           __HIP_MEMORY_SCOPE_AGENT);
                if (s == NBLK) break;
                __builtin_amdgcn_s_sleep(2);
            }
            __builtin_amdgcn_fence(__ATOMIC_RELEASE, "agent");
            __hip_atomic_fetch_add(done, 1, __ATOMIC_RELEASE,
                                   __HIP_MEMORY_SCOPE_AGENT);
        }
        if (blockIdx.x == 0) {
            int T = 0;
            for (;;) {
                int s = 0; T = 0;
#pragma unroll
                for (int k = 0; k < 8; ++k) {
                    int v = __hip_atomic_load(&arr[(base + k) * 16],
                                              __ATOMIC_RELAXED,
                                              __HIP_MEMORY_SCOPE_AGENT);
                    s += v; T += (v != 0);
                }
                if (s == NBLK) break;
                __builtin_amdgcn_s_sleep(2);
            }
            while (__hip_atomic_load(done, __ATOMIC_RELAXED,
                                     __HIP_MEMORY_SCOPE_AGENT) < T)
                __builtin_amdgcn_s_sleep(2);
            __builtin_amdgcn_fence(__ATOMIC_ACQUIRE, "agent");
        }
        asm volatile("" ::: "memory");
    }
    if (blockIdx.x == 0) {
        __syncthreads();
        phase_final(smem, clsbuf, pairpart, out);
    }
}

extern "C" void kernel_launch(void* const* d_in, const int* in_sizes, int n_in,
                              void* d_out, int out_size, void* d_ws, size_t ws_size,
                              hipStream_t stream)
{
    const float* x    = (const float*)d_in[0];
    const int*   lb   = (const int*)d_in[1];
    const float* mem  = (const float*)d_in[2];
    const float* fc_w = (const float*)d_in[3];
    const float* fc_b = (const float*)d_in[4];
    const float* p1w  = (const float*)d_in[5];
    const float* p1b  = (const float*)d_in[6];
    const float* p2w  = (const float*)d_in[7];
    const float* p2b  = (const float*)d_in[8];

    float* ws  = (float*)d_ws;
    int*   bar = (int*)(ws + OFF_BAR);

    // Zero barrier state (arr[4][8] + done[4] + gen[32] lines) — captured.
    hipMemsetAsync(bar, 0, 8192, stream);

    mega<<<NBLK, 256, 0, stream>>>(x, lb, mem, fc_w, fc_b,
                                   p1w, p1b, p2w, p2b, ws, (float*)d_out);
}

// Round 5
// 140.416 us; speedup vs baseline: 2.8549x; 1.0442x over previous
//
#include <hip/hip_runtime.h>
#include <math.h>

// Problem constants
#define B_    1024
#define D_    768
#define C_    150
#define P_    64
#define TWOD  1536
#define NCLS  151   // C+1
#define CPAD  256   // partial row: 0..150 logits, 151..191 junk, 192..255 u

// fused_tile: 128b x 64c per block, 8x4/thr, e split 16 ways
#define ECHUNKS 16
#define ECHUNK  96

// gemm: 64x128 tile, BK=32, bf16 LDS stride 40
#define ASTR  40
// u-path LDS stride (halves)
#define USTRU 120
// pair phase LDS stride (halves)
#define USTR  72

// persistent grid
#define NBLK  512

// Workspace layout (float offsets)
#define OFF_MH      0
#define OFF_XH      (OFF_MH + (C_ * TWOD) / 2)
#define OFF_PARTIAL (OFF_XH + (B_ * TWOD) / 2)
#define OFF_UHF     (OFF_PARTIAL + ECHUNKS * B_ * CPAD)
#define OFF_SQN     (OFF_UHF + (B_ * P_) / 2)
#define OFF_CLS     (OFF_SQN + B_)
#define OFF_PAIR    (OFF_CLS + B_)
#define OFF_BAR     (OFF_PAIR + 1024)
// bar layout (ints, 16-int = 64B spacing):
//   arr[4 barriers][8 groups] at (b*8+g)*16    (512 ints)
//   gen[32 replicas]          at 576 + r*16    (512 ints)

typedef __bf16    bfx8   __attribute__((ext_vector_type(8)));
typedef _Float16  fp16x8 __attribute__((ext_vector_type(8)));
typedef _Float16  h2v    __attribute__((ext_vector_type(2)));
typedef float     f32x4  __attribute__((ext_vector_type(4)));

__device__ inline ushort f2bf(float f) {
    union { float f; unsigned u; } c; c.f = f;
    unsigned r = c.u + 0x7fffu + ((c.u >> 16) & 1u);
    return (ushort)(r >> 16);
}
__device__ inline ushort f2h(float f) {
    _Float16 h = (_Float16)f;
    return __builtin_bit_cast(ushort, h);
}
// pack 8 fp32 -> 8 bf16 in a uint4
__device__ inline uint4 pack_bf8(float4 a, float4 b) {
    uint4 r;
    r.x = (unsigned)f2bf(a.x) | ((unsigned)f2bf(a.y) << 16);
    r.y = (unsigned)f2bf(a.z) | ((unsigned)f2bf(a.w) << 16);
    r.z = (unsigned)f2bf(b.x) | ((unsigned)f2bf(b.y) << 16);
    r.w = (unsigned)f2bf(b.z) | ((unsigned)f2bf(b.w) << 16);
    return r;
}
// pack 8 fp32 -> 8 f16 in a uint4
__device__ inline uint4 pack_h8(float4 a, float4 b) {
    uint4 r;
    r.x = (unsigned)f2h(a.x) | ((unsigned)f2h(a.y) << 16);
    r.y = (unsigned)f2h(a.z) | ((unsigned)f2h(a.w) << 16);
    r.z = (unsigned)f2h(b.x) | ((unsigned)f2h(b.y) << 16);
    r.w = (unsigned)f2h(b.z) | ((unsigned)f2h(b.w) << 16);
    return r;
}
__device__ inline unsigned addrelu2(unsigned a, unsigned m) {
    h2v s = __builtin_bit_cast(h2v, a) + __builtin_bit_cast(h2v, m);
    h2v z = {(_Float16)0.f, (_Float16)0.f};
    s = __builtin_elementwise_max(s, z);
    return __builtin_bit_cast(unsigned, s);
}
__device__ inline unsigned relu2(unsigned a) {
    h2v s = __builtin_bit_cast(h2v, a);
    h2v z = {(_Float16)0.f, (_Float16)0.f};
    s = __builtin_elementwise_max(s, z);
    return __builtin_bit_cast(unsigned, s);
}
__device__ inline float dot2acc(unsigned a, unsigned b, float c) {
    return __builtin_amdgcn_fdot2(__builtin_bit_cast(h2v, a),
                                  __builtin_bit_cast(h2v, b), c, false);
}

// ---------------------------------------------------------------------------
// Write-through stores (sc0 sc1 nt): bypass the producer XCD's L2 straight
// to the agent coherence point (L3). This is how LLVM emits agent-scope
// atomic stores — data is agent-visible once vmcnt-complete, with NO
// buffer_wbl2 needed. nt avoids polluting local L2 (lines are never re-read
// by the producer). All cross-phase buffers (xh, mh, partial, uhf, sqn,
// clsbuf, pairpart) use these; barriers then need zero cache maintenance.
// ---------------------------------------------------------------------------
__device__ __forceinline__ void st_wt_u16(ushort* p, unsigned v) {
    asm volatile("global_store_short %0, %1, off sc0 sc1 nt"
                 :: "v"(p), "v"(v) : "memory");
}
__device__ __forceinline__ void st_wt_f32(float* p, float v) {
    asm volatile("global_store_dword %0, %1, off sc0 sc1 nt"
                 :: "v"(p), "v"(v) : "memory");
}
__device__ __forceinline__ void st_wt_f32x4(float* p, f32x4 v) {
    asm volatile("global_store_dwordx4 %0, %1, off sc0 sc1 nt"
                 :: "v"(p), "v"(v) : "memory");
}

// ---------------------------------------------------------------------------
// Grid barrier v5: fence-free (relies on write-through data stores).
// v4 residual (~10us/barrier) = buffer_wbl2 full-L2 tag scan (~32K lines)
// in each XCD flusher + root's buffer_inv scan. v5 removes both: data is
// already at L3 via sc0/sc1/nt stores, so the barrier is pure control:
// (1) explicit s_waitcnt vmcnt(0) per wave (inline-asm stores are invisible
//     to compiler waitcnt bookkeeping!) -> all data stores L3-complete;
// (2) arrival = relaxed fetch_add spread over 8 lines by blockIdx&7;
// (3) block 0 polls the 8 counters, publishes gen to 32 replicated lines;
// (4) others poll their replica relaxed. No wbl2, no inv anywhere.
// Reader-side safety (validated by v4 passing with fence-free readers):
// forward dataflow + dispatch-start invalidate => no reader L2 ever holds
// a stale copy of a cross-phase address.
// ---------------------------------------------------------------------------
__device__ __forceinline__ void grid_barrier(int* bar, int b)
{
    asm volatile("s_waitcnt vmcnt(0)" ::: "memory");
    __syncthreads();
    if (threadIdx.x == 0) {
        int* arr = bar + (b - 1) * 8 * 16;
        int* gen = bar + 576;
        __hip_atomic_fetch_add(&arr[(blockIdx.x & 7) * 16], 1,
                               __ATOMIC_RELAXED, __HIP_MEMORY_SCOPE_AGENT);
        if (blockIdx.x == 0) {
            for (;;) {
                int s = 0;
#pragma unroll
                for (int k = 0; k < 8; ++k)
                    s += __hip_atomic_load(&arr[k * 16], __ATOMIC_RELAXED,
                                           __HIP_MEMORY_SCOPE_AGENT);
                if (s == NBLK) break;
                __builtin_amdgcn_s_sleep(1);
            }
#pragma unroll
            for (int r = 0; r < 32; ++r)
                __hip_atomic_store(&gen[r * 16], b, __ATOMIC_RELAXED,
                                   __HIP_MEMORY_SCOPE_AGENT);
        } else {
            int* myg = &gen[(blockIdx.x & 31) * 16];
            while (__hip_atomic_load(myg, __ATOMIC_RELAXED,
                                     __HIP_MEMORY_SCOPE_AGENT) < b)
                __builtin_amdgcn_s_sleep(4);
        }
        asm volatile("" ::: "memory");
    }
    __syncthreads();
}

// ---------------------------------------------------------------------------
// Phase B: merged MFMA GEMM, fp32 inputs with in-register fp32->bf16 convert
// during LDS staging. tasks [0,192): xh = x@Wx^T + fc_b;
// tasks [192,228): mh = mem@Wm^T. 64x128 tile, BK=32, 4 waves.
// ---------------------------------------------------------------------------
__device__ __forceinline__ void phase_gemm(
    int id, char* smemc,
    const float* __restrict__ x, const float* __restrict__ mem,
    const float* __restrict__ fc_w, const float* __restrict__ fc_b,
    ushort* __restrict__ xh, ushort* __restrict__ mh)
{
    if (id >= 228) return;
    ushort* As = (ushort*)smemc;                    // 64 x ASTR
    ushort* Bs = (ushort*)(smemc + 64 * ASTR * 2);  // 128 x ASTR
    const int t = threadIdx.x;

    const float* A; ushort* Out; int M, m0, n0, koff; bool xblk;
    if (id < 192) {
        xblk = true;  A = x;    Out = xh; M = B_;
        m0 = (id & 15) * 64; n0 = (id >> 4) * 128; koff = 0;
    } else {
        int q = id - 192;
        xblk = false; A = mem;  Out = mh; M = C_;
        m0 = (q % 3) * 64; n0 = (q / 3) * 128; koff = D_;
    }

    const int wave = t >> 6, lane = t & 63;
    const int wm = (wave & 1) * 32, wn = (wave >> 1) * 64;
    const int fm = lane & 15, quad = lane >> 4;

    const int row_a = t >> 2, qa = (t & 3) * 8;
    const int ar = min(m0 + row_a, M - 1);
    const float* Arow = A + (size_t)ar * D_ + qa;
    const float* Brow = fc_w + (size_t)(n0 + row_a) * TWOD + koff + qa;

    f32x4 acc[2][4];
#pragma unroll
    for (int j = 0; j < 4; ++j) {
        float bv = xblk ? fc_b[n0 + wn + j * 16 + fm] : 0.f;
#pragma unroll
        for (int i = 0; i < 2; ++i)
            acc[i][j] = (f32x4){bv, bv, bv, bv};
    }

    float4 pa0  = *(const float4*)(Arow);
    float4 pa1  = *(const float4*)(Arow + 4);
    float4 pb00 = *(const float4*)(Brow);
    float4 pb01 = *(const float4*)(Brow + 4);
    float4 pb10 = *(const float4*)(Brow + 64 * TWOD);
    float4 pb11 = *(const float4*)(Brow + 64 * TWOD + 4);

    for (int k0 = 0; k0 < D_; k0 += 32) {
        __syncthreads();
        *(uint4*)&As[row_a * ASTR + qa]        = pack_bf8(pa0, pa1);
        *(uint4*)&Bs[row_a * ASTR + qa]        = pack_bf8(pb00, pb01);
        *(uint4*)&Bs[(64 + row_a) * ASTR + qa] = pack_bf8(pb10, pb11);
        __syncthreads();
        if (k0 + 32 < D_) {
            pa0  = *(const float4*)(Arow + k0 + 32);
            pa1  = *(const float4*)(Arow + k0 + 36);
            pb00 = *(const float4*)(Brow + k0 + 32);
            pb01 = *(const float4*)(Brow + k0 + 36);
            pb10 = *(const float4*)(Brow + 64 * TWOD + k0 + 32);
            pb11 = *(const float4*)(Brow + 64 * TWOD + k0 + 36);
        }
        bfx8 af[2], bff[4];
#pragma unroll
        for (int i = 0; i < 2; ++i)
            af[i] = *(const bfx8*)&As[(wm + i * 16 + fm) * ASTR + quad * 8];
#pragma unroll
        for (int j = 0; j < 4; ++j)
            bff[j] = *(const bfx8*)&Bs[(wn + j * 16 + fm) * ASTR + quad * 8];
#pragma unroll
        for (int i = 0; i < 2; ++i)
#pragma unroll
            for (int j = 0; j < 4; ++j)
                acc[i][j] = __builtin_amdgcn_mfma_f32_16x16x32_bf16(
                    af[i], bff[j], acc[i][j], 0, 0, 0);
    }

#pragma unroll
    for (int i = 0; i < 2; ++i)
#pragma unroll
        for (int j = 0; j < 4; ++j)
#pragma unroll
            for (int r = 0; r < 4; ++r) {
                int row = m0 + wm + i * 16 + quad * 4 + r;
                int col = n0 + wn + j * 16 + fm;
                if (row < M)
                    st_wt_u16(&Out[(size_t)row * TWOD + col],
                              (unsigned)f2h(acc[i][j][r]));
            }
}

// ---------------------------------------------------------------------------
// Phase C: fused tile. y<3: elementwise partial[z][b][c] = sum relu(xh+m)*p1
// y==3: MFMA f16 u-projection partial[z][b][192+n] = sum relu(xh)*p2.
// ---------------------------------------------------------------------------
__device__ __forceinline__ void phase_fused(
    int id, char* smem,
    const ushort* __restrict__ xh, const ushort* __restrict__ mh,
    const float* __restrict__ p1w, const float* __restrict__ p2w,
    float* __restrict__ partial)
{
    const int t  = threadIdx.x;
    const int b0 = (id & 7) * 128;
    const int y  = (id >> 3) & 3;
    const int z  = id >> 5;
    const int e0 = z * ECHUNK;

    if (y == 3) {
        // -------- MFMA f16 u-projection path --------
        ushort* Au = (ushort*)smem;                 // 128 x USTRU halves
        ushort* Wu = (ushort*)(smem + 30720);       // 64 x USTRU halves
        const int wave = t >> 6, lane = t & 63;
        const int fm = lane & 15, quad = lane >> 4;

        {   // stage relu(xh) f16 : 128 rows x 96 k
            const int row = t >> 1, kh = (t & 1) * 48;
            const ushort* src = xh + (size_t)(b0 + row) * TWOD + e0 + kh;
            uint4 v[6];
#pragma unroll
            for (int i = 0; i < 6; ++i) v[i] = *(const uint4*)&src[i * 8];
#pragma unroll
            for (int i = 0; i < 6; ++i) {
                v[i].x = relu2(v[i].x); v[i].y = relu2(v[i].y);
                v[i].z = relu2(v[i].z); v[i].w = relu2(v[i].w);
                *(uint4*)&Au[row * USTRU + kh + i * 8] = v[i];
            }
        }
        {   // stage p2 (fp32 -> f16) : 64 rows x 96 k
            const int row = t >> 2, ks = (t & 3) * 24;
            const float* pw = p2w + (size_t)row * TWOD + e0 + ks;
#pragma unroll
            for (int i = 0; i < 3; ++i) {
                float4 lo = *(const float4*)&pw[i * 8];
                float4 hi = *(const float4*)&pw[i * 8 + 4];
                *(uint4*)&Wu[row * USTRU + ks + i * 8] = pack_h8(lo, hi);
            }
        }
        __syncthreads();

        f32x4 uacc[2][4];
#pragma unroll
        for (int i = 0; i < 2; ++i)
#pragma unroll
            for (int j = 0; j < 4; ++j) uacc[i][j] = (f32x4){0.f, 0.f, 0.f, 0.f};
#pragma unroll
        for (int k0 = 0; k0 < ECHUNK; k0 += 32) {
            fp16x8 af[2], bff[4];
#pragma unroll
            for (int i = 0; i < 2; ++i)
                af[i] = *(const fp16x8*)&Au[(wave * 32 + i * 16 + fm) * USTRU + k0 + quad * 8];
#pragma unroll
            for (int j = 0; j < 4; ++j)
                bff[j] = *(const fp16x8*)&Wu[(j * 16 + fm) * USTRU + k0 + quad * 8];
#pragma unroll
            for (int i = 0; i < 2; ++i)
#pragma unroll
                for (int j = 0; j < 4; ++j)
                    uacc[i][j] = __builtin_amdgcn_mfma_f32_16x16x32_f16(
                        af[i], bff[j], uacc[i][j], 0, 0, 0);
        }
#pragma unroll
        for (int i = 0; i < 2; ++i)
#pragma unroll
            for (int j = 0; j < 4; ++j)
#pragma unroll
                for (int r = 0; r < 4; ++r) {
                    int row = b0 + wave * 32 + i * 16 + quad * 4 + r;
                    st_wt_f32(&partial[((size_t)z * B_ + row) * CPAD + 192 + j * 16 + fm],
                              uacc[i][j][r]);
                }
        return;
    }

    // -------- elementwise f16 path: cols c0..c0+63 (c0 in {0,64,128}) -----
    unsigned* xT = (unsigned*)smem;             // [48 e-pairs][128 b]
    unsigned* mT = (unsigned*)(smem + 24576);   // [48][64 c]
    unsigned* wT = (unsigned*)(smem + 36864);   // [48]
    const int c0 = y * 64;
    const int tm = t & 15, tn = t >> 4;

    {   // stage x: 2 thr/row, 48 halves each
        const int row = t >> 1, ph = (t & 1) * 48;
        const ushort* src = xh + (size_t)(b0 + row) * TWOD + e0 + ph;
        uint4 v[6];
#pragma unroll
        for (int i = 0; i < 6; ++i) v[i] = *(const uint4*)&src[i * 8];
#pragma unroll
        for (int i = 0; i < 6; ++i) {
            const int ep = (t & 1) * 24 + i * 4;
            xT[(ep + 0) * 128 + row] = v[i].x;
            xT[(ep + 1) * 128 + row] = v[i].y;
            xT[(ep + 2) * 128 + row] = v[i].z;
            xT[(ep + 3) * 128 + row] = v[i].w;
        }
    }
    {   // stage m: 4 thr/col, 24 halves each
        const int col = t & 63, seg = t >> 6;
        const int gc  = c0 + col;
        uint4 v[3];
        if (gc < C_) {
            const ushort* src = mh + (size_t)gc * TWOD + e0 + seg * 24;
#pragma unroll
            for (int i = 0; i < 3; ++i) v[i] = *(const uint4*)&src[i * 8];
        } else {
#pragma unroll
            for (int i = 0; i < 3; ++i) v[i] = make_uint4(0, 0, 0, 0);
        }
#pragma unroll
        for (int i = 0; i < 3; ++i) {
            const int ep = seg * 12 + i * 4;
            mT[(ep + 0) * 64 + col] = v[i].x;
            mT[(ep + 1) * 64 + col] = v[i].y;
            mT[(ep + 2) * 64 + col] = v[i].z;
            mT[(ep + 3) * 64 + col] = v[i].w;
        }
    }
    if (t < 12) {  // stage w (p1, fp32 -> f16): 96 halves
        float4 lo = *(const float4*)&p1w[e0 + t * 8];
        float4 hi = *(const float4*)&p1w[e0 + t * 8 + 4];
        uint4 v = pack_h8(lo, hi);
        wT[t * 4 + 0] = v.x; wT[t * 4 + 1] = v.y;
        wT[t * 4 + 2] = v.z; wT[t * 4 + 3] = v.w;
    }
    __syncthreads();

    float acc[8][4] = {};
#pragma unroll 4
    for (int ep = 0; ep < 48; ++ep) {
        uint4 a0 = *(const uint4*)&xT[ep * 128 + tm * 8];
        uint4 a1 = *(const uint4*)&xT[ep * 128 + tm * 8 + 4];
        uint4 mj = *(const uint4*)&mT[ep * 64 + tn * 4];
        const unsigned wv = wT[ep];
        const unsigned aa[8] = {a0.x, a0.y, a0.z, a0.w, a1.x, a1.y, a1.z, a1.w};
        const unsigned mm[4] = {mj.x, mj.y, mj.z, mj.w};
#pragma unroll
        for (int i = 0; i < 8; ++i)
#pragma unroll
            for (int j = 0; j < 4; ++j)
                acc[i][j] = dot2acc(addrelu2(aa[i], mm[j]), wv, acc[i][j]);
    }

#pragma unroll
    for (int i = 0; i < 8; ++i) {
        const int gb = b0 + tm * 8 + i;
        f32x4 v = {acc[i][0], acc[i][1], acc[i][2], acc[i][3]};
        st_wt_f32x4(&partial[((size_t)z * B_ + gb) * CPAD + c0 + tn * 4], v);
    }
}

// ---------------------------------------------------------------------------
// Phase D: per-row reduce of partials + bias, u-normalize (f16) + cls loss.
// ---------------------------------------------------------------------------
__device__ __forceinline__ void phase_reduce(
    char* smemc,
    const float* __restrict__ partial,
    const float* __restrict__ p1b, const float* __restrict__ p2b,
    const int* __restrict__ lb,
    ushort* __restrict__ uhf, float* __restrict__ sqn,
    float* __restrict__ clsbuf)
{
    float* sval = (float*)smemc;
    const int t = threadIdx.x;
    for (int b = blockIdx.x; b < B_; b += NBLK) {
        float v = 0.f;
#pragma unroll
        for (int z = 0; z < ECHUNKS; ++z)
            v += partial[((size_t)z * B_ + b) * CPAD + t];
        if (t < NCLS)       v += p1b[0];
        else if (t >= 192)  v += p2b[t - 192];

        sval[t] = v;
        __syncthreads();

        if (t < 64) {
            float uv = sval[192 + t];
            float s = uv * uv;
#pragma unroll
            for (int off = 32; off; off >>= 1) s += __shfl_xor(s, off);
            float inv = 1.f / fmaxf(sqrtf(s), 1e-12f);
            st_wt_u16(&uhf[(size_t)b * P_ + t], (unsigned)f2h(uv * inv));
            if (t == 0) st_wt_f32(&sqn[b], s * inv * inv);

            const int l = lb[b];
            float mx = -1e30f;
            for (int j = t; j < NCLS; j += 64)
                if (!(j == l && l < C_)) mx = fmaxf(mx, sval[j]);
#pragma unroll
            for (int off = 32; off; off >>= 1) mx = fmaxf(mx, __shfl_xor(mx, off));
            float se = 0.f;
            for (int j = t; j < NCLS; j += 64)
                if (!(j == l && l < C_)) se += expf(sval[j] - mx);
#pragma unroll
            for (int off = 32; off; off >>= 1) se += __shfl_xor(se, off);

            if (t == 0) {
                float l150  = sval[C_];
                float loss2 = mx + logf(se) - l150;
                float loss1 = 0.f;
                if (l < C_) {
                    float a  = sval[l];
                    float m2 = fmaxf(a, l150);
                    loss1 = m2 - a + logf(expf(a - m2) + expf(l150 - m2));
                }
                st_wt_f32(&clsbuf[b], loss1 + loss2);
            }
        }
        __syncthreads();
    }
}

// ---------------------------------------------------------------------------
// Phase E: pairwise margin losses via f16 MFMA Gram tiles. 256 tasks.
// ---------------------------------------------------------------------------
__device__ __forceinline__ void phase_pair(
    int id, char* smemc,
    const ushort* __restrict__ uhf, const float* __restrict__ sqn,
    const int* __restrict__ lb, float* __restrict__ pairpart)
{
    ushort* ui_s = (ushort*)smemc;               // 64*USTR halves = 9216 B
    ushort* uj_s = (ushort*)(smemc + 9216);      // 9216 B
    float*  sni  = (float*)(smemc + 18432);
    float*  snj  = (float*)(smemc + 18688);
    int*    li   = (int*)(smemc + 18944);
    int*    lj   = (int*)(smemc + 19200);
    float*  red  = (float*)(smemc + 19456);      // [4][4]

    const int t  = threadIdx.x;
    const int i0 = (id & 15) * 64, j0 = (id >> 4) * 64;

    for (int idx = t; idx < 512; idx += 256) {
        int row = idx >> 3, ch = (idx & 7) * 8;
        *(uint4*)&ui_s[row * USTR + ch] =
            *(const uint4*)&uhf[(size_t)(i0 + row) * P_ + ch];
        *(uint4*)&uj_s[row * USTR + ch] =
            *(const uint4*)&uhf[(size_t)(j0 + row) * P_ + ch];
    }
    if (t < 64)       { sni[t] = sqn[i0 + t]; li[t] = lb[i0 + t]; }
    else if (t < 128) { int q = t - 64; snj[q] = sqn[j0 + q]; lj[q] = lb[j0 + q]; }
    __syncthreads();

    const int wave = t >> 6, lane = t & 63;
    const int n = lane & 15, quad = lane >> 4;
    const int iw = wave * 16;

    const fp16x8 af0 = *(const fp16x8*)&ui_s[(iw + n) * USTR + quad * 8];
    const fp16x8 af1 = *(const fp16x8*)&ui_s[(iw + n) * USTR + quad * 8 + 32];

    f32x4 acc[4];
#pragma unroll
    for (int jt = 0; jt < 4; ++jt) {
        const fp16x8 bf0 = *(const fp16x8*)&uj_s[(jt * 16 + n) * USTR + quad * 8];
        const fp16x8 bf1 = *(const fp16x8*)&uj_s[(jt * 16 + n) * USTR + quad * 8 + 32];
        acc[jt] = __builtin_amdgcn_mfma_f32_16x16x32_f16(
            af0, bf0, (f32x4){0.f, 0.f, 0.f, 0.f}, 0, 0, 0);
        acc[jt] = __builtin_amdgcn_mfma_f32_16x16x32_f16(
            af1, bf1, acc[jt], 0, 0, 0);
    }

    float ps = 0.f, pc = 0.f, ns = 0.f, nc = 0.f;
#pragma unroll
    for (int jt = 0; jt < 4; ++jt)
#pragma unroll
        for (int r = 0; r < 4; ++r) {
            const int il = iw + quad * 4 + r;
            const int jl = jt * 16 + n;
            float sq = sni[il] + snj[jl] - 2.f * acc[jt][r];
            float dist = sq > 0.f ? sqrtf(fmaxf(sq, 1e-16f)) : 0.f;
            bool same = (li[il] == lj[jl]);
            if (same) {
                if (i0 + il != j0 + jl) { ps += fmaxf(dist - 0.7f, 0.f); pc += 1.f; }
            } else {
                ns += fmaxf(1.4f - dist, 0.f); nc += 1.f;
            }
        }

#pragma unroll
    for (int off = 32; off; off >>= 1) {
        ps += __shfl_xor(ps, off); pc += __shfl_xor(pc, off);
        ns += __shfl_xor(ns, off); nc += __shfl_xor(nc, off);
    }
    if (lane == 0) { red[0 * 4 + wave] = ps; red[1 * 4 + wave] = pc;
                     red[2 * 4 + wave] = ns; red[3 * 4 + wave] = nc; }
    __syncthreads();
    if (t == 0) {
        f32x4 v;
        v[0] = red[0] + red[1] + red[2] + red[3];
        v[1] = red[4] + red[5] + red[6] + red[7];
        v[2] = red[8] + red[9] + red[10] + red[11];
        v[3] = red[12] + red[13] + red[14] + red[15];
        st_wt_f32x4(&pairpart[(size_t)id * 4], v);
    }
}

// ---------------------------------------------------------------------------
// Phase F: block 0 reduces clsbuf[1024] and pairpart[256][4] -> out[0].
// ---------------------------------------------------------------------------
__device__ __forceinline__ void phase_final(
    char* smemc,
    const float* __restrict__ clsbuf, const float* __restrict__ pairpart,
    float* __restrict__ out)
{
    float* red = (float*)smemc;   // [5][4]
    const int t = threadIdx.x;
    float c = clsbuf[t] + clsbuf[t + 256] + clsbuf[t + 512] + clsbuf[t + 768];
    float4 pp = *(const float4*)&pairpart[(size_t)t * 4];
    float ps = pp.x, pc = pp.y, ns = pp.z, nc = pp.w;
#pragma unroll
    for (int off = 32; off; off >>= 1) {
        c  += __shfl_xor(c, off);
        ps += __shfl_xor(ps, off); pc += __shfl_xor(pc, off);
        ns += __shfl_xor(ns, off); nc += __shfl_xor(nc, off);
    }
    const int wave = t >> 6, lane = t & 63;
    if (lane == 0) { red[0 * 4 + wave] = c; red[1 * 4 + wave] = ps;
                     red[2 * 4 + wave] = pc; red[3 * 4 + wave] = ns;
                     red[4 * 4 + wave] = nc; }
    __syncthreads();
    if (t == 0) {
        float C = 0.f, PS = 0.f, PC = 0.f, NS = 0.f, NC = 0.f;
#pragma unroll
        for (int w = 0; w < 4; ++w) {
            C += red[0 * 4 + w]; PS += red[1 * 4 + w]; PC += red[2 * 4 + w];
            NS += red[3 * 4 + w]; NC += red[4 * 4 + w];
        }
        out[0] = C / (float)B_ + PS / fmaxf(PC, 1.f) + NS / fmaxf(NC, 1.f);
    }
}

// ---------------------------------------------------------------------------
// Persistent mega-kernel: 512 blocks x 256 threads, 2 blocks/CU co-resident.
// Barriers 1-3 full rendezvous (v5 fence-free); barrier 4 is arrive-only:
// non-root blocks exit after arrival, root waits for all then runs final.
// ---------------------------------------------------------------------------
__global__ __launch_bounds__(256, 2) void mega(
    const float* __restrict__ x, const int* __restrict__ lb,
    const float* __restrict__ mem, const float* __restrict__ fc_w,
    const float* __restrict__ fc_b, const float* __restrict__ p1w,
    const float* __restrict__ p1b, const float* __restrict__ p2w,
    const float* __restrict__ p2b,
    float* ws, float* out)
{
    __shared__ __align__(16) char smem[46080];

    ushort* mh       = (ushort*)(ws + OFF_MH);
    ushort* xh       = (ushort*)(ws + OFF_XH);
    float*  partial  = ws + OFF_PARTIAL;
    ushort* uhf      = (ushort*)(ws + OFF_UHF);
    float*  sqn      = ws + OFF_SQN;
    float*  clsbuf   = ws + OFF_CLS;
    float*  pairpart = ws + OFF_PAIR;
    int*    bar      = (int*)(ws + OFF_BAR);

    const int id = blockIdx.x;

    phase_gemm(id, smem, x, mem, fc_w, fc_b, xh, mh);
    grid_barrier(bar, 1);
    phase_fused(id, smem, xh, mh, p1w, p2w, partial);
    grid_barrier(bar, 2);
    phase_reduce(smem, partial, p1b, p2b, lb, uhf, sqn, clsbuf);
    grid_barrier(bar, 3);
    if (id < 256) phase_pair(id, smem, uhf, sqn, lb, pairpart);

    // ---- barrier 4 (arrive-only, fence-free) + root-runs-final ----
    asm volatile("s_waitcnt vmcnt(0)" ::: "memory");
    __syncthreads();
    if (threadIdx.x == 0) {
        int* arr = bar + 3 * 8 * 16;
        __hip_atomic_fetch_add(&arr[(blockIdx.x & 7) * 16], 1,
                               __ATOMIC_RELAXED, __HIP_MEMORY_SCOPE_AGENT);
    }
    if (blockIdx.x == 0) {
        if (threadIdx.x == 0) {
            int* arr = bar + 3 * 8 * 16;
            for (;;) {
                int s = 0;
#pragma unroll
                for (int k = 0; k < 8; ++k)
                    s += __hip_atomic_load(&arr[k * 16], __ATOMIC_RELAXED,
                                           __HIP_MEMORY_SCOPE_AGENT);
                if (s == NBLK) break;
                __builtin_amdgcn_s_sleep(1);
            }
        }
        asm volatile("" ::: "memory");
        __syncthreads();
        phase_final(smem, clsbuf, pairpart, out);
    }
}

extern "C" void kernel_launch(void* const* d_in, const int* in_sizes, int n_in,
                              void* d_out, int out_size, void* d_ws, size_t ws_size,
                              hipStream_t stream)
{
    const float* x    = (const float*)d_in[0];
    const int*   lb   = (const int*)d_in[1];
    const float* mem  = (const float*)d_in[2];
    const float* fc_w = (const float*)d_in[3];
    const float* fc_b = (const float*)d_in[4];
    const float* p1w  = (const float*)d_in[5];
    const float* p1b  = (const float*)d_in[6];
    const float* p2w  = (const float*)d_in[7];
    const float* p2b  = (const float*)d_in[8];

    float* ws  = (float*)d_ws;
    int*   bar = (int*)(ws + OFF_BAR);

    // Zero barrier state (arr[4][8] lines + gen[32] lines) — captured node.
    hipMemsetAsync(bar, 0, 8192, stream);

    mega<<<NBLK, 256, 0, stream>>>(x, lb, mem, fc_w, fc_b,
                                   p1w, p1b, p2w, p2b, ws, (float*)d_out);
}

// Round 6
// 132.681 us; speedup vs baseline: 3.0213x; 1.0583x over previous
//
#include <hip/hip_runtime.h>
#include <math.h>

// Problem constants
#define B_    1024
#define D_    768
#define C_    150
#define P_    64
#define TWOD  1536
#define NCLS  151   // C+1
#define CPAD  256   // partial row: 0..150 logits, 151..191 junk, 192..255 u

// fused_tile: 128b x 64c per block, 8x4/thr, e split 16 ways
#define ECHUNKS 16
#define ECHUNK  96

// gemm v2: 64x64 tile, BK=64, double-buffered LDS, stride 72 halves
#define GSTR  72
#define GBUF  (64 * GSTR)      // halves per buffer
#define NKT   (D_ / 64)        // 12 k-iterations
// u-path LDS stride (halves)
#define USTRU 120
// pair phase LDS stride (halves)
#define USTR  72

// persistent grid
#define NBLK  512

// Workspace layout (float offsets)
#define OFF_MH      0
#define OFF_XH      (OFF_MH + (C_ * TWOD) / 2)
#define OFF_PARTIAL (OFF_XH + (B_ * TWOD) / 2)
#define OFF_UHF     (OFF_PARTIAL + ECHUNKS * B_ * CPAD)
#define OFF_SQN     (OFF_UHF + (B_ * P_) / 2)
#define OFF_CLS     (OFF_SQN + B_)
#define OFF_PAIR    (OFF_CLS + B_)
#define OFF_BAR     (OFF_PAIR + 1024)
// bar layout (ints, 16-int = 64B spacing):
//   arr[4 barriers][8 groups] at (b*8+g)*16    (512 ints)
//   gen[32 replicas]          at 576 + r*16    (512 ints)

typedef __bf16    bfx8   __attribute__((ext_vector_type(8)));
typedef _Float16  fp16x8 __attribute__((ext_vector_type(8)));
typedef _Float16  h2v    __attribute__((ext_vector_type(2)));
typedef float     f32x4  __attribute__((ext_vector_type(4)));

__device__ inline ushort f2bf(float f) {
    union { float f; unsigned u; } c; c.f = f;
    unsigned r = c.u + 0x7fffu + ((c.u >> 16) & 1u);
    return (ushort)(r >> 16);
}
__device__ inline ushort f2h(float f) {
    _Float16 h = (_Float16)f;
    return __builtin_bit_cast(ushort, h);
}
// pack 8 fp32 -> 8 bf16 in a uint4
__device__ inline uint4 pack_bf8(float4 a, float4 b) {
    uint4 r;
    r.x = (unsigned)f2bf(a.x) | ((unsigned)f2bf(a.y) << 16);
    r.y = (unsigned)f2bf(a.z) | ((unsigned)f2bf(a.w) << 16);
    r.z = (unsigned)f2bf(b.x) | ((unsigned)f2bf(b.y) << 16);
    r.w = (unsigned)f2bf(b.z) | ((unsigned)f2bf(b.w) << 16);
    return r;
}
// pack 8 fp32 -> 8 f16 in a uint4
__device__ inline uint4 pack_h8(float4 a, float4 b) {
    uint4 r;
    r.x = (unsigned)f2h(a.x) | ((unsigned)f2h(a.y) << 16);
    r.y = (unsigned)f2h(a.z) | ((unsigned)f2h(a.w) << 16);
    r.z = (unsigned)f2h(b.x) | ((unsigned)f2h(b.y) << 16);
    r.w = (unsigned)f2h(b.z) | ((unsigned)f2h(b.w) << 16);
    return r;
}
__device__ inline unsigned addrelu2(unsigned a, unsigned m) {
    h2v s = __builtin_bit_cast(h2v, a) + __builtin_bit_cast(h2v, m);
    h2v z = {(_Float16)0.f, (_Float16)0.f};
    s = __builtin_elementwise_max(s, z);
    return __builtin_bit_cast(unsigned, s);
}
__device__ inline unsigned relu2(unsigned a) {
    h2v s = __builtin_bit_cast(h2v, a);
    h2v z = {(_Float16)0.f, (_Float16)0.f};
    s = __builtin_elementwise_max(s, z);
    return __builtin_bit_cast(unsigned, s);
}
__device__ inline float dot2acc(unsigned a, unsigned b, float c) {
    return __builtin_amdgcn_fdot2(__builtin_bit_cast(h2v, a),
                                  __builtin_bit_cast(h2v, b), c, false);
}

// ---------------------------------------------------------------------------
// Write-through stores (sc0 sc1, NO nt): straight to the agent coherence
// point (L3) — agent-visible once vmcnt-complete, no wbl2 needed (validated
// v5: absmax 0 with fence-free readers). v5's nt flag marked the lines
// LRU-0 in L3 -> they evicted to HBM and readers re-fetched from HBM
// (FETCH_SIZE grew ~8MB). Dropping nt keeps xh/mh/partial L3-resident for
// their consumer phases.
// ---------------------------------------------------------------------------
__device__ __forceinline__ void st_wt_u16(ushort* p, unsigned v) {
    asm volatile("global_store_short %0, %1, off sc0 sc1"
                 :: "v"(p), "v"(v) : "memory");
}
__device__ __forceinline__ void st_wt_f32(float* p, float v) {
    asm volatile("global_store_dword %0, %1, off sc0 sc1"
                 :: "v"(p), "v"(v) : "memory");
}
__device__ __forceinline__ void st_wt_f32x4(float* p, f32x4 v) {
    asm volatile("global_store_dwordx4 %0, %1, off sc0 sc1"
                 :: "v"(p), "v"(v) : "memory");
}

// ---------------------------------------------------------------------------
// Grid barrier v5 (unchanged from round 5 — measured ~2-3us each):
// explicit vmcnt(0) (inline-asm stores invisible to compiler bookkeeping),
// relaxed fetch_add arrival spread over 8 lines, block-0 detector publishes
// to 32 replicated gen lines, relaxed polls, zero cache maintenance.
// ---------------------------------------------------------------------------
__device__ __forceinline__ void grid_barrier(int* bar, int b)
{
    asm volatile("s_waitcnt vmcnt(0)" ::: "memory");
    __syncthreads();
    if (threadIdx.x == 0) {
        int* arr = bar + (b - 1) * 8 * 16;
        int* gen = bar + 576;
        __hip_atomic_fetch_add(&arr[(blockIdx.x & 7) * 16], 1,
                               __ATOMIC_RELAXED, __HIP_MEMORY_SCOPE_AGENT);
        if (blockIdx.x == 0) {
            for (;;) {
                int s = 0;
#pragma unroll
                for (int k = 0; k < 8; ++k)
                    s += __hip_atomic_load(&arr[k * 16], __ATOMIC_RELAXED,
                                           __HIP_MEMORY_SCOPE_AGENT);
                if (s == NBLK) break;
                __builtin_amdgcn_s_sleep(1);
            }
#pragma unroll
            for (int r = 0; r < 32; ++r)
                __hip_atomic_store(&gen[r * 16], b, __ATOMIC_RELAXED,
                                   __HIP_MEMORY_SCOPE_AGENT);
        } else {
            int* myg = &gen[(blockIdx.x & 31) * 16];
            while (__hip_atomic_load(myg, __ATOMIC_RELAXED,
                                     __HIP_MEMORY_SCOPE_AGENT) < b)
                __builtin_amdgcn_s_sleep(4);
        }
        asm volatile("" ::: "memory");
    }
    __syncthreads();
}

// ---------------------------------------------------------------------------
// Phase B v2: merged MFMA GEMM, 64x64 tiles (456 tasks, was 228 @64x128 ->
// 89% machine util), BK=64 (12 iters, was 24), double-buffered LDS with ONE
// sync/iter and loads issued a full iteration ahead (in-flight window ~= a
// whole iteration, hiding the ~600cy L3 latency that was ~400cy exposed).
// tasks [0,384): xh = x@Wx^T + fc_b ; tasks [384,456): mh = mem@Wm^T.
// 4 waves, each computes 16 rows x 64 cols (1x4 frags of 16x16, K=64).
// ---------------------------------------------------------------------------
__device__ __forceinline__ void phase_gemm(
    int id, char* smemc,
    const float* __restrict__ x, const float* __restrict__ mem,
    const float* __restrict__ fc_w, const float* __restrict__ fc_b,
    ushort* __restrict__ xh, ushort* __restrict__ mh)
{
    if (id >= 456) return;
    ushort* As = (ushort*)smemc;                       // 2 x 64 x GSTR
    ushort* Bs = (ushort*)(smemc + 2 * GBUF * 2);      // 2 x 64 x GSTR
    const int t = threadIdx.x;

    const float* A; ushort* Out; int M, m0, n0, koff; bool xblk;
    if (id < 384) {
        xblk = true;  A = x;    Out = xh; M = B_;
        m0 = (id & 15) * 64; n0 = (id >> 4) * 64; koff = 0;
    } else {
        int q = id - 384;
        xblk = false; A = mem;  Out = mh; M = C_;
        m0 = (q % 3) * 64; n0 = (q / 3) * 64; koff = D_;
    }

    const int wave = t >> 6, lane = t & 63;
    const int wm = wave * 16;
    const int fm = lane & 15, quad = lane >> 4;

    // staging: 4 threads/row, 16 consecutive floats each
    const int row_a = t >> 2, qa = (t & 3) * 16;
    const int ar = min(m0 + row_a, M - 1);
    const float* Arow = A + (size_t)ar * D_ + qa;
    const float* Brow = fc_w + (size_t)(n0 + row_a) * TWOD + koff + qa;
    const int lw = row_a * GSTR + qa;

    f32x4 acc[4];
#pragma unroll
    for (int j = 0; j < 4; ++j) {
        float bv = xblk ? fc_b[n0 + j * 16 + fm] : 0.f;
        acc[j] = (f32x4){bv, bv, bv, bv};
    }

    float4 pa0 = *(const float4*)(Arow);
    float4 pa1 = *(const float4*)(Arow + 4);
    float4 pa2 = *(const float4*)(Arow + 8);
    float4 pa3 = *(const float4*)(Arow + 12);
    float4 pb0 = *(const float4*)(Brow);
    float4 pb1 = *(const float4*)(Brow + 4);
    float4 pb2 = *(const float4*)(Brow + 8);
    float4 pb3 = *(const float4*)(Brow + 12);

    for (int kt = 0; kt < NKT; ++kt) {
        ushort* Ad = As + (kt & 1) * GBUF;
        ushort* Bd = Bs + (kt & 1) * GBUF;
        // write regs(kt) -> buf[kt&1]  (vmcnt wait: loads issued 1 iter ago)
        *(uint4*)&Ad[lw]     = pack_bf8(pa0, pa1);
        *(uint4*)&Ad[lw + 8] = pack_bf8(pa2, pa3);
        *(uint4*)&Bd[lw]     = pack_bf8(pb0, pb1);
        *(uint4*)&Bd[lw + 8] = pack_bf8(pb2, pb3);
        __syncthreads();
        // issue loads(kt+1) — in flight across the whole MFMA segment + next
        // iter's pack/write
        if (kt + 1 < NKT) {
            const int k1 = (kt + 1) * 64;
            pa0 = *(const float4*)(Arow + k1);
            pa1 = *(const float4*)(Arow + k1 + 4);
            pa2 = *(const float4*)(Arow + k1 + 8);
            pa3 = *(const float4*)(Arow + k1 + 12);
            pb0 = *(const float4*)(Brow + k1);
            pb1 = *(const float4*)(Brow + k1 + 4);
            pb2 = *(const float4*)(Brow + k1 + 8);
            pb3 = *(const float4*)(Brow + k1 + 12);
        }
        // consume buf[kt&1]: K=64 as two K=32 MFMA slices
#pragma unroll
        for (int ks = 0; ks < 2; ++ks) {
            bfx8 af = *(const bfx8*)&Ad[(wm + fm) * GSTR + ks * 32 + quad * 8];
#pragma unroll
            for (int j = 0; j < 4; ++j) {
                bfx8 bf = *(const bfx8*)&Bd[(j * 16 + fm) * GSTR + ks * 32 + quad * 8];
                acc[j] = __builtin_amdgcn_mfma_f32_16x16x32_bf16(
                    af, bf, acc[j], 0, 0, 0);
            }
        }
    }

#pragma unroll
    for (int j = 0; j < 4; ++j)
#pragma unroll
        for (int r = 0; r < 4; ++r) {
            int row = m0 + wm + quad * 4 + r;
            int col = n0 + j * 16 + fm;
            if (row < M)
                st_wt_u16(&Out[(size_t)row * TWOD + col],
                          (unsigned)f2h(acc[j][r]));
        }
}

// ---------------------------------------------------------------------------
// Phase C: fused tile. y<3: elementwise partial[z][b][c] = sum relu(xh+m)*p1
// y==3: MFMA f16 u-projection partial[z][b][192+n] = sum relu(xh)*p2.
// ---------------------------------------------------------------------------
__device__ __forceinline__ void phase_fused(
    int id, char* smem,
    const ushort* __restrict__ xh, const ushort* __restrict__ mh,
    const float* __restrict__ p1w, const float* __restrict__ p2w,
    float* __restrict__ partial)
{
    const int t  = threadIdx.x;
    const int b0 = (id & 7) * 128;
    const int y  = (id >> 3) & 3;
    const int z  = id >> 5;
    const int e0 = z * ECHUNK;

    if (y == 3) {
        // -------- MFMA f16 u-projection path --------
        ushort* Au = (ushort*)smem;                 // 128 x USTRU halves
        ushort* Wu = (ushort*)(smem + 30720);       // 64 x USTRU halves
        const int wave = t >> 6, lane = t & 63;
        const int fm = lane & 15, quad = lane >> 4;

        {   // stage relu(xh) f16 : 128 rows x 96 k
            const int row = t >> 1, kh = (t & 1) * 48;
            const ushort* src = xh + (size_t)(b0 + row) * TWOD + e0 + kh;
            uint4 v[6];
#pragma unroll
            for (int i = 0; i < 6; ++i) v[i] = *(const uint4*)&src[i * 8];
#pragma unroll
            for (int i = 0; i < 6; ++i) {
                v[i].x = relu2(v[i].x); v[i].y = relu2(v[i].y);
                v[i].z = relu2(v[i].z); v[i].w = relu2(v[i].w);
                *(uint4*)&Au[row * USTRU + kh + i * 8] = v[i];
            }
        }
        {   // stage p2 (fp32 -> f16) : 64 rows x 96 k
            const int row = t >> 2, ks = (t & 3) * 24;
            const float* pw = p2w + (size_t)row * TWOD + e0 + ks;
#pragma unroll
            for (int i = 0; i < 3; ++i) {
                float4 lo = *(const float4*)&pw[i * 8];
                float4 hi = *(const float4*)&pw[i * 8 + 4];
                *(uint4*)&Wu[row * USTRU + ks + i * 8] = pack_h8(lo, hi);
            }
        }
        __syncthreads();

        f32x4 uacc[2][4];
#pragma unroll
        for (int i = 0; i < 2; ++i)
#pragma unroll
            for (int j = 0; j < 4; ++j) uacc[i][j] = (f32x4){0.f, 0.f, 0.f, 0.f};
#pragma unroll
        for (int k0 = 0; k0 < ECHUNK; k0 += 32) {
            fp16x8 af[2], bff[4];
#pragma unroll
            for (int i = 0; i < 2; ++i)
                af[i] = *(const fp16x8*)&Au[(wave * 32 + i * 16 + fm) * USTRU + k0 + quad * 8];
#pragma unroll
            for (int j = 0; j < 4; ++j)
                bff[j] = *(const fp16x8*)&Wu[(j * 16 + fm) * USTRU + k0 + quad * 8];
#pragma unroll
            for (int i = 0; i < 2; ++i)
#pragma unroll
                for (int j = 0; j < 4; ++j)
                    uacc[i][j] = __builtin_amdgcn_mfma_f32_16x16x32_f16(
                        af[i], bff[j], uacc[i][j], 0, 0, 0);
        }
#pragma unroll
        for (int i = 0; i < 2; ++i)
#pragma unroll
            for (int j = 0; j < 4; ++j)
#pragma unroll
                for (int r = 0; r < 4; ++r) {
                    int row = b0 + wave * 32 + i * 16 + quad * 4 + r;
                    st_wt_f32(&partial[((size_t)z * B_ + row) * CPAD + 192 + j * 16 + fm],
                              uacc[i][j][r]);
                }
        return;
    }

    // -------- elementwise f16 path: cols c0..c0+63 (c0 in {0,64,128}) -----
    unsigned* xT = (unsigned*)smem;             // [48 e-pairs][128 b]
    unsigned* mT = (unsigned*)(smem + 24576);   // [48][64 c]
    unsigned* wT = (unsigned*)(smem + 36864);   // [48]
    const int c0 = y * 64;
    const int tm = t & 15, tn = t >> 4;

    {   // stage x: 2 thr/row, 48 halves each
        const int row = t >> 1, ph = (t & 1) * 48;
        const ushort* src = xh + (size_t)(b0 + row) * TWOD + e0 + ph;
        uint4 v[6];
#pragma unroll
        for (int i = 0; i < 6; ++i) v[i] = *(const uint4*)&src[i * 8];
#pragma unroll
        for (int i = 0; i < 6; ++i) {
            const int ep = (t & 1) * 24 + i * 4;
            xT[(ep + 0) * 128 + row] = v[i].x;
            xT[(ep + 1) * 128 + row] = v[i].y;
            xT[(ep + 2) * 128 + row] = v[i].z;
            xT[(ep + 3) * 128 + row] = v[i].w;
        }
    }
    {   // stage m: 4 thr/col, 24 halves each
        const int col = t & 63, seg = t >> 6;
        const int gc  = c0 + col;
        uint4 v[3];
        if (gc < C_) {
            const ushort* src = mh + (size_t)gc * TWOD + e0 + seg * 24;
#pragma unroll
            for (int i = 0; i < 3; ++i) v[i] = *(const uint4*)&src[i * 8];
        } else {
#pragma unroll
            for (int i = 0; i < 3; ++i) v[i] = make_uint4(0, 0, 0, 0);
        }
#pragma unroll
        for (int i = 0; i < 3; ++i) {
            const int ep = seg * 12 + i * 4;
            mT[(ep + 0) * 64 + col] = v[i].x;
            mT[(ep + 1) * 64 + col] = v[i].y;
            mT[(ep + 2) * 64 + col] = v[i].z;
            mT[(ep + 3) * 64 + col] = v[i].w;
        }
    }
    if (t < 12) {  // stage w (p1, fp32 -> f16): 96 halves
        float4 lo = *(const float4*)&p1w[e0 + t * 8];
        float4 hi = *(const float4*)&p1w[e0 + t * 8 + 4];
        uint4 v = pack_h8(lo, hi);
        wT[t * 4 + 0] = v.x; wT[t * 4 + 1] = v.y;
        wT[t * 4 + 2] = v.z; wT[t * 4 + 3] = v.w;
    }
    __syncthreads();

    float acc[8][4] = {};
#pragma unroll 4
    for (int ep = 0; ep < 48; ++ep) {
        uint4 a0 = *(const uint4*)&xT[ep * 128 + tm * 8];
        uint4 a1 = *(const uint4*)&xT[ep * 128 + tm * 8 + 4];
        uint4 mj = *(const uint4*)&mT[ep * 64 + tn * 4];
        const unsigned wv = wT[ep];
        const unsigned aa[8] = {a0.x, a0.y, a0.z, a0.w, a1.x, a1.y, a1.z, a1.w};
        const unsigned mm[4] = {mj.x, mj.y, mj.z, mj.w};
#pragma unroll
        for (int i = 0; i < 8; ++i)
#pragma unroll
            for (int j = 0; j < 4; ++j)
                acc[i][j] = dot2acc(addrelu2(aa[i], mm[j]), wv, acc[i][j]);
    }

#pragma unroll
    for (int i = 0; i < 8; ++i) {
        const int gb = b0 + tm * 8 + i;
        f32x4 v = {acc[i][0], acc[i][1], acc[i][2], acc[i][3]};
        st_wt_f32x4(&partial[((size_t)z * B_ + gb) * CPAD + c0 + tn * 4], v);
    }
}

// ---------------------------------------------------------------------------
// Phase D: per-row reduce of partials + bias, u-normalize (f16) + cls loss.
// ---------------------------------------------------------------------------
__device__ __forceinline__ void phase_reduce(
    char* smemc,
    const float* __restrict__ partial,
    const float* __restrict__ p1b, const float* __restrict__ p2b,
    const int* __restrict__ lb,
    ushort* __restrict__ uhf, float* __restrict__ sqn,
    float* __restrict__ clsbuf)
{
    float* sval = (float*)smemc;
    const int t = threadIdx.x;
    for (int b = blockIdx.x; b < B_; b += NBLK) {
        float v = 0.f;
#pragma unroll
        for (int z = 0; z < ECHUNKS; ++z)
            v += partial[((size_t)z * B_ + b) * CPAD + t];
        if (t < NCLS)       v += p1b[0];
        else if (t >= 192)  v += p2b[t - 192];

        sval[t] = v;
        __syncthreads();

        if (t < 64) {
            float uv = sval[192 + t];
            float s = uv * uv;
#pragma unroll
            for (int off = 32; off; off >>= 1) s += __shfl_xor(s, off);
            float inv = 1.f / fmaxf(sqrtf(s), 1e-12f);
            st_wt_u16(&uhf[(size_t)b * P_ + t], (unsigned)f2h(uv * inv));
            if (t == 0) st_wt_f32(&sqn[b], s * inv * inv);

            const int l = lb[b];
            float mx = -1e30f;
            for (int j = t; j < NCLS; j += 64)
                if (!(j == l && l < C_)) mx = fmaxf(mx, sval[j]);
#pragma unroll
            for (int off = 32; off; off >>= 1) mx = fmaxf(mx, __shfl_xor(mx, off));
            float se = 0.f;
            for (int j = t; j < NCLS; j += 64)
                if (!(j == l && l < C_)) se += expf(sval[j] - mx);
#pragma unroll
            for (int off = 32; off; off >>= 1) se += __shfl_xor(se, off);

            if (t == 0) {
                float l150  = sval[C_];
                float loss2 = mx + logf(se) - l150;
                float loss1 = 0.f;
                if (l < C_) {
                    float a  = sval[l];
                    float m2 = fmaxf(a, l150);
                    loss1 = m2 - a + logf(expf(a - m2) + expf(l150 - m2));
                }
                st_wt_f32(&clsbuf[b], loss1 + loss2);
            }
        }
        __syncthreads();
    }
}

// ---------------------------------------------------------------------------
// Phase E: pairwise margin losses via f16 MFMA Gram tiles. 256 tasks.
// ---------------------------------------------------------------------------
__device__ __forceinline__ void phase_pair(
    int id, char* smemc,
    const ushort* __restrict__ uhf, const float* __restrict__ sqn,
    const int* __restrict__ lb, float* __restrict__ pairpart)
{
    ushort* ui_s = (ushort*)smemc;               // 64*USTR halves = 9216 B
    ushort* uj_s = (ushort*)(smemc + 9216);      // 9216 B
    float*  sni  = (float*)(smemc + 18432);
    float*  snj  = (float*)(smemc + 18688);
    int*    li   = (int*)(smemc + 18944);
    int*    lj   = (int*)(smemc + 19200);
    float*  red  = (float*)(smemc + 19456);      // [4][4]

    const int t  = threadIdx.x;
    const int i0 = (id & 15) * 64, j0 = (id >> 4) * 64;

    for (int idx = t; idx < 512; idx += 256) {
        int row = idx >> 3, ch = (idx & 7) * 8;
        *(uint4*)&ui_s[row * USTR + ch] =
            *(const uint4*)&uhf[(size_t)(i0 + row) * P_ + ch];
        *(uint4*)&uj_s[row * USTR + ch] =
            *(const uint4*)&uhf[(size_t)(j0 + row) * P_ + ch];
    }
    if (t < 64)       { sni[t] = sqn[i0 + t]; li[t] = lb[i0 + t]; }
    else if (t < 128) { int q = t - 64; snj[q] = sqn[j0 + q]; lj[q] = lb[j0 + q]; }
    __syncthreads();

    const int wave = t >> 6, lane = t & 63;
    const int n = lane & 15, quad = lane >> 4;
    const int iw = wave * 16;

    const fp16x8 af0 = *(const fp16x8*)&ui_s[(iw + n) * USTR + quad * 8];
    const fp16x8 af1 = *(const fp16x8*)&ui_s[(iw + n) * USTR + quad * 8 + 32];

    f32x4 acc[4];
#pragma unroll
    for (int jt = 0; jt < 4; ++jt) {
        const fp16x8 bf0 = *(const fp16x8*)&uj_s[(jt * 16 + n) * USTR + quad * 8];
        const fp16x8 bf1 = *(const fp16x8*)&uj_s[(jt * 16 + n) * USTR + quad * 8 + 32];
        acc[jt] = __builtin_amdgcn_mfma_f32_16x16x32_f16(
            af0, bf0, (f32x4){0.f, 0.f, 0.f, 0.f}, 0, 0, 0);
        acc[jt] = __builtin_amdgcn_mfma_f32_16x16x32_f16(
            af1, bf1, acc[jt], 0, 0, 0);
    }

    float ps = 0.f, pc = 0.f, ns = 0.f, nc = 0.f;
#pragma unroll
    for (int jt = 0; jt < 4; ++jt)
#pragma unroll
        for (int r = 0; r < 4; ++r) {
            const int il = iw + quad * 4 + r;
            const int jl = jt * 16 + n;
            float sq = sni[il] + snj[jl] - 2.f * acc[jt][r];
            float dist = sq > 0.f ? sqrtf(fmaxf(sq, 1e-16f)) : 0.f;
            bool same = (li[il] == lj[jl]);
            if (same) {
                if (i0 + il != j0 + jl) { ps += fmaxf(dist - 0.7f, 0.f); pc += 1.f; }
            } else {
                ns += fmaxf(1.4f - dist, 0.f); nc += 1.f;
            }
        }

#pragma unroll
    for (int off = 32; off; off >>= 1) {
        ps += __shfl_xor(ps, off); pc += __shfl_xor(pc, off);
        ns += __shfl_xor(ns, off); nc += __shfl_xor(nc, off);
    }
    if (lane == 0) { red[0 * 4 + wave] = ps; red[1 * 4 + wave] = pc;
                     red[2 * 4 + wave] = ns; red[3 * 4 + wave] = nc; }
    __syncthreads();
    if (t == 0) {
        f32x4 v;
        v[0] = red[0] + red[1] + red[2] + red[3];
        v[1] = red[4] + red[5] + red[6] + red[7];
        v[2] = red[8] + red[9] + red[10] + red[11];
        v[3] = red[12] + red[13] + red[14] + red[15];
        st_wt_f32x4(&pairpart[(size_t)id * 4], v);
    }
}

// ---------------------------------------------------------------------------
// Phase F: block 0 reduces clsbuf[1024] and pairpart[256][4] -> out[0].
// ---------------------------------------------------------------------------
__device__ __forceinline__ void phase_final(
    char* smemc,
    const float* __restrict__ clsbuf, const float* __restrict__ pairpart,
    float* __restrict__ out)
{
    float* red = (float*)smemc;   // [5][4]
    const int t = threadIdx.x;
    float c = clsbuf[t] + clsbuf[t + 256] + clsbuf[t + 512] + clsbuf[t + 768];
    float4 pp = *(const float4*)&pairpart[(size_t)t * 4];
    float ps = pp.x, pc = pp.y, ns = pp.z, nc = pp.w;
#pragma unroll
    for (int off = 32; off; off >>= 1) {
        c  += __shfl_xor(c, off);
        ps += __shfl_xor(ps, off); pc += __shfl_xor(pc, off);
        ns += __shfl_xor(ns, off); nc += __shfl_xor(nc, off);
    }
    const int wave = t >> 6, lane = t & 63;
    if (lane == 0) { red[0 * 4 + wave] = c; red[1 * 4 + wave] = ps;
                     red[2 * 4 + wave] = pc; red[3 * 4 + wave] = ns;
                     red[4 * 4 + wave] = nc; }
    __syncthreads();
    if (t == 0) {
        float C = 0.f, PS = 0.f, PC = 0.f, NS = 0.f, NC = 0.f;
#pragma unroll
        for (int w = 0; w < 4; ++w) {
            C += red[0 * 4 + w]; PS += red[1 * 4 + w]; PC += red[2 * 4 + w];
            NS += red[3 * 4 + w]; NC += red[4 * 4 + w];
        }
        out[0] = C / (float)B_ + PS / fmaxf(PC, 1.f) + NS / fmaxf(NC, 1.f);
    }
}

// ---------------------------------------------------------------------------
// Persistent mega-kernel: 512 blocks x 256 threads, 2 blocks/CU co-resident.
// ---------------------------------------------------------------------------
__global__ __launch_bounds__(256, 2) void mega(
    const float* __restrict__ x, const int* __restrict__ lb,
    const float* __restrict__ mem, const float* __restrict__ fc_w,
    const float* __restrict__ fc_b, const float* __restrict__ p1w,
    const float* __restrict__ p1b, const float* __restrict__ p2w,
    const float* __restrict__ p2b,
    float* ws, float* out)
{
    __shared__ __align__(16) char smem[46080];

    ushort* mh       = (ushort*)(ws + OFF_MH);
    ushort* xh       = (ushort*)(ws + OFF_XH);
    float*  partial  = ws + OFF_PARTIAL;
    ushort* uhf      = (ushort*)(ws + OFF_UHF);
    float*  sqn      = ws + OFF_SQN;
    float*  clsbuf   = ws + OFF_CLS;
    float*  pairpart = ws + OFF_PAIR;
    int*    bar      = (int*)(ws + OFF_BAR);

    const int id = blockIdx.x;

    phase_gemm(id, smem, x, mem, fc_w, fc_b, xh, mh);
    grid_barrier(bar, 1);
    phase_fused(id, smem, xh, mh, p1w, p2w, partial);
    grid_barrier(bar, 2);
    phase_reduce(smem, partial, p1b, p2b, lb, uhf, sqn, clsbuf);
    grid_barrier(bar, 3);
    if (id < 256) phase_pair(id, smem, uhf, sqn, lb, pairpart);

    // ---- barrier 4 (arrive-only, fence-free) + root-runs-final ----
    asm volatile("s_waitcnt vmcnt(0)" ::: "memory");
    __syncthreads();
    if (threadIdx.x == 0) {
        int* arr = bar + 3 * 8 * 16;
        __hip_atomic_fetch_add(&arr[(blockIdx.x & 7) * 16], 1,
                               __ATOMIC_RELAXED, __HIP_MEMORY_SCOPE_AGENT);
    }
    if (blockIdx.x == 0) {
        if (threadIdx.x == 0) {
            int* arr = bar + 3 * 8 * 16;
            for (;;) {
                int s = 0;
#pragma unroll
                for (int k = 0; k < 8; ++k)
                    s += __hip_atomic_load(&arr[k * 16], __ATOMIC_RELAXED,
                                           __HIP_MEMORY_SCOPE_AGENT);
                if (s == NBLK) break;
                __builtin_amdgcn_s_sleep(1);
            }
        }
        asm volatile("" ::: "memory");
        __syncthreads();
        phase_final(smem, clsbuf, pairpart, out);
    }
}

extern "C" void kernel_launch(void* const* d_in, const int* in_sizes, int n_in,
                              void* d_out, int out_size, void* d_ws, size_t ws_size,
                              hipStream_t stream)
{
    const float* x    = (const float*)d_in[0];
    const int*   lb   = (const int*)d_in[1];
    const float* mem  = (const float*)d_in[2];
    const float* fc_w = (const float*)d_in[3];
    const float* fc_b = (const float*)d_in[4];
    const float* p1w  = (const float*)d_in[5];
    const float* p1b  = (const float*)d_in[6];
    const float* p2w  = (const float*)d_in[7];
    const float* p2b  = (const float*)d_in[8];

    float* ws  = (float*)d_ws;
    int*   bar = (int*)(ws + OFF_BAR);

    // Zero barrier state (arr[4][8] lines + gen[32] lines) — captured node.
    hipMemsetAsync(bar, 0, 8192, stream);

    mega<<<NBLK, 256, 0, stream>>>(x, lb, mem, fc_w, fc_b,
                                   p1w, p1b, p2w, p2b, ws, (float*)d_out);
}

// Round 7
// 131.498 us; speedup vs baseline: 3.0485x; 1.0090x over previous
//
#include <hip/hip_runtime.h>
#include <math.h>

// Problem constants
#define B_    1024
#define D_    768
#define C_    150
#define P_    64
#define TWOD  1536
#define NCLS  151   // C+1
#define CPAD  256   // partial row: 0..150 logits, 151..191 junk, 192..255 u

// fused_tile: 128b x 64c per block, 8x4/thr, e split 16 ways
#define ECHUNKS 16
#define ECHUNK  96

// gemm v2: 64x64 tile, BK=64, double-buffered LDS, stride 72 halves
#define GSTR  72
#define GBUF  (64 * GSTR)      // halves per buffer
#define NKT   (D_ / 64)        // 12 k-iterations
// u-path LDS stride (halves)
#define USTRU 120
// pair phase LDS stride (halves)
#define USTR  72
// fused xT padded stride (words/ep): row b at offset b + (b>>3)*4
#define XSTR  192

// persistent grid
#define NBLK  512

// Workspace layout (float offsets) — barrier state now lives in device
// globals (not poisoned by the harness workspace fill -> no memset needed).
#define OFF_MH      0
#define OFF_XH      (OFF_MH + (C_ * TWOD) / 2)
#define OFF_PARTIAL (OFF_XH + (B_ * TWOD) / 2)
#define OFF_UHF     (OFF_PARTIAL + ECHUNKS * B_ * CPAD)
#define OFF_SQN     (OFF_UHF + (B_ * P_) / 2)
#define OFF_CLS     (OFF_SQN + B_)
#define OFF_PAIR    (OFF_CLS + B_)

typedef __bf16    bfx8   __attribute__((ext_vector_type(8)));
typedef _Float16  fp16x8 __attribute__((ext_vector_type(8)));
typedef _Float16  h2v    __attribute__((ext_vector_type(2)));
typedef float     f32x4  __attribute__((ext_vector_type(4)));

// ---------------------------------------------------------------------------
// Persistent barrier state (device globals: zero-initialized at module load,
// persist across launches/graph-replays/rocprof-replays, and are NOT touched
// by the harness's workspace poison fill).
// Monotonic protocol: g_gen counts grid barriers EVER completed. Each block
// reads G0 = gen at kernel entry (safe: gen cannot advance past G0 until
// this block itself arrives at barrier 1, and the entry read is pinned by
// s_waitcnt before the arrival). Single arrival-counter set g_arr[8 lines];
// barrier b target: sum >= 512*(G0+b). No reset, no memset, ever.
// ---------------------------------------------------------------------------
__device__ int g_arr[8 * 16];    // 8 counter lines, 64B-spaced
__device__ int g_gen[32 * 16];   // 32 replicated gen lines

__device__ inline ushort f2bf(float f) {
    union { float f; unsigned u; } c; c.f = f;
    unsigned r = c.u + 0x7fffu + ((c.u >> 16) & 1u);
    return (ushort)(r >> 16);
}
__device__ inline ushort f2h(float f) {
    _Float16 h = (_Float16)f;
    return __builtin_bit_cast(ushort, h);
}
// pack 8 fp32 -> 8 bf16 in a uint4
__device__ inline uint4 pack_bf8(float4 a, float4 b) {
    uint4 r;
    r.x = (unsigned)f2bf(a.x) | ((unsigned)f2bf(a.y) << 16);
    r.y = (unsigned)f2bf(a.z) | ((unsigned)f2bf(a.w) << 16);
    r.z = (unsigned)f2bf(b.x) | ((unsigned)f2bf(b.y) << 16);
    r.w = (unsigned)f2bf(b.z) | ((unsigned)f2bf(b.w) << 16);
    return r;
}
// pack 8 fp32 -> 8 f16 in a uint4
__device__ inline uint4 pack_h8(float4 a, float4 b) {
    uint4 r;
    r.x = (unsigned)f2h(a.x) | ((unsigned)f2h(a.y) << 16);
    r.y = (unsigned)f2h(a.z) | ((unsigned)f2h(a.w) << 16);
    r.z = (unsigned)f2h(b.x) | ((unsigned)f2h(b.y) << 16);
    r.w = (unsigned)f2h(b.z) | ((unsigned)f2h(b.w) << 16);
    return r;
}
__device__ inline unsigned addrelu2(unsigned a, unsigned m) {
    h2v s = __builtin_bit_cast(h2v, a) + __builtin_bit_cast(h2v, m);
    h2v z = {(_Float16)0.f, (_Float16)0.f};
    s = __builtin_elementwise_max(s, z);
    return __builtin_bit_cast(unsigned, s);
}
__device__ inline unsigned relu2(unsigned a) {
    h2v s = __builtin_bit_cast(h2v, a);
    h2v z = {(_Float16)0.f, (_Float16)0.f};
    s = __builtin_elementwise_max(s, z);
    return __builtin_bit_cast(unsigned, s);
}
__device__ inline float dot2acc(unsigned a, unsigned b, float c) {
    return __builtin_amdgcn_fdot2(__builtin_bit_cast(h2v, a),
                                  __builtin_bit_cast(h2v, b), c, false);
}

// ---------------------------------------------------------------------------
// Write-through stores (sc0 sc1): agent-visible at the coherence point once
// vmcnt-complete, no wbl2 needed (validated v5/v6: absmax 0 with fence-free
// readers). Note (r6 counters): these lines do NOT allocate in L3 — readers
// re-fetch from HBM (FETCH 42.5MB). Accepted cost of the fence-free design.
// ---------------------------------------------------------------------------
__device__ __forceinline__ void st_wt_u16(ushort* p, unsigned v) {
    asm volatile("global_store_short %0, %1, off sc0 sc1"
                 :: "v"(p), "v"(v) : "memory");
}
__device__ __forceinline__ void st_wt_f32(float* p, float v) {
    asm volatile("global_store_dword %0, %1, off sc0 sc1"
                 :: "v"(p), "v"(v) : "memory");
}
__device__ __forceinline__ void st_wt_f32x4(float* p, f32x4 v) {
    asm volatile("global_store_dwordx4 %0, %1, off sc0 sc1"
                 :: "v"(p), "v"(v) : "memory");
}

// ---------------------------------------------------------------------------
// Grid barrier v6: monotonic, zero cache maintenance (~2-3us measured class).
// ---------------------------------------------------------------------------
__device__ __forceinline__ void grid_barrier(int G0, int b)
{
    asm volatile("s_waitcnt vmcnt(0)" ::: "memory");
    __syncthreads();
    if (threadIdx.x == 0) {
        const int target = G0 + b;
        __hip_atomic_fetch_add(&g_arr[(blockIdx.x & 7) * 16], 1,
                               __ATOMIC_RELAXED, __HIP_MEMORY_SCOPE_AGENT);
        if (blockIdx.x == 0) {
            const int starget = NBLK * target;
            for (;;) {
                int s = 0;
#pragma unroll
                for (int k = 0; k < 8; ++k)
                    s += __hip_atomic_load(&g_arr[k * 16], __ATOMIC_RELAXED,
                                           __HIP_MEMORY_SCOPE_AGENT);
                if (s - starget >= 0) break;
                __builtin_amdgcn_s_sleep(1);
            }
#pragma unroll
            for (int r = 0; r < 32; ++r)
                __hip_atomic_store(&g_gen[r * 16], target, __ATOMIC_RELAXED,
                                   __HIP_MEMORY_SCOPE_AGENT);
        } else {
            int* myg = &g_gen[(blockIdx.x & 31) * 16];
            while (__hip_atomic_load(myg, __ATOMIC_RELAXED,
                                     __HIP_MEMORY_SCOPE_AGENT) - target < 0)
                __builtin_amdgcn_s_sleep(4);
        }
        asm volatile("" ::: "memory");
    }
    __syncthreads();
}

// ---------------------------------------------------------------------------
// Phase B: merged MFMA GEMM (unchanged from r6 — 64x64, BK=64, dbuf LDS).
// ---------------------------------------------------------------------------
__device__ __forceinline__ void phase_gemm(
    int id, char* smemc,
    const float* __restrict__ x, const float* __restrict__ mem,
    const float* __restrict__ fc_w, const float* __restrict__ fc_b,
    ushort* __restrict__ xh, ushort* __restrict__ mh)
{
    if (id >= 456) return;
    ushort* As = (ushort*)smemc;                       // 2 x 64 x GSTR
    ushort* Bs = (ushort*)(smemc + 2 * GBUF * 2);      // 2 x 64 x GSTR
    const int t = threadIdx.x;

    const float* A; ushort* Out; int M, m0, n0, koff; bool xblk;
    if (id < 384) {
        xblk = true;  A = x;    Out = xh; M = B_;
        m0 = (id & 15) * 64; n0 = (id >> 4) * 64; koff = 0;
    } else {
        int q = id - 384;
        xblk = false; A = mem;  Out = mh; M = C_;
        m0 = (q % 3) * 64; n0 = (q / 3) * 64; koff = D_;
    }

    const int wave = t >> 6, lane = t & 63;
    const int wm = wave * 16;
    const int fm = lane & 15, quad = lane >> 4;

    const int row_a = t >> 2, qa = (t & 3) * 16;
    const int ar = min(m0 + row_a, M - 1);
    const float* Arow = A + (size_t)ar * D_ + qa;
    const float* Brow = fc_w + (size_t)(n0 + row_a) * TWOD + koff + qa;
    const int lw = row_a * GSTR + qa;

    f32x4 acc[4];
#pragma unroll
    for (int j = 0; j < 4; ++j) {
        float bv = xblk ? fc_b[n0 + j * 16 + fm] : 0.f;
        acc[j] = (f32x4){bv, bv, bv, bv};
    }

    float4 pa0 = *(const float4*)(Arow);
    float4 pa1 = *(const float4*)(Arow + 4);
    float4 pa2 = *(const float4*)(Arow + 8);
    float4 pa3 = *(const float4*)(Arow + 12);
    float4 pb0 = *(const float4*)(Brow);
    float4 pb1 = *(const float4*)(Brow + 4);
    float4 pb2 = *(const float4*)(Brow + 8);
    float4 pb3 = *(const float4*)(Brow + 12);

    for (int kt = 0; kt < NKT; ++kt) {
        ushort* Ad = As + (kt & 1) * GBUF;
        ushort* Bd = Bs + (kt & 1) * GBUF;
        *(uint4*)&Ad[lw]     = pack_bf8(pa0, pa1);
        *(uint4*)&Ad[lw + 8] = pack_bf8(pa2, pa3);
        *(uint4*)&Bd[lw]     = pack_bf8(pb0, pb1);
        *(uint4*)&Bd[lw + 8] = pack_bf8(pb2, pb3);
        __syncthreads();
        if (kt + 1 < NKT) {
            const int k1 = (kt + 1) * 64;
            pa0 = *(const float4*)(Arow + k1);
            pa1 = *(const float4*)(Arow + k1 + 4);
            pa2 = *(const float4*)(Arow + k1 + 8);
            pa3 = *(const float4*)(Arow + k1 + 12);
            pb0 = *(const float4*)(Brow + k1);
            pb1 = *(const float4*)(Brow + k1 + 4);
            pb2 = *(const float4*)(Brow + k1 + 8);
            pb3 = *(const float4*)(Brow + k1 + 12);
        }
#pragma unroll
        for (int ks = 0; ks < 2; ++ks) {
            bfx8 af = *(const bfx8*)&Ad[(wm + fm) * GSTR + ks * 32 + quad * 8];
#pragma unroll
            for (int j = 0; j < 4; ++j) {
                bfx8 bf = *(const bfx8*)&Bd[(j * 16 + fm) * GSTR + ks * 32 + quad * 8];
                acc[j] = __builtin_amdgcn_mfma_f32_16x16x32_bf16(
                    af, bf, acc[j], 0, 0, 0);
            }
        }
    }

#pragma unroll
    for (int j = 0; j < 4; ++j)
#pragma unroll
        for (int r = 0; r < 4; ++r) {
            int row = m0 + wm + quad * 4 + r;
            int col = n0 + j * 16 + fm;
            if (row < M)
                st_wt_u16(&Out[(size_t)row * TWOD + col],
                          (unsigned)f2h(acc[j][r]));
        }
}

// ---------------------------------------------------------------------------
// Phase C: fused tile. y<3: elementwise partial[z][b][c] = sum relu(xh+m)*p1
// y==3: MFMA f16 u-projection partial[z][b][192+n] = sum relu(xh)*p2.
// xT layout padded (r7): word idx = ep*XSTR + b + (b>>3)*4 — read starts at
// tm*12 % 32 (8 distinct banks, was 4) -> 4-way conflict becomes ~2-way free.
// ---------------------------------------------------------------------------
__device__ __forceinline__ void phase_fused(
    int id, char* smem,
    const ushort* __restrict__ xh, const ushort* __restrict__ mh,
    const float* __restrict__ p1w, const float* __restrict__ p2w,
    float* __restrict__ partial)
{
    const int t  = threadIdx.x;
    const int b0 = (id & 7) * 128;
    const int y  = (id >> 3) & 3;
    const int z  = id >> 5;
    const int e0 = z * ECHUNK;

    if (y == 3) {
        // -------- MFMA f16 u-projection path --------
        ushort* Au = (ushort*)smem;                 // 128 x USTRU halves
        ushort* Wu = (ushort*)(smem + 30720);       // 64 x USTRU halves
        const int wave = t >> 6, lane = t & 63;
        const int fm = lane & 15, quad = lane >> 4;

        {   // stage relu(xh) f16 : 128 rows x 96 k
            const int row = t >> 1, kh = (t & 1) * 48;
            const ushort* src = xh + (size_t)(b0 + row) * TWOD + e0 + kh;
            uint4 v[6];
#pragma unroll
            for (int i = 0; i < 6; ++i) v[i] = *(const uint4*)&src[i * 8];
#pragma unroll
            for (int i = 0; i < 6; ++i) {
                v[i].x = relu2(v[i].x); v[i].y = relu2(v[i].y);
                v[i].z = relu2(v[i].z); v[i].w = relu2(v[i].w);
                *(uint4*)&Au[row * USTRU + kh + i * 8] = v[i];
            }
        }
        {   // stage p2 (fp32 -> f16) : 64 rows x 96 k
            const int row = t >> 2, ks = (t & 3) * 24;
            const float* pw = p2w + (size_t)row * TWOD + e0 + ks;
#pragma unroll
            for (int i = 0; i < 3; ++i) {
                float4 lo = *(const float4*)&pw[i * 8];
                float4 hi = *(const float4*)&pw[i * 8 + 4];
                *(uint4*)&Wu[row * USTRU + ks + i * 8] = pack_h8(lo, hi);
            }
        }
        __syncthreads();

        f32x4 uacc[2][4];
#pragma unroll
        for (int i = 0; i < 2; ++i)
#pragma unroll
            for (int j = 0; j < 4; ++j) uacc[i][j] = (f32x4){0.f, 0.f, 0.f, 0.f};
#pragma unroll
        for (int k0 = 0; k0 < ECHUNK; k0 += 32) {
            fp16x8 af[2], bff[4];
#pragma unroll
            for (int i = 0; i < 2; ++i)
                af[i] = *(const fp16x8*)&Au[(wave * 32 + i * 16 + fm) * USTRU + k0 + quad * 8];
#pragma unroll
            for (int j = 0; j < 4; ++j)
                bff[j] = *(const fp16x8*)&Wu[(j * 16 + fm) * USTRU + k0 + quad * 8];
#pragma unroll
            for (int i = 0; i < 2; ++i)
#pragma unroll
                for (int j = 0; j < 4; ++j)
                    uacc[i][j] = __builtin_amdgcn_mfma_f32_16x16x32_f16(
                        af[i], bff[j], uacc[i][j], 0, 0, 0);
        }
#pragma unroll
        for (int i = 0; i < 2; ++i)
#pragma unroll
            for (int j = 0; j < 4; ++j)
#pragma unroll
                for (int r = 0; r < 4; ++r) {
                    int row = b0 + wave * 32 + i * 16 + quad * 4 + r;
                    st_wt_f32(&partial[((size_t)z * B_ + row) * CPAD + 192 + j * 16 + fm],
                              uacc[i][j][r]);
                }
        return;
    }

    // -------- elementwise f16 path: cols c0..c0+63 (c0 in {0,64,128}) -----
    unsigned* xT = (unsigned*)smem;             // [48 ep][XSTR] padded words
    unsigned* mT = (unsigned*)(smem + 36864);   // [48][64 c]
    unsigned* wT = (unsigned*)(smem + 49152);   // [48]
    const int c0 = y * 64;
    const int tm = t & 15, tn = t >> 4;

    {   // stage x: 2 thr/row, 48 halves each (padded xT layout)
        const int row = t >> 1, ph = (t & 1) * 48;
        const int rowo = row + ((row >> 3) << 2);
        const ushort* src = xh + (size_t)(b0 + row) * TWOD + e0 + ph;
        uint4 v[6];
#pragma unroll
        for (int i = 0; i < 6; ++i) v[i] = *(const uint4*)&src[i * 8];
#pragma unroll
        for (int i = 0; i < 6; ++i) {
            const int ep = (t & 1) * 24 + i * 4;
            xT[(ep + 0) * XSTR + rowo] = v[i].x;
            xT[(ep + 1) * XSTR + rowo] = v[i].y;
            xT[(ep + 2) * XSTR + rowo] = v[i].z;
            xT[(ep + 3) * XSTR + rowo] = v[i].w;
        }
    }
    {   // stage m: 4 thr/col, 24 halves each
        const int col = t & 63, seg = t >> 6;
        const int gc  = c0 + col;
        uint4 v[3];
        if (gc < C_) {
            const ushort* src = mh + (size_t)gc * TWOD + e0 + seg * 24;
#pragma unroll
            for (int i = 0; i < 3; ++i) v[i] = *(const uint4*)&src[i * 8];
        } else {
#pragma unroll
            for (int i = 0; i < 3; ++i) v[i] = make_uint4(0, 0, 0, 0);
        }
#pragma unroll
        for (int i = 0; i < 3; ++i) {
            const int ep = seg * 12 + i * 4;
            mT[(ep + 0) * 64 + col] = v[i].x;
            mT[(ep + 1) * 64 + col] = v[i].y;
            mT[(ep + 2) * 64 + col] = v[i].z;
            mT[(ep + 3) * 64 + col] = v[i].w;
        }
    }
    if (t < 12) {  // stage w (p1, fp32 -> f16): 96 halves
        float4 lo = *(const float4*)&p1w[e0 + t * 8];
        float4 hi = *(const float4*)&p1w[e0 + t * 8 + 4];
        uint4 v = pack_h8(lo, hi);
        wT[t * 4 + 0] = v.x; wT[t * 4 + 1] = v.y;
        wT[t * 4 + 2] = v.z; wT[t * 4 + 3] = v.w;
    }
    __syncthreads();

    float acc[8][4] = {};
#pragma unroll 4
    for (int ep = 0; ep < 48; ++ep) {
        uint4 a0 = *(const uint4*)&xT[ep * XSTR + tm * 12];
        uint4 a1 = *(const uint4*)&xT[ep * XSTR + tm * 12 + 4];
        uint4 mj = *(const uint4*)&mT[ep * 64 + tn * 4];
        const unsigned wv = wT[ep];
        const unsigned aa[8] = {a0.x, a0.y, a0.z, a0.w, a1.x, a1.y, a1.z, a1.w};
        const unsigned mm[4] = {mj.x, mj.y, mj.z, mj.w};
#pragma unroll
        for (int i = 0; i < 8; ++i)
#pragma unroll
            for (int j = 0; j < 4; ++j)
                acc[i][j] = dot2acc(addrelu2(aa[i], mm[j]), wv, acc[i][j]);
    }

#pragma unroll
    for (int i = 0; i < 8; ++i) {
        const int gb = b0 + tm * 8 + i;
        f32x4 v = {acc[i][0], acc[i][1], acc[i][2], acc[i][3]};
        st_wt_f32x4(&partial[((size_t)z * B_ + gb) * CPAD + c0 + tn * 4], v);
    }
}

// ---------------------------------------------------------------------------
// Phase D: per-row reduce of partials + bias, u-normalize (f16) + cls loss.
// ---------------------------------------------------------------------------
__device__ __forceinline__ void phase_reduce(
    char* smemc,
    const float* __restrict__ partial,
    const float* __restrict__ p1b, const float* __restrict__ p2b,
    const int* __restrict__ lb,
    ushort* __restrict__ uhf, float* __restrict__ sqn,
    float* __restrict__ clsbuf)
{
    float* sval = (float*)smemc;
    const int t = threadIdx.x;
    for (int b = blockIdx.x; b < B_; b += NBLK) {
        float v = 0.f;
#pragma unroll
        for (int z = 0; z < ECHUNKS; ++z)
            v += partial[((size_t)z * B_ + b) * CPAD + t];
        if (t < NCLS)       v += p1b[0];
        else if (t >= 192)  v += p2b[t - 192];

        sval[t] = v;
        __syncthreads();

        if (t < 64) {
            float uv = sval[192 + t];
            float s = uv * uv;
#pragma unroll
            for (int off = 32; off; off >>= 1) s += __shfl_xor(s, off);
            float inv = 1.f / fmaxf(sqrtf(s), 1e-12f);
            st_wt_u16(&uhf[(size_t)b * P_ + t], (unsigned)f2h(uv * inv));
            if (t == 0) st_wt_f32(&sqn[b], s * inv * inv);

            const int l = lb[b];
            float mx = -1e30f;
            for (int j = t; j < NCLS; j += 64)
                if (!(j == l && l < C_)) mx = fmaxf(mx, sval[j]);
#pragma unroll
            for (int off = 32; off; off >>= 1) mx = fmaxf(mx, __shfl_xor(mx, off));
            float se = 0.f;
            for (int j = t; j < NCLS; j += 64)
                if (!(j == l && l < C_)) se += expf(sval[j] - mx);
#pragma unroll
            for (int off = 32; off; off >>= 1) se += __shfl_xor(se, off);

            if (t == 0) {
                float l150  = sval[C_];
                float loss2 = mx + logf(se) - l150;
                float loss1 = 0.f;
                if (l < C_) {
                    float a  = sval[l];
                    float m2 = fmaxf(a, l150);
                    loss1 = m2 - a + logf(expf(a - m2) + expf(l150 - m2));
                }
                st_wt_f32(&clsbuf[b], loss1 + loss2);
            }
        }
        __syncthreads();
    }
}

// ---------------------------------------------------------------------------
// Phase E: pairwise margin losses via f16 MFMA Gram tiles. 256 tasks.
// ---------------------------------------------------------------------------
__device__ __forceinline__ void phase_pair(
    int id, char* smemc,
    const ushort* __restrict__ uhf, const float* __restrict__ sqn,
    const int* __restrict__ lb, float* __restrict__ pairpart)
{
    ushort* ui_s = (ushort*)smemc;               // 64*USTR halves = 9216 B
    ushort* uj_s = (ushort*)(smemc + 9216);      // 9216 B
    float*  sni  = (float*)(smemc + 18432);
    float*  snj  = (float*)(smemc + 18688);
    int*    li   = (int*)(smemc + 18944);
    int*    lj   = (int*)(smemc + 19200);
    float*  red  = (float*)(smemc + 19456);      // [4][4]

    const int t  = threadIdx.x;
    const int i0 = (id & 15) * 64, j0 = (id >> 4) * 64;

    for (int idx = t; idx < 512; idx += 256) {
        int row = idx >> 3, ch = (idx & 7) * 8;
        *(uint4*)&ui_s[row * USTR + ch] =
            *(const uint4*)&uhf[(size_t)(i0 + row) * P_ + ch];
        *(uint4*)&uj_s[row * USTR + ch] =
            *(const uint4*)&uhf[(size_t)(j0 + row) * P_ + ch];
    }
    if (t < 64)       { sni[t] = sqn[i0 + t]; li[t] = lb[i0 + t]; }
    else if (t < 128) { int q = t - 64; snj[q] = sqn[j0 + q]; lj[q] = lb[j0 + q]; }
    __syncthreads();

    const int wave = t >> 6, lane = t & 63;
    const int n = lane & 15, quad = lane >> 4;
    const int iw = wave * 16;

    const fp16x8 af0 = *(const fp16x8*)&ui_s[(iw + n) * USTR + quad * 8];
    const fp16x8 af1 = *(const fp16x8*)&ui_s[(iw + n) * USTR + quad * 8 + 32];

    f32x4 acc[4];
#pragma unroll
    for (int jt = 0; jt < 4; ++jt) {
        const fp16x8 bf0 = *(const fp16x8*)&uj_s[(jt * 16 + n) * USTR + quad * 8];
        const fp16x8 bf1 = *(const fp16x8*)&uj_s[(jt * 16 + n) * USTR + quad * 8 + 32];
        acc[jt] = __builtin_amdgcn_mfma_f32_16x16x32_f16(
            af0, bf0, (f32x4){0.f, 0.f, 0.f, 0.f}, 0, 0, 0);
        acc[jt] = __builtin_amdgcn_mfma_f32_16x16x32_f16(
            af1, bf1, acc[jt], 0, 0, 0);
    }

    float ps = 0.f, pc = 0.f, ns = 0.f, nc = 0.f;
#pragma unroll
    for (int jt = 0; jt < 4; ++jt)
#pragma unroll
        for (int r = 0; r < 4; ++r) {
            const int il = iw + quad * 4 + r;
            const int jl = jt * 16 + n;
            float sq = sni[il] + snj[jl] - 2.f * acc[jt][r];
            float dist = sq > 0.f ? sqrtf(fmaxf(sq, 1e-16f)) : 0.f;
            bool same = (li[il] == lj[jl]);
            if (same) {
                if (i0 + il != j0 + jl) { ps += fmaxf(dist - 0.7f, 0.f); pc += 1.f; }
            } else {
                ns += fmaxf(1.4f - dist, 0.f); nc += 1.f;
            }
        }

#pragma unroll
    for (int off = 32; off; off >>= 1) {
        ps += __shfl_xor(ps, off); pc += __shfl_xor(pc, off);
        ns += __shfl_xor(ns, off); nc += __shfl_xor(nc, off);
    }
    if (lane == 0) { red[0 * 4 + wave] = ps; red[1 * 4 + wave] = pc;
                     red[2 * 4 + wave] = ns; red[3 * 4 + wave] = nc; }
    __syncthreads();
    if (t == 0) {
        f32x4 v;
        v[0] = red[0] + red[1] + red[2] + red[3];
        v[1] = red[4] + red[5] + red[6] + red[7];
        v[2] = red[8] + red[9] + red[10] + red[11];
        v[3] = red[12] + red[13] + red[14] + red[15];
        st_wt_f32x4(&pairpart[(size_t)id * 4], v);
    }
}

// ---------------------------------------------------------------------------
// Phase F: block 0 reduces clsbuf[1024] and pairpart[256][4] -> out[0].
// ---------------------------------------------------------------------------
__device__ __forceinline__ void phase_final(
    char* smemc,
    const float* __restrict__ clsbuf, const float* __restrict__ pairpart,
    float* __restrict__ out)
{
    float* red = (float*)smemc;   // [5][4]
    const int t = threadIdx.x;
    float c = clsbuf[t] + clsbuf[t + 256] + clsbuf[t + 512] + clsbuf[t + 768];
    float4 pp = *(const float4*)&pairpart[(size_t)t * 4];
    float ps = pp.x, pc = pp.y, ns = pp.z, nc = pp.w;
#pragma unroll
    for (int off = 32; off; off >>= 1) {
        c  += __shfl_xor(c, off);
        ps += __shfl_xor(ps, off); pc += __shfl_xor(pc, off);
        ns += __shfl_xor(ns, off); nc += __shfl_xor(nc, off);
    }
    const int wave = t >> 6, lane = t & 63;
    if (lane == 0) { red[0 * 4 + wave] = c; red[1 * 4 + wave] = ps;
                     red[2 * 4 + wave] = pc; red[3 * 4 + wave] = ns;
                     red[4 * 4 + wave] = nc; }
    __syncthreads();
    if (t == 0) {
        float C = 0.f, PS = 0.f, PC = 0.f, NS = 0.f, NC = 0.f;
#pragma unroll
        for (int w = 0; w < 4; ++w) {
            C += red[0 * 4 + w]; PS += red[1 * 4 + w]; PC += red[2 * 4 + w];
            NS += red[3 * 4 + w]; NC += red[4 * 4 + w];
        }
        out[0] = C / (float)B_ + PS / fmaxf(PC, 1.f) + NS / fmaxf(NC, 1.f);
    }
}

// ---------------------------------------------------------------------------
// Persistent mega-kernel: 512 blocks x 256 threads, 2 blocks/CU co-resident
// (LDS 49344 B -> 80KB/block budget at 2/CU still holds).
// ---------------------------------------------------------------------------
__global__ __launch_bounds__(256, 2) void mega(
    const float* __restrict__ x, const int* __restrict__ lb,
    const float* __restrict__ mem, const float* __restrict__ fc_w,
    const float* __restrict__ fc_b, const float* __restrict__ p1w,
    const float* __restrict__ p1b, const float* __restrict__ p2w,
    const float* __restrict__ p2b,
    float* ws, float* out)
{
    __shared__ __align__(16) char smem[49344];

    ushort* mh       = (ushort*)(ws + OFF_MH);
    ushort* xh       = (ushort*)(ws + OFF_XH);
    float*  partial  = ws + OFF_PARTIAL;
    ushort* uhf      = (ushort*)(ws + OFF_UHF);
    float*  sqn      = ws + OFF_SQN;
    float*  clsbuf   = ws + OFF_CLS;
    float*  pairpart = ws + OFF_PAIR;

    const int id = blockIdx.x;

    // Entry read of the monotonic barrier epoch. Safe: gen cannot advance
    // past its pre-launch value until THIS block arrives at barrier 1, and
    // the waitcnt pins the load's completion before any arrival below.
    int G0 = 0;
    if (threadIdx.x == 0) {
        G0 = __hip_atomic_load(&g_gen[(blockIdx.x & 31) * 16],
                               __ATOMIC_RELAXED, __HIP_MEMORY_SCOPE_AGENT);
        asm volatile("s_waitcnt vmcnt(0)" ::: "memory");
    }

    phase_gemm(id, smem, x, mem, fc_w, fc_b, xh, mh);
    grid_barrier(G0, 1);
    phase_fused(id, smem, xh, mh, p1w, p2w, partial);
    grid_barrier(G0, 2);
    phase_reduce(smem, partial, p1b, p2b, lb, uhf, sqn, clsbuf);
    grid_barrier(G0, 3);
    if (id < 256) phase_pair(id, smem, uhf, sqn, lb, pairpart);

    // ---- barrier 4 (arrive-only, monotonic) + root-runs-final ----
    asm volatile("s_waitcnt vmcnt(0)" ::: "memory");
    __syncthreads();
    if (threadIdx.x == 0) {
        __hip_atomic_fetch_add(&g_arr[(blockIdx.x & 7) * 16], 1,
                               __ATOMIC_RELAXED, __HIP_MEMORY_SCOPE_AGENT);
    }
    if (blockIdx.x == 0) {
        if (threadIdx.x == 0) {
            const int starget = NBLK * (G0 + 4);
            for (;;) {
                int s = 0;
#pragma unroll
                for (int k = 0; k < 8; ++k)
                    s += __hip_atomic_load(&g_arr[k * 16], __ATOMIC_RELAXED,
                                           __HIP_MEMORY_SCOPE_AGENT);
                if (s - starget >= 0) break;
                __builtin_amdgcn_s_sleep(1);
            }
            // Advance gen so the NEXT launch's entry reads see G0+4.
#pragma unroll
            for (int r = 0; r < 32; ++r)
                __hip_atomic_store(&g_gen[r * 16], G0 + 4, __ATOMIC_RELAXED,
                                   __HIP_MEMORY_SCOPE_AGENT);
        }
        asm volatile("" ::: "memory");
        __syncthreads();
        phase_final(smem, clsbuf, pairpart, out);
    }
}

extern "C" void kernel_launch(void* const* d_in, const int* in_sizes, int n_in,
                              void* d_out, int out_size, void* d_ws, size_t ws_size,
                              hipStream_t stream)
{
    const float* x    = (const float*)d_in[0];
    const int*   lb   = (const int*)d_in[1];
    const float* mem  = (const float*)d_in[2];
    const float* fc_w = (const float*)d_in[3];
    const float* fc_b = (const float*)d_in[4];
    const float* p1w  = (const float*)d_in[5];
    const float* p1b  = (const float*)d_in[6];
    const float* p2w  = (const float*)d_in[7];
    const float* p2b  = (const float*)d_in[8];

    float* ws = (float*)d_ws;

    // Single node: barrier state is persistent device-global (monotonic),
    // no memset required.
    mega<<<NBLK, 256, 0, stream>>>(x, lb, mem, fc_w, fc_b,
                                   p1w, p1b, p2w, p2b, ws, (float*)d_out);
}